// Round 10
// baseline (332.003 us; speedup 1.0000x reference)
//
#include <hip/hip_runtime.h>
#include <math.h>

#define B_C   4096   // comments
#define N_SRT 8192   // srt rows
#define D_C   768
#define D_S   1024
#define KSEL  2
#define NGRP  (N_SRT / 4)   // 2048 groups of 4 consecutive srt rows
#define PGRP  8             // groups refined per comment row (32 candidates)

typedef float    f32x4  __attribute__((ext_vector_type(4)));
typedef short    short8 __attribute__((ext_vector_type(8)));
typedef _Float16 half8  __attribute__((ext_vector_type(8)));

__device__ inline unsigned short f2bf(float f) {           // RTNE float->bf16
    unsigned u = __float_as_uint(f);
    u += 0x7FFF + ((u >> 16) & 1);
    return (unsigned short)(u >> 16);
}
__device__ inline float bf2f(unsigned short h) {
    return __uint_as_float(((unsigned)h) << 16);
}

#define GLOAD_LDS16(gsrc, ldst)                                                     \
    __builtin_amdgcn_global_load_lds(                                               \
        (const __attribute__((address_space(1))) void*)(gsrc),                      \
        (__attribute__((address_space(3))) void*)(ldst), 16, 0, 0)

// ---------------------------------------------------------------------------
// split_act: fp16 2-term split of activations. Plane0 = f16(x) (scale 1),
// plane1 = f16(2^11 * (x - plane0)) (scale 2^11). Residual <= 2^-22 |x|.
// ---------------------------------------------------------------------------
__global__ __launch_bounds__(256)
void split_act(const float* __restrict__ srt, const float* __restrict__ com,
               _Float16* __restrict__ pS, _Float16* __restrict__ pC) {
    const int g = blockIdx.x * 256 + threadIdx.x;   // one 8-elem group / thread
    const int E0 = N_SRT * D_S / 8;
    const float* src;
    _Float16* dst;
    size_t stride;
    if (g < E0) {
        src = srt + (size_t)g * 8; dst = pS + (size_t)g * 8;
        stride = (size_t)N_SRT * D_S;
    } else {
        const int g2 = g - E0;
        src = com + (size_t)g2 * 8; dst = pC + (size_t)g2 * 8;
        stride = (size_t)B_C * D_C;
    }
    const float4 a = *reinterpret_cast<const float4*>(src);
    const float4 b = *reinterpret_cast<const float4*>(src + 4);
    const float x[8] = {a.x, a.y, a.z, a.w, b.x, b.y, b.z, b.w};
    half8 hv, mv;
#pragma unroll
    for (int j = 0; j < 8; ++j) {
        const _Float16 h = (_Float16)x[j];
        const float    r = x[j] - (float)h;          // exact
        hv[j] = h; mv[j] = (_Float16)(r * 2048.0f);
    }
    *reinterpret_cast<half8*>(dst)          = hv;
    *reinterpret_cast<half8*>(dst + stride) = mv;
}

// ---------------------------------------------------------------------------
// split_w: W[k][n] -> 2 fp16 planes of W^T: Wt[p][n][k]. Plane0 = f16(2^15 W)
// (scale 2^15, keeps all weights fp16-normal), plane1 = f16(2^11 * residual)
// (scale 2^26). 64x64 LDS transpose, pad 65.
// ---------------------------------------------------------------------------
__global__ __launch_bounds__(256)
void split_w(const float* __restrict__ W, _Float16* __restrict__ Wt, int K) {
    __shared__ float t[64][65];
    const int n0 = blockIdx.x * 64, k0 = blockIdx.y * 64;
    const int tid = threadIdx.x;
    const int c = tid & 63, rq = tid >> 6;
#pragma unroll
    for (int j = 0; j < 16; ++j) {
        const int kr = rq * 16 + j;
        t[kr][c] = W[(size_t)(k0 + kr) * D_S + n0 + c];
    }
    __syncthreads();
    const size_t PS = (size_t)K * D_S;
#pragma unroll
    for (int j = 0; j < 16; ++j) {
        const int nr = rq * 16 + j;
        const float xs = t[c][nr] * 32768.0f;        // exact (pow2 scale)
        const _Float16 h = (_Float16)xs;
        const float    r = xs - (float)h;            // exact
        const size_t o = (size_t)(n0 + nr) * K + k0 + c;
        Wt[o]      = h;
        Wt[o + PS] = (_Float16)(r * 2048.0f);
    }
}

// ---------------------------------------------------------------------------
// transform_mfma_all (round-10 reshape): 128-thread blocks, 2 waves.
// Block tile 128(n) x 128(m); wave tile 128(n) x 64(m): per K=32 step each
// wave issues 12 ds_read_b128 per 32 MFMA (ratio 0.375 vs round-9's 0.5) --
// the shared LDS unit was the 1.5x-oversubscribed pipe (round-9 PMC model).
// 2-phase stage-ahead dbuf, BK=32 XOR swizzle, XCD-chunked swizzle, scaled
// fp16x3 single-accumulator numerics: all unchanged (verified).
// acc[i][j]: n = bn + i*16 + lg*4 + q (i=0..7);  m = bm + wv*64 + j*16 + lr.
// LDS 32 KB/block; VGPR ~200 (acc 128) -> ~5 blocks/CU.
// ---------------------------------------------------------------------------
__global__ __launch_bounds__(128)
void transform_mfma_all(const _Float16* __restrict__ actS,
                        const _Float16* __restrict__ wtS,
                        const float* __restrict__ bS,
                        float* __restrict__ CS, unsigned short* __restrict__ HS,
                        const _Float16* __restrict__ actC,
                        const _Float16* __restrict__ wtC,
                        const float* __restrict__ bC,
                        float* __restrict__ CC, unsigned short* __restrict__ HC) {
    __shared__ __align__(16) _Float16 sA[2][128 * 32];  // Wt tile (8KB each)
    __shared__ __align__(16) _Float16 sB[2][128 * 32];  // Act tile
    const int tid  = threadIdx.x;
    const int lane = tid & 63;
    const int wv   = tid >> 6;            // wave 0/1
    const int lr   = lane & 15, lg = lane >> 4;

    // per-segment XCD-chunked bijective swizzle (512%8==0, 256%8==0)
    const int hw = blockIdx.x;
    int lgid, seg;
    if (hw < 512) { seg = 0; lgid = (hw & 7) * 64 + (hw >> 3); }
    else          { const int h2 = hw - 512; seg = 1; lgid = (h2 & 7) * 32 + (h2 >> 3); }

    const _Float16* __restrict__ actP = seg ? actC : actS;
    const _Float16* __restrict__ wtP  = seg ? wtC  : wtS;
    const float* __restrict__ bias    = seg ? bC   : bS;
    float* __restrict__ C             = seg ? CC   : CS;
    unsigned short* __restrict__ H    = seg ? HC   : HS;
    const int K   = seg ? D_C : D_S;
    const int KC  = seg ? (D_C / 32) : (D_S / 32);    // 24 : 32
    const size_t aps = seg ? (size_t)B_C * D_C : (size_t)N_SRT * D_S;
    const size_t wps = (size_t)D_S * K;

    const int bn = (lgid & 7) * 128;      // out-col tile
    const int bm = (lgid >> 3) * 128;     // act-row tile

    const f32x4 vzero = {0.f, 0.f, 0.f, 0.f};
    f32x4 acc[8][4];
#pragma unroll
    for (int i = 0; i < 8; ++i)
#pragma unroll
        for (int j = 0; j < 4; ++j) acc[i][j] = vzero;

    const int NT = 3 * KC;

    auto stage = [&](int buf, int t) {
        const int pp = (t >= KC) + (t >= 2 * KC);    // 0,1,2
        const int kb = (t - pp * KC) * 32;
        const _Float16* gA = wtP  + (pp == 2 ? wps : 0) + (size_t)bn * K + kb;
        const _Float16* gB = actP + (pp == 1 ? aps : 0) + (size_t)bm * K + kb;
#pragma unroll
        for (int i = 0; i < 4; ++i) {
            const int idx = tid + i * 128;           // 0..511
            const int r   = idx >> 2;                // row 0..127
            const int sw  = ((idx & 3) ^ ((r >> 1) & 3)) * 8;  // elem offset
            GLOAD_LDS16(gA + (size_t)r * K + sw,
                        (char*)&sA[buf][0] + idx * 16);
            GLOAD_LDS16(gB + (size_t)r * K + sw,
                        (char*)&sB[buf][0] + idx * 16);
        }
    };

    stage(0, 0);
    __syncthreads();

    for (int t = 0; t < NT; ++t) {
        const int cur = t & 1;
        if (t + 1 < NT) stage(cur ^ 1, t + 1);
        const bool first = (t < KC);     // pp0: scale act frags by 2^11

        half8 a[8], b[4];
#pragma unroll
        for (int i = 0; i < 8; ++i) {
            const int ra = i * 16 + lr;
            a[i] = *(const half8*)((const char*)&sA[cur][0] + ra * 64 +
                                   ((lg ^ ((ra >> 1) & 3)) * 16));
        }
#pragma unroll
        for (int j = 0; j < 4; ++j) {
            const int rb = wv * 64 + j * 16 + lr;
            b[j] = *(const half8*)((const char*)&sB[cur][0] + rb * 64 +
                                   ((lg ^ ((rb >> 1) & 3)) * 16));
        }
        if (first) {
#pragma unroll
            for (int j = 0; j < 4; ++j)
                b[j] = b[j] * (_Float16)2048.0f;     // exact pow2
        }
#pragma unroll
        for (int i = 0; i < 8; ++i)
#pragma unroll
            for (int j = 0; j < 4; ++j)
                acc[i][j] = __builtin_amdgcn_mfma_f32_16x16x32_f16(
                    a[i], b[j], acc[i][j], 0, 0, 0);
        __syncthreads();
    }

    // epilogue: n = bn + i*16 + lg*4 + q;  m = bm + wv*64 + j*16 + lr
    const float s2 = 1.4901161193847656e-8f;    // 2^-26
#pragma unroll
    for (int i = 0; i < 8; ++i) {
        const int n = bn + i * 16 + lg * 4;
        const f32x4 bb = *reinterpret_cast<const f32x4*>(&bias[n]);
#pragma unroll
        for (int j = 0; j < 4; ++j) {
            const int m = bm + wv * 64 + j * 16 + lr;
            f32x4 o;
#pragma unroll
            for (int q = 0; q < 4; ++q)
                o[q] = fmaxf(fmaf(acc[i][j][q], s2, bb[q]), 0.f);
            *reinterpret_cast<f32x4*>(&C[(size_t)m * D_S + n]) = o;
            ushort4 hh;
            hh.x = f2bf(o[0]); hh.y = f2bf(o[1]);
            hh.z = f2bf(o[2]); hh.w = f2bf(o[3]);
            *reinterpret_cast<ushort4*>(&H[(size_t)m * D_S + n]) = hh;
        }
    }
}

// ---------------------------------------------------------------------------
// FALLBACK (round-5 verified): fused fp32 VALU transforms (ws too small).
// ---------------------------------------------------------------------------
#define NB0 ((B_C / 128) * (D_S / 128))     // 256
#define NB1 ((N_SRT / 128) * (D_S / 128))   // 512

__global__ __launch_bounds__(256)
void transform_fused(const float* __restrict__ A0, const float* __restrict__ W0,
                     const float* __restrict__ b0, float* __restrict__ C0,
                     unsigned short* __restrict__ H0,
                     const float* __restrict__ A1, const float* __restrict__ W1,
                     const float* __restrict__ b1, float* __restrict__ C1,
                     unsigned short* __restrict__ H1) {
    __shared__ __align__(16) float As[2][128][16];
    __shared__ __align__(16) float Bs[2][2048];

    const bool p1 = (int)blockIdx.x >= NB0;
    const int  b  = p1 ? (int)blockIdx.x - NB0 : (int)blockIdx.x;
    const float* __restrict__ A = p1 ? A1 : A0;
    const float* __restrict__ W = p1 ? W1 : W0;
    const float* __restrict__ bias = p1 ? b1 : b0;
    float* __restrict__ C = p1 ? C1 : C0;
    unsigned short* __restrict__ H = p1 ? H1 : H0;
    const int K = p1 ? D_S : D_C;

    const int bn = (b & 7) * 128;
    const int bm = (b >> 3) * 128;

    const int tid = threadIdx.x;
    const int tx = tid & 15, ty = tid >> 4;

    int a_off[2], w_off[2];
#pragma unroll
    for (int i = 0; i < 2; ++i) {
        const int idx = tid + i * 256;
        const int r = idx >> 2, q = idx & 3;
        a_off[i] = r * K + (q ^ ((r >> 3) & 3)) * 4;
        const int s = idx & 63;
        const int kloc = 2 * (idx >> 6) + ((s >> 4) & 1);
        const int cb   = 2 * (s & 15) + (s >> 5);
        w_off[i] = kloc * D_S + cb * 4;
    }

#define STAGE(bufi, k0)                                                        \
    {                                                                          \
        _Pragma("unroll")                                                      \
        for (int i = 0; i < 2; ++i) {                                          \
            const int idx = tid + i * 256;                                     \
            GLOAD_LDS16(A + (size_t)bm * K + (k0) + a_off[i],                  \
                        (char*)&As[bufi][0][0] + idx * 16);                    \
            GLOAD_LDS16(W + (size_t)(k0) * D_S + bn + w_off[i],                \
                        (char*)&Bs[bufi][0] + idx * 16);                       \
        }                                                                      \
    }

    float acc[8][8] = {};

    STAGE(0, 0);
    __syncthreads();

    const int nk = K / 16;
    for (int t = 0; t < nk; ++t) {
        const int cur = t & 1;
        if (t + 1 < nk) STAGE(t & 1 ? 0 : 1, (t + 1) * 16);

        const float* __restrict__ Bf = &Bs[cur][0];
#pragma unroll
        for (int kq = 0; kq < 4; ++kq) {
            f32x4 a4[8];
#pragma unroll
            for (int i = 0; i < 8; ++i)
                a4[i] = *reinterpret_cast<const f32x4*>(
                    &As[cur][ty * 8 + i][(kq ^ (ty & 3)) * 4]);
#pragma unroll
            for (int k2 = 0; k2 < 4; ++k2) {
                const int k = kq * 4 + k2;
                const int boff = (k >> 1) * 256 + (tx + ((k & 1) << 4)) * 4;
                const f32x4 bx = *reinterpret_cast<const f32x4*>(Bf + boff);
                const f32x4 by = *reinterpret_cast<const f32x4*>(Bf + boff + 128);
                const float bv[8] = {bx[0], bx[1], bx[2], bx[3], by[0], by[1], by[2], by[3]};
#pragma unroll
                for (int i = 0; i < 8; ++i) {
                    const float av = a4[i][k2];
#pragma unroll
                    for (int j = 0; j < 8; ++j)
                        acc[i][j] = fmaf(av, bv[j], acc[i][j]);
                }
            }
        }
        __syncthreads();
    }
#undef STAGE

    const f32x4 g0 = *reinterpret_cast<const f32x4*>(&bias[bn + tx * 8]);
    const f32x4 g1 = *reinterpret_cast<const f32x4*>(&bias[bn + tx * 8 + 4]);
#pragma unroll
    for (int i = 0; i < 8; ++i) {
        const int m = bm + ty * 8 + i;
        const int n = bn + tx * 8;
        f32x4 o0, o1;
#pragma unroll
        for (int j = 0; j < 4; ++j) {
            o0[j] = fmaxf(acc[i][j]     + g0[j], 0.f);
            o1[j] = fmaxf(acc[i][j + 4] + g1[j], 0.f);
        }
        *reinterpret_cast<f32x4*>(&C[(size_t)m * D_S + n])     = o0;
        *reinterpret_cast<f32x4*>(&C[(size_t)m * D_S + n + 4]) = o1;
        short8 h;
#pragma unroll
        for (int j = 0; j < 4; ++j) {
            h[j]     = (short)f2bf(o0[j]);
            h[j + 4] = (short)f2bf(o1[j]);
        }
        *reinterpret_cast<short8*>(&H[(size_t)m * D_S + n]) = h;
    }
}

// ---------------------------------------------------------------------------
// Kernel 2: bf16 MFMA score filter (round-10 reshape, same as transform):
// 128-thread blocks, 2 waves; block 128(n) x 128(c); wave tile 128(n) x 64(c).
// BK=32 swizzle + 2-phase stage-ahead dbuf unchanged.
// acc[i][j]: n = n0 + i*16 + lg*4 + q;  c = c0 + wv*64 + j*16 + lr.
// ---------------------------------------------------------------------------
__global__ __launch_bounds__(128)
void scores_filter(const unsigned short* __restrict__ TSh,
                   const unsigned short* __restrict__ TCh,
                   unsigned short* __restrict__ G) {
    __shared__ __align__(16) unsigned short sA[2][128 * 32];
    __shared__ __align__(16) unsigned short sB[2][128 * 32];
    const int tid  = threadIdx.x;
    const int lane = tid & 63;
    const int wv   = tid >> 6;
    const int lr   = lane & 15, lg = lane >> 4;
    const int n0   = blockIdx.x * 128;
    const int c0   = blockIdx.y * 128;

    const f32x4 vzero = {0.f, 0.f, 0.f, 0.f};
    f32x4 acc[8][4];
#pragma unroll
    for (int i = 0; i < 8; ++i)
#pragma unroll
        for (int j = 0; j < 4; ++j) acc[i][j] = vzero;

#define FSTAGE(bufi, kb)                                                       \
    {                                                                          \
        _Pragma("unroll")                                                      \
        for (int i = 0; i < 4; ++i) {                                          \
            const int idx = tid + i * 128;                                     \
            const int r   = idx >> 2;                                          \
            const int sw  = ((idx & 3) ^ ((r >> 1) & 3)) * 8;                  \
            GLOAD_LDS16(TSh + (size_t)(n0 + r) * D_S + (kb) + sw,              \
                        (char*)&sA[bufi][0] + idx * 16);                       \
            GLOAD_LDS16(TCh + (size_t)(c0 + r) * D_S + (kb) + sw,              \
                        (char*)&sB[bufi][0] + idx * 16);                       \
        }                                                                      \
    }

    FSTAGE(0, 0);
    __syncthreads();

    for (int kc = 0; kc < 32; ++kc) {
        const int cur = kc & 1;
        if (kc + 1 < 32) FSTAGE(cur ^ 1, (kc + 1) * 32);

        short8 a[8], b[4];
#pragma unroll
        for (int i = 0; i < 8; ++i) {
            const int ra = i * 16 + lr;
            a[i] = *(const short8*)((const char*)&sA[cur][0] + ra * 64 +
                                    ((lg ^ ((ra >> 1) & 3)) * 16));
        }
#pragma unroll
        for (int j = 0; j < 4; ++j) {
            const int rb = wv * 64 + j * 16 + lr;
            b[j] = *(const short8*)((const char*)&sB[cur][0] + rb * 64 +
                                    ((lg ^ ((rb >> 1) & 3)) * 16));
        }
#pragma unroll
        for (int i = 0; i < 8; ++i)
#pragma unroll
            for (int j = 0; j < 4; ++j)
                acc[i][j] = __builtin_amdgcn_mfma_f32_16x16x32_bf16(
                    a[i], b[j], acc[i][j], 0, 0, 0);
        __syncthreads();
    }
#undef FSTAGE

    // extraction: per-lane q-run is 4 consecutive n => natural 4-wide group max
#pragma unroll
    for (int i = 0; i < 8; ++i) {
        const int n4 = (n0 >> 2) + i * 4 + lg;
#pragma unroll
        for (int j = 0; j < 4; ++j) {
            const int c = c0 + wv * 64 + j * 16 + lr;
            const f32x4 v = acc[i][j];
            const float m = fmaxf(fmaxf(v.x, v.y), fmaxf(v.z, v.w));
            G[(size_t)c * NGRP + n4] = f2bf(m);
        }
    }
}

// ---------------------------------------------------------------------------
// Kernel 3: per comment row, top-8 groups by approx group-max (unchanged).
// ---------------------------------------------------------------------------
__global__ __launch_bounds__(256)
void top_groups(const unsigned short* __restrict__ G, int* __restrict__ g8) {
    const int w = threadIdx.x >> 6, lane = threadIdx.x & 63;
    const int row = blockIdx.x * 4 + w;
    float v[32];
    const unsigned short* gp = G + (size_t)row * NGRP + lane * 32;
#pragma unroll
    for (int i = 0; i < 4; ++i) {
        short8 h = *(const short8*)(gp + i * 8);
#pragma unroll
        for (int j = 0; j < 8; ++j) v[i * 8 + j] = bf2f((unsigned short)h[j]);
    }
    float pv = INFINITY; int pi = -1;
    int gl[8];
#pragma unroll
    for (int k = 0; k < 8; ++k) {
        float bv = -INFINITY; int bi = NGRP;
#pragma unroll
        for (int i = 0; i < 32; ++i) {
            const int idx = lane * 32 + i;
            const bool after  = (v[i] < pv) || (v[i] == pv && idx > pi);
            const bool before = (v[i] > bv) || (v[i] == bv && idx < bi);
            if (after && before) { bv = v[i]; bi = idx; }
        }
#pragma unroll
        for (int off = 32; off >= 1; off >>= 1) {
            const float ov = __shfl_xor(bv, off);
            const int   oi = __shfl_xor(bi, off);
            if ((ov > bv) || (ov == bv && oi < bi)) { bv = ov; bi = oi; }
        }
        gl[k] = bi; pv = bv; pi = bi;
    }
#pragma unroll
    for (int a = 0; a < 8; ++a)
#pragma unroll
        for (int b2 = 0; b2 < 7; ++b2)
            if (gl[b2] > gl[b2 + 1]) { int t = gl[b2]; gl[b2] = gl[b2 + 1]; gl[b2 + 1] = t; }
    if (lane == 0) {
        int4 lo = make_int4(gl[0], gl[1], gl[2], gl[3]);
        int4 hi = make_int4(gl[4], gl[5], gl[6], gl[7]);
        *reinterpret_cast<int4*>(g8 + (size_t)row * 8)     = lo;
        *reinterpret_cast<int4*>(g8 + (size_t)row * 8 + 4) = hi;
    }
}

// ---------------------------------------------------------------------------
// Kernel 4: exact fp32 refine of the 32 candidates per row (unchanged).
// ---------------------------------------------------------------------------
__global__ __launch_bounds__(256)
void refine(const float* __restrict__ t_c, const float* __restrict__ t_s,
            const int* __restrict__ g8, int* __restrict__ tidx) {
    __shared__ float tc[D_S];
    __shared__ float sc[4 * PGRP];
    const int row = blockIdx.x;
    const int tid = threadIdx.x;
    *reinterpret_cast<float4*>(&tc[tid * 4]) =
        *reinterpret_cast<const float4*>(&t_c[(size_t)row * D_S + tid * 4]);
    __syncthreads();
    const int w = tid >> 6, lane = tid & 63;
    float4 c4[4];
#pragma unroll
    for (int q = 0; q < 4; ++q)
        c4[q] = *reinterpret_cast<const float4*>(&tc[lane * 16 + q * 4]);
#pragma unroll
    for (int i = 0; i < 2; ++i) {
        const int slotg = w * 2 + i;
        const int g = g8[(size_t)row * 8 + slotg];
#pragma unroll
        for (int o = 0; o < 4; ++o) {
            const int n = g * 4 + o;
            const float* ts = t_s + (size_t)n * D_S + lane * 16;
            float p = 0.f;
#pragma unroll
            for (int q = 0; q < 4; ++q) {
                const float4 tv = *reinterpret_cast<const float4*>(ts + q * 4);
                p += c4[q].x * tv.x + c4[q].y * tv.y + c4[q].z * tv.z + c4[q].w * tv.w;
            }
#pragma unroll
            for (int off = 32; off >= 1; off >>= 1) p += __shfl_xor(p, off);
            if (lane == 0) sc[slotg * 4 + o] = p;
        }
    }
    __syncthreads();
    if (tid == 0) {
        float v1 = -INFINITY, v2 = -INFINITY; int i1 = 0, i2 = 0;
#pragma unroll
        for (int s = 0; s < 4 * PGRP; ++s) {
            const int n = g8[(size_t)row * 8 + (s >> 2)] * 4 + (s & 3);
            const float v = sc[s];
            if (v > v1)      { v2 = v1; i2 = i1; v1 = v; i1 = n; }
            else if (v > v2) { v2 = v; i2 = n; }
        }
        tidx[row * 2 + 0] = i1;
        tidx[row * 2 + 1] = i2;
    }
}

// ---------------------------------------------------------------------------
// Kernel 5: gather selected transformed-srt rows (unchanged).
// ---------------------------------------------------------------------------
__global__ __launch_bounds__(256)
void gather_rows(const float* __restrict__ TS, const int* __restrict__ topIdx,
                 float* __restrict__ out) {
    const int row = blockIdx.x;
    const int src = topIdx[row];
    const int tid = threadIdx.x;
    const float4 v = *reinterpret_cast<const float4*>(&TS[(size_t)src * D_S + tid * 4]);
    *reinterpret_cast<float4*>(&out[(size_t)row * D_S + tid * 4]) = v;
}

// ---------------------------------------------------------------------------
extern "C" void kernel_launch(void* const* d_in, const int* in_sizes, int n_in,
                              void* d_out, int out_size, void* d_ws, size_t ws_size,
                              hipStream_t stream) {
    const float* srt      = (const float*)d_in[0];  // [8192,1024]
    const float* comments = (const float*)d_in[1];  // [4096,768]
    const float* Wc       = (const float*)d_in[2];  // [768,1024]
    const float* bc       = (const float*)d_in[3];  // [1024]
    const float* Ws       = (const float*)d_in[4];  // [1024,1024]
    const float* bs       = (const float*)d_in[5];  // [1024]
    float* out = (float*)d_out;

    // base workspace layout (identical to previous rounds)
    char* p = (char*)d_ws;
    float* t_c = (float*)p;          p += (size_t)B_C * D_S * 4;     // 16 MB
    float* t_s = (float*)p;          p += (size_t)N_SRT * D_S * 4;   // 32 MB
    unsigned short* tc_h = (unsigned short*)p; p += (size_t)B_C * D_S * 2;    // 8 MB
    unsigned short* ts_h = (unsigned short*)p; p += (size_t)N_SRT * D_S * 2;  // 16 MB
    unsigned short* G    = (unsigned short*)p; p += (size_t)B_C * NGRP * 2;   // 16 MB
    int* g8   = (int*)p;             p += (size_t)B_C * PGRP * 4;
    int* tidx = (int*)p;             p += (size_t)B_C * KSEL * 4;

    // fp16 2-plane workspace (appended; ~53.4 MB)
    _Float16* actS = (_Float16*)p; p += 2 * (size_t)N_SRT * D_S * 2; // 33.5 MB
    _Float16* actC = (_Float16*)p; p += 2 * (size_t)B_C * D_C * 2;   // 12.6 MB
    _Float16* wtS  = (_Float16*)p; p += 2 * (size_t)D_S * D_S * 2;   // 4.2 MB
    _Float16* wtC  = (_Float16*)p; p += 2 * (size_t)D_S * D_C * 2;   // 3.1 MB
    const size_t required = (size_t)(p - (char*)d_ws);

    if (ws_size >= required) {
        // --- scaled fp16x3 MFMA transform path (single fused launch) ---
        split_act<<<(N_SRT * D_S / 8 + B_C * D_C / 8) / 256, 256, 0, stream>>>(
            srt, comments, actS, actC);
        split_w<<<dim3(D_S / 64, D_S / 64), 256, 0, stream>>>(Ws, wtS, D_S);
        split_w<<<dim3(D_S / 64, D_C / 64), 256, 0, stream>>>(Wc, wtC, D_C);

        transform_mfma_all<<<512 + 256, 128, 0, stream>>>(
            actS, wtS, bs, t_s, ts_h,
            actC, wtC, bc, t_c, tc_h);
    } else {
        // --- fallback: round-5 verified fp32 VALU path ---
        transform_fused<<<NB0 + NB1, 256, 0, stream>>>(
            comments, Wc, bc, t_c, tc_h,
            srt,      Ws, bs, t_s, ts_h);
    }

    scores_filter<<<dim3(N_SRT / 128, B_C / 128), 128, 0, stream>>>(ts_h, tc_h, G);
    top_groups<<<B_C / 4, 256, 0, stream>>>(G, g8);
    refine<<<B_C, 256, 0, stream>>>(t_c, t_s, g8, tidx);
    gather_rows<<<B_C * KSEL, 256, 0, stream>>>(t_s, tidx, out);
}

// Round 11
// 288.292 us; speedup vs baseline: 1.1516x; 1.1516x over previous
//
#include <hip/hip_runtime.h>
#include <math.h>

#define B_C   4096   // comments
#define N_SRT 8192   // srt rows
#define D_C   768
#define D_S   1024
#define KSEL  2
#define NGRP  (N_SRT / 4)   // 2048 groups of 4 consecutive srt rows
#define PGRP  8             // groups refined per comment row (32 candidates)

typedef float    f32x4  __attribute__((ext_vector_type(4)));
typedef short    short8 __attribute__((ext_vector_type(8)));
typedef _Float16 half8  __attribute__((ext_vector_type(8)));

__device__ inline unsigned short f2bf(float f) {           // RTNE float->bf16
    unsigned u = __float_as_uint(f);
    u += 0x7FFF + ((u >> 16) & 1);
    return (unsigned short)(u >> 16);
}
__device__ inline float bf2f(unsigned short h) {
    return __uint_as_float(((unsigned)h) << 16);
}

#define GLOAD_LDS16(gsrc, ldst)                                                     \
    __builtin_amdgcn_global_load_lds(                                               \
        (const __attribute__((address_space(1))) void*)(gsrc),                      \
        (__attribute__((address_space(3))) void*)(ldst), 16, 0, 0)

// counted-vmcnt barrier pieces (T4): tile in flight stays across the barrier
#define WAIT_VM4  asm volatile("s_waitcnt vmcnt(4)" ::: "memory")
#define WAIT_VM0  asm volatile("s_waitcnt vmcnt(0)" ::: "memory")
#define WAIT_LGKM asm volatile("s_waitcnt lgkmcnt(0)" ::: "memory")

// ---------------------------------------------------------------------------
// split_act: fp16 2-term split of activations. Plane0 = f16(x) (scale 1),
// plane1 = f16(2^11 * (x - plane0)) (scale 2^11). Residual <= 2^-22 |x|.
// ---------------------------------------------------------------------------
__global__ __launch_bounds__(256)
void split_act(const float* __restrict__ srt, const float* __restrict__ com,
               _Float16* __restrict__ pS, _Float16* __restrict__ pC) {
    const int g = blockIdx.x * 256 + threadIdx.x;   // one 8-elem group / thread
    const int E0 = N_SRT * D_S / 8;
    const float* src;
    _Float16* dst;
    size_t stride;
    if (g < E0) {
        src = srt + (size_t)g * 8; dst = pS + (size_t)g * 8;
        stride = (size_t)N_SRT * D_S;
    } else {
        const int g2 = g - E0;
        src = com + (size_t)g2 * 8; dst = pC + (size_t)g2 * 8;
        stride = (size_t)B_C * D_C;
    }
    const float4 a = *reinterpret_cast<const float4*>(src);
    const float4 b = *reinterpret_cast<const float4*>(src + 4);
    const float x[8] = {a.x, a.y, a.z, a.w, b.x, b.y, b.z, b.w};
    half8 hv, mv;
#pragma unroll
    for (int j = 0; j < 8; ++j) {
        const _Float16 h = (_Float16)x[j];
        const float    r = x[j] - (float)h;          // exact
        hv[j] = h; mv[j] = (_Float16)(r * 2048.0f);
    }
    *reinterpret_cast<half8*>(dst)          = hv;
    *reinterpret_cast<half8*>(dst + stride) = mv;
}

// ---------------------------------------------------------------------------
// split_w: W[k][n] -> 2 fp16 planes of W^T: Wt[p][n][k]. Plane0 = f16(2^15 W)
// (scale 2^15), plane1 = f16(2^11 * residual) (scale 2^26). 64x64 LDS
// transpose, pad 65.
// ---------------------------------------------------------------------------
__global__ __launch_bounds__(256)
void split_w(const float* __restrict__ W, _Float16* __restrict__ Wt, int K) {
    __shared__ float t[64][65];
    const int n0 = blockIdx.x * 64, k0 = blockIdx.y * 64;
    const int tid = threadIdx.x;
    const int c = tid & 63, rq = tid >> 6;
#pragma unroll
    for (int j = 0; j < 16; ++j) {
        const int kr = rq * 16 + j;
        t[kr][c] = W[(size_t)(k0 + kr) * D_S + n0 + c];
    }
    __syncthreads();
    const size_t PS = (size_t)K * D_S;
#pragma unroll
    for (int j = 0; j < 16; ++j) {
        const int nr = rq * 16 + j;
        const float xs = t[c][nr] * 32768.0f;        // exact (pow2 scale)
        const _Float16 h = (_Float16)xs;
        const float    r = xs - (float)h;            // exact
        const size_t o = (size_t)(n0 + nr) * K + k0 + c;
        Wt[o]      = h;
        Wt[o + PS] = (_Float16)(r * 2048.0f);
    }
}

// ---------------------------------------------------------------------------
// transform_mfma_all: round-9 verified geometry (256 threads, 4 waves 2x2,
// 128x128 tile, 64x64 wave tile, BK=32, XOR swizzle, XCD-chunked swizzle,
// scaled fp16x3 single-accumulator) with round-11 sync: LDS triple-buffer
// (48KB, still 3 blocks/CU) + counted vmcnt(4) + raw s_barrier. The 2-phase
// __syncthreads drained vmcnt to 0 every step (~500cy, 55% of step time by
// round-9 cycle accounting / m233); now tile t+2's loads stay in flight
// across the barrier, only tile t+1 (issued a full step ago) is awaited.
// Hazard sketch: stage(t+2) targets buf last READ at step t-1, whose reads
// completed before barrier(t-1) via lgkmcnt(0); reads of tile t+2 are
// covered by barrier(t+1)'s vmcnt(4). Tail steps drain vmcnt(0).
// ---------------------------------------------------------------------------
__global__ __launch_bounds__(256)
void transform_mfma_all(const _Float16* __restrict__ actS,
                        const _Float16* __restrict__ wtS,
                        const float* __restrict__ bS,
                        float* __restrict__ CS, unsigned short* __restrict__ HS,
                        const _Float16* __restrict__ actC,
                        const _Float16* __restrict__ wtC,
                        const float* __restrict__ bC,
                        float* __restrict__ CC, unsigned short* __restrict__ HC) {
    __shared__ __align__(16) _Float16 sA[3][128 * 32];  // Wt tiles (8KB each)
    __shared__ __align__(16) _Float16 sB[3][128 * 32];  // Act tiles
    const int tid  = threadIdx.x;
    const int lane = tid & 63;
    const int w    = tid >> 6;
    const int lr   = lane & 15, lg = lane >> 4;
    const int wn   = w & 1, wc = w >> 1;

    // per-segment XCD-chunked bijective swizzle (512%8==0, 256%8==0)
    const int hw = blockIdx.x;
    int lgid, seg;
    if (hw < 512) { seg = 0; lgid = (hw & 7) * 64 + (hw >> 3); }
    else          { const int h2 = hw - 512; seg = 1; lgid = (h2 & 7) * 32 + (h2 >> 3); }

    const _Float16* __restrict__ actP = seg ? actC : actS;
    const _Float16* __restrict__ wtP  = seg ? wtC  : wtS;
    const float* __restrict__ bias    = seg ? bC   : bS;
    float* __restrict__ C             = seg ? CC   : CS;
    unsigned short* __restrict__ H    = seg ? HC   : HS;
    const int K   = seg ? D_C : D_S;
    const int KC  = seg ? (D_C / 32) : (D_S / 32);    // 24 : 32
    const size_t aps = seg ? (size_t)B_C * D_C : (size_t)N_SRT * D_S;
    const size_t wps = (size_t)D_S * K;

    const int bn = (lgid & 7) * 128;      // out-col tile
    const int bm = (lgid >> 3) * 128;     // act-row tile

    const f32x4 vzero = {0.f, 0.f, 0.f, 0.f};
    f32x4 acc[4][4];
#pragma unroll
    for (int i = 0; i < 4; ++i)
#pragma unroll
        for (int j = 0; j < 4; ++j) acc[i][j] = vzero;

    const int NT = 3 * KC;

    auto stage = [&](int buf, int t) {     // 4 gload_lds / thread / tile
        const int pp = (t >= KC) + (t >= 2 * KC);    // 0,1,2
        const int kb = (t - pp * KC) * 32;
        const _Float16* gA = wtP  + (pp == 2 ? wps : 0) + (size_t)bn * K + kb;
        const _Float16* gB = actP + (pp == 1 ? aps : 0) + (size_t)bm * K + kb;
#pragma unroll
        for (int i = 0; i < 2; ++i) {
            const int idx = tid + i * 256;           // 0..511
            const int r   = idx >> 2;                // row 0..127
            const int sw  = ((idx & 3) ^ ((r >> 1) & 3)) * 8;  // elem offset
            GLOAD_LDS16(gA + (size_t)r * K + sw,
                        (char*)&sA[buf][0] + idx * 16);
            GLOAD_LDS16(gB + (size_t)r * K + sw,
                        (char*)&sB[buf][0] + idx * 16);
        }
    };

    stage(0, 0);
    stage(1, 1);
    WAIT_VM4;                              // tile 0 landed (tile 1 in flight)
    __builtin_amdgcn_s_barrier();

    int cur = 0;
    for (int t = 0; t < NT; ++t) {
        const bool first = (t < KC);       // pp0: scale act frags by 2^11
        const bool more  = (t + 2 < NT);

        half8 a[4], b[4];
#pragma unroll
        for (int t4 = 0; t4 < 4; ++t4) {
            const int ra = wn * 64 + t4 * 16 + lr;
            a[t4] = *(const half8*)((const char*)&sA[cur][0] + ra * 64 +
                                    ((lg ^ ((ra >> 1) & 3)) * 16));
            const int rb = wc * 64 + t4 * 16 + lr;
            b[t4] = *(const half8*)((const char*)&sB[cur][0] + rb * 64 +
                                    ((lg ^ ((rb >> 1) & 3)) * 16));
        }
        if (more) {
            int nx2 = cur + 2; if (nx2 >= 3) nx2 -= 3;
            stage(nx2, t + 2);
        }
        if (first) {
#pragma unroll
            for (int t4 = 0; t4 < 4; ++t4)
                b[t4] = b[t4] * (_Float16)2048.0f;   // exact pow2
        }
#pragma unroll
        for (int i = 0; i < 4; ++i)
#pragma unroll
            for (int j = 0; j < 4; ++j)
                acc[i][j] = __builtin_amdgcn_mfma_f32_16x16x32_f16(
                    a[i], b[j], acc[i][j], 0, 0, 0);

        if (more) { WAIT_VM4; } else { WAIT_VM0; }   // tile t+1 ready
        WAIT_LGKM;                                   // own reads retired
        __builtin_amdgcn_s_barrier();
        ++cur; if (cur == 3) cur = 0;
    }

    // epilogue: n = bn + wn*64 + i*16 + lg*4 + q;  m = bm + wc*64 + j*16 + lr
    const float s2 = 1.4901161193847656e-8f;    // 2^-26
#pragma unroll
    for (int i = 0; i < 4; ++i) {
        const int n = bn + wn * 64 + i * 16 + lg * 4;
        const f32x4 bb = *reinterpret_cast<const f32x4*>(&bias[n]);
#pragma unroll
        for (int j = 0; j < 4; ++j) {
            const int m = bm + wc * 64 + j * 16 + lr;
            f32x4 o;
#pragma unroll
            for (int q = 0; q < 4; ++q)
                o[q] = fmaxf(fmaf(acc[i][j][q], s2, bb[q]), 0.f);
            *reinterpret_cast<f32x4*>(&C[(size_t)m * D_S + n]) = o;
            ushort4 hh;
            hh.x = f2bf(o[0]); hh.y = f2bf(o[1]);
            hh.z = f2bf(o[2]); hh.w = f2bf(o[3]);
            *reinterpret_cast<ushort4*>(&H[(size_t)m * D_S + n]) = hh;
        }
    }
}

// ---------------------------------------------------------------------------
// FALLBACK (round-5 verified): fused fp32 VALU transforms (ws too small).
// ---------------------------------------------------------------------------
#define NB0 ((B_C / 128) * (D_S / 128))     // 256
#define NB1 ((N_SRT / 128) * (D_S / 128))   // 512

__global__ __launch_bounds__(256)
void transform_fused(const float* __restrict__ A0, const float* __restrict__ W0,
                     const float* __restrict__ b0, float* __restrict__ C0,
                     unsigned short* __restrict__ H0,
                     const float* __restrict__ A1, const float* __restrict__ W1,
                     const float* __restrict__ b1, float* __restrict__ C1,
                     unsigned short* __restrict__ H1) {
    __shared__ __align__(16) float As[2][128][16];
    __shared__ __align__(16) float Bs[2][2048];

    const bool p1 = (int)blockIdx.x >= NB0;
    const int  b  = p1 ? (int)blockIdx.x - NB0 : (int)blockIdx.x;
    const float* __restrict__ A = p1 ? A1 : A0;
    const float* __restrict__ W = p1 ? W1 : W0;
    const float* __restrict__ bias = p1 ? b1 : b0;
    float* __restrict__ C = p1 ? C1 : C0;
    unsigned short* __restrict__ H = p1 ? H1 : H0;
    const int K = p1 ? D_S : D_C;

    const int bn = (b & 7) * 128;
    const int bm = (b >> 3) * 128;

    const int tid = threadIdx.x;
    const int tx = tid & 15, ty = tid >> 4;

    int a_off[2], w_off[2];
#pragma unroll
    for (int i = 0; i < 2; ++i) {
        const int idx = tid + i * 256;
        const int r = idx >> 2, q = idx & 3;
        a_off[i] = r * K + (q ^ ((r >> 3) & 3)) * 4;
        const int s = idx & 63;
        const int kloc = 2 * (idx >> 6) + ((s >> 4) & 1);
        const int cb   = 2 * (s & 15) + (s >> 5);
        w_off[i] = kloc * D_S + cb * 4;
    }

#define STAGE(bufi, k0)                                                        \
    {                                                                          \
        _Pragma("unroll")                                                      \
        for (int i = 0; i < 2; ++i) {                                          \
            const int idx = tid + i * 256;                                     \
            GLOAD_LDS16(A + (size_t)bm * K + (k0) + a_off[i],                  \
                        (char*)&As[bufi][0][0] + idx * 16);                    \
            GLOAD_LDS16(W + (size_t)(k0) * D_S + bn + w_off[i],                \
                        (char*)&Bs[bufi][0] + idx * 16);                       \
        }                                                                      \
    }

    float acc[8][8] = {};

    STAGE(0, 0);
    __syncthreads();

    const int nk = K / 16;
    for (int t = 0; t < nk; ++t) {
        const int cur = t & 1;
        if (t + 1 < nk) STAGE(t & 1 ? 0 : 1, (t + 1) * 16);

        const float* __restrict__ Bf = &Bs[cur][0];
#pragma unroll
        for (int kq = 0; kq < 4; ++kq) {
            f32x4 a4[8];
#pragma unroll
            for (int i = 0; i < 8; ++i)
                a4[i] = *reinterpret_cast<const f32x4*>(
                    &As[cur][ty * 8 + i][(kq ^ (ty & 3)) * 4]);
#pragma unroll
            for (int k2 = 0; k2 < 4; ++k2) {
                const int k = kq * 4 + k2;
                const int boff = (k >> 1) * 256 + (tx + ((k & 1) << 4)) * 4;
                const f32x4 bx = *reinterpret_cast<const f32x4*>(Bf + boff);
                const f32x4 by = *reinterpret_cast<const f32x4*>(Bf + boff + 128);
                const float bv[8] = {bx[0], bx[1], bx[2], bx[3], by[0], by[1], by[2], by[3]};
#pragma unroll
                for (int i = 0; i < 8; ++i) {
                    const float av = a4[i][k2];
#pragma unroll
                    for (int j = 0; j < 8; ++j)
                        acc[i][j] = fmaf(av, bv[j], acc[i][j]);
                }
            }
        }
        __syncthreads();
    }
#undef STAGE

    const f32x4 g0 = *reinterpret_cast<const f32x4*>(&bias[bn + tx * 8]);
    const f32x4 g1 = *reinterpret_cast<const f32x4*>(&bias[bn + tx * 8 + 4]);
#pragma unroll
    for (int i = 0; i < 8; ++i) {
        const int m = bm + ty * 8 + i;
        const int n = bn + tx * 8;
        f32x4 o0, o1;
#pragma unroll
        for (int j = 0; j < 4; ++j) {
            o0[j] = fmaxf(acc[i][j]     + g0[j], 0.f);
            o1[j] = fmaxf(acc[i][j + 4] + g1[j], 0.f);
        }
        *reinterpret_cast<f32x4*>(&C[(size_t)m * D_S + n])     = o0;
        *reinterpret_cast<f32x4*>(&C[(size_t)m * D_S + n + 4]) = o1;
        short8 h;
#pragma unroll
        for (int j = 0; j < 4; ++j) {
            h[j]     = (short)f2bf(o0[j]);
            h[j + 4] = (short)f2bf(o1[j]);
        }
        *reinterpret_cast<short8*>(&H[(size_t)m * D_S + n]) = h;
    }
}

// ---------------------------------------------------------------------------
// Kernel 2: bf16 MFMA score filter — round-9 verified geometry (256 threads,
// 4 waves 2x2, 128x128 tile, BK=32, XOR swizzle) with the same round-11
// 3-buffer counted-vmcnt sync as transform_mfma_all.
// ---------------------------------------------------------------------------
__global__ __launch_bounds__(256)
void scores_filter(const unsigned short* __restrict__ TSh,
                   const unsigned short* __restrict__ TCh,
                   unsigned short* __restrict__ G) {
    __shared__ __align__(16) unsigned short sA[3][128 * 32];
    __shared__ __align__(16) unsigned short sB[3][128 * 32];
    const int tid  = threadIdx.x;
    const int lane = tid & 63;
    const int w    = tid >> 6;
    const int lr   = lane & 15, lg = lane >> 4;
    const int wn   = w & 1, wc = w >> 1;
    const int n0   = blockIdx.x * 128;
    const int c0   = blockIdx.y * 128;

    const f32x4 vzero = {0.f, 0.f, 0.f, 0.f};
    f32x4 acc[4][4];
#pragma unroll
    for (int i = 0; i < 4; ++i)
#pragma unroll
        for (int j = 0; j < 4; ++j) acc[i][j] = vzero;

    auto stage = [&](int buf, int kc) {    // 4 gload_lds / thread / tile
        const int kb = kc * 32;
#pragma unroll
        for (int i = 0; i < 2; ++i) {
            const int idx = tid + i * 256;
            const int r   = idx >> 2;
            const int sw  = ((idx & 3) ^ ((r >> 1) & 3)) * 8;
            GLOAD_LDS16(TSh + (size_t)(n0 + r) * D_S + kb + sw,
                        (char*)&sA[buf][0] + idx * 16);
            GLOAD_LDS16(TCh + (size_t)(c0 + r) * D_S + kb + sw,
                        (char*)&sB[buf][0] + idx * 16);
        }
    };

    stage(0, 0);
    stage(1, 1);
    WAIT_VM4;
    __builtin_amdgcn_s_barrier();

    int cur = 0;
    for (int kc = 0; kc < 32; ++kc) {
        const bool more = (kc + 2 < 32);

        short8 a[4], b[4];
#pragma unroll
        for (int t = 0; t < 4; ++t) {
            const int ra = wn * 64 + t * 16 + lr;
            a[t] = *(const short8*)((const char*)&sA[cur][0] + ra * 64 +
                                    ((lg ^ ((ra >> 1) & 3)) * 16));
            const int rb = wc * 64 + t * 16 + lr;
            b[t] = *(const short8*)((const char*)&sB[cur][0] + rb * 64 +
                                    ((lg ^ ((rb >> 1) & 3)) * 16));
        }
        if (more) {
            int nx2 = cur + 2; if (nx2 >= 3) nx2 -= 3;
            stage(nx2, kc + 2);
        }
#pragma unroll
        for (int i = 0; i < 4; ++i)
#pragma unroll
            for (int j = 0; j < 4; ++j)
                acc[i][j] = __builtin_amdgcn_mfma_f32_16x16x32_bf16(
                    a[i], b[j], acc[i][j], 0, 0, 0);

        if (more) { WAIT_VM4; } else { WAIT_VM0; }
        WAIT_LGKM;
        __builtin_amdgcn_s_barrier();
        ++cur; if (cur == 3) cur = 0;
    }

    // extraction: per-lane j-run is 4 consecutive n => natural 4-wide group max
#pragma unroll
    for (int nt = 0; nt < 4; ++nt) {
        const int n4 = (n0 >> 2) + wn * 16 + nt * 4 + lg;
#pragma unroll
        for (int ct = 0; ct < 4; ++ct) {
            const int c = c0 + wc * 64 + ct * 16 + lr;
            const f32x4 v = acc[nt][ct];
            const float m = fmaxf(fmaxf(v.x, v.y), fmaxf(v.z, v.w));
            G[(size_t)c * NGRP + n4] = f2bf(m);
        }
    }
}

// ---------------------------------------------------------------------------
// Kernel 3: per comment row, top-8 groups by approx group-max (unchanged).
// ---------------------------------------------------------------------------
__global__ __launch_bounds__(256)
void top_groups(const unsigned short* __restrict__ G, int* __restrict__ g8) {
    const int w = threadIdx.x >> 6, lane = threadIdx.x & 63;
    const int row = blockIdx.x * 4 + w;
    float v[32];
    const unsigned short* gp = G + (size_t)row * NGRP + lane * 32;
#pragma unroll
    for (int i = 0; i < 4; ++i) {
        short8 h = *(const short8*)(gp + i * 8);
#pragma unroll
        for (int j = 0; j < 8; ++j) v[i * 8 + j] = bf2f((unsigned short)h[j]);
    }
    float pv = INFINITY; int pi = -1;
    int gl[8];
#pragma unroll
    for (int k = 0; k < 8; ++k) {
        float bv = -INFINITY; int bi = NGRP;
#pragma unroll
        for (int i = 0; i < 32; ++i) {
            const int idx = lane * 32 + i;
            const bool after  = (v[i] < pv) || (v[i] == pv && idx > pi);
            const bool before = (v[i] > bv) || (v[i] == bv && idx < bi);
            if (after && before) { bv = v[i]; bi = idx; }
        }
#pragma unroll
        for (int off = 32; off >= 1; off >>= 1) {
            const float ov = __shfl_xor(bv, off);
            const int   oi = __shfl_xor(bi, off);
            if ((ov > bv) || (ov == bv && oi < bi)) { bv = ov; bi = oi; }
        }
        gl[k] = bi; pv = bv; pi = bi;
    }
#pragma unroll
    for (int a = 0; a < 8; ++a)
#pragma unroll
        for (int b2 = 0; b2 < 7; ++b2)
            if (gl[b2] > gl[b2 + 1]) { int t = gl[b2]; gl[b2] = gl[b2 + 1]; gl[b2 + 1] = t; }
    if (lane == 0) {
        int4 lo = make_int4(gl[0], gl[1], gl[2], gl[3]);
        int4 hi = make_int4(gl[4], gl[5], gl[6], gl[7]);
        *reinterpret_cast<int4*>(g8 + (size_t)row * 8)     = lo;
        *reinterpret_cast<int4*>(g8 + (size_t)row * 8 + 4) = hi;
    }
}

// ---------------------------------------------------------------------------
// Kernel 4: exact fp32 refine of the 32 candidates per row (unchanged).
// ---------------------------------------------------------------------------
__global__ __launch_bounds__(256)
void refine(const float* __restrict__ t_c, const float* __restrict__ t_s,
            const int* __restrict__ g8, int* __restrict__ tidx) {
    __shared__ float tc[D_S];
    __shared__ float sc[4 * PGRP];
    const int row = blockIdx.x;
    const int tid = threadIdx.x;
    *reinterpret_cast<float4*>(&tc[tid * 4]) =
        *reinterpret_cast<const float4*>(&t_c[(size_t)row * D_S + tid * 4]);
    __syncthreads();
    const int w = tid >> 6, lane = tid & 63;
    float4 c4[4];
#pragma unroll
    for (int q = 0; q < 4; ++q)
        c4[q] = *reinterpret_cast<const float4*>(&tc[lane * 16 + q * 4]);
#pragma unroll
    for (int i = 0; i < 2; ++i) {
        const int slotg = w * 2 + i;
        const int g = g8[(size_t)row * 8 + slotg];
#pragma unroll
        for (int o = 0; o < 4; ++o) {
            const int n = g * 4 + o;
            const float* ts = t_s + (size_t)n * D_S + lane * 16;
            float p = 0.f;
#pragma unroll
            for (int q = 0; q < 4; ++q) {
                const float4 tv = *reinterpret_cast<const float4*>(ts + q * 4);
                p += c4[q].x * tv.x + c4[q].y * tv.y + c4[q].z * tv.z + c4[q].w * tv.w;
            }
#pragma unroll
            for (int off = 32; off >= 1; off >>= 1) p += __shfl_xor(p, off);
            if (lane == 0) sc[slotg * 4 + o] = p;
        }
    }
    __syncthreads();
    if (tid == 0) {
        float v1 = -INFINITY, v2 = -INFINITY; int i1 = 0, i2 = 0;
#pragma unroll
        for (int s = 0; s < 4 * PGRP; ++s) {
            const int n = g8[(size_t)row * 8 + (s >> 2)] * 4 + (s & 3);
            const float v = sc[s];
            if (v > v1)      { v2 = v1; i2 = i1; v1 = v; i1 = n; }
            else if (v > v2) { v2 = v; i2 = n; }
        }
        tidx[row * 2 + 0] = i1;
        tidx[row * 2 + 1] = i2;
    }
}

// ---------------------------------------------------------------------------
// Kernel 5: gather selected transformed-srt rows (unchanged).
// ---------------------------------------------------------------------------
__global__ __launch_bounds__(256)
void gather_rows(const float* __restrict__ TS, const int* __restrict__ topIdx,
                 float* __restrict__ out) {
    const int row = blockIdx.x;
    const int src = topIdx[row];
    const int tid = threadIdx.x;
    const float4 v = *reinterpret_cast<const float4*>(&TS[(size_t)src * D_S + tid * 4]);
    *reinterpret_cast<float4*>(&out[(size_t)row * D_S + tid * 4]) = v;
}

// ---------------------------------------------------------------------------
extern "C" void kernel_launch(void* const* d_in, const int* in_sizes, int n_in,
                              void* d_out, int out_size, void* d_ws, size_t ws_size,
                              hipStream_t stream) {
    const float* srt      = (const float*)d_in[0];  // [8192,1024]
    const float* comments = (const float*)d_in[1];  // [4096,768]
    const float* Wc       = (const float*)d_in[2];  // [768,1024]
    const float* bc       = (const float*)d_in[3];  // [1024]
    const float* Ws       = (const float*)d_in[4];  // [1024,1024]
    const float* bs       = (const float*)d_in[5];  // [1024]
    float* out = (float*)d_out;

    // base workspace layout (identical to previous rounds)
    char* p = (char*)d_ws;
    float* t_c = (float*)p;          p += (size_t)B_C * D_S * 4;     // 16 MB
    float* t_s = (float*)p;          p += (size_t)N_SRT * D_S * 4;   // 32 MB
    unsigned short* tc_h = (unsigned short*)p; p += (size_t)B_C * D_S * 2;    // 8 MB
    unsigned short* ts_h = (unsigned short*)p; p += (size_t)N_SRT * D_S * 2;  // 16 MB
    unsigned short* G    = (unsigned short*)p; p += (size_t)B_C * NGRP * 2;   // 16 MB
    int* g8   = (int*)p;             p += (size_t)B_C * PGRP * 4;
    int* tidx = (int*)p;             p += (size_t)B_C * KSEL * 4;

    // fp16 2-plane workspace (appended; ~53.4 MB)
    _Float16* actS = (_Float16*)p; p += 2 * (size_t)N_SRT * D_S * 2; // 33.5 MB
    _Float16* actC = (_Float16*)p; p += 2 * (size_t)B_C * D_C * 2;   // 12.6 MB
    _Float16* wtS  = (_Float16*)p; p += 2 * (size_t)D_S * D_S * 2;   // 4.2 MB
    _Float16* wtC  = (_Float16*)p; p += 2 * (size_t)D_S * D_C * 2;   // 3.1 MB
    const size_t required = (size_t)(p - (char*)d_ws);

    if (ws_size >= required) {
        // --- scaled fp16x3 MFMA transform path (single fused launch) ---
        split_act<<<(N_SRT * D_S / 8 + B_C * D_C / 8) / 256, 256, 0, stream>>>(
            srt, comments, actS, actC);
        split_w<<<dim3(D_S / 64, D_S / 64), 256, 0, stream>>>(Ws, wtS, D_S);
        split_w<<<dim3(D_S / 64, D_C / 64), 256, 0, stream>>>(Wc, wtC, D_C);

        transform_mfma_all<<<512 + 256, 256, 0, stream>>>(
            actS, wtS, bs, t_s, ts_h,
            actC, wtC, bc, t_c, tc_h);
    } else {
        // --- fallback: round-5 verified fp32 VALU path ---
        transform_fused<<<NB0 + NB1, 256, 0, stream>>>(
            comments, Wc, bc, t_c, tc_h,
            srt,      Ws, bs, t_s, ts_h);
    }

    scores_filter<<<dim3(N_SRT / 128, B_C / 128), 256, 0, stream>>>(ts_h, tc_h, G);
    top_groups<<<B_C / 4, 256, 0, stream>>>(G, g8);
    refine<<<B_C, 256, 0, stream>>>(t_c, t_s, g8, tidx);
    gather_rows<<<B_C * KSEL, 256, 0, stream>>>(t_s, tidx, out);
}

// Round 12
// 283.105 us; speedup vs baseline: 1.1727x; 1.0183x over previous
//
#include <hip/hip_runtime.h>
#include <math.h>

#define B_C   4096   // comments
#define N_SRT 8192   // srt rows
#define D_C   768
#define D_S   1024
#define KSEL  2
#define NGRP  (N_SRT / 4)   // 2048 groups of 4 consecutive srt rows
#define PGRP  8             // groups refined per comment row (32 candidates)

typedef float    f32x4  __attribute__((ext_vector_type(4)));
typedef short    short8 __attribute__((ext_vector_type(8)));
typedef _Float16 half8  __attribute__((ext_vector_type(8)));

__device__ inline unsigned short f2bf(float f) {           // RTNE float->bf16
    unsigned u = __float_as_uint(f);
    u += 0x7FFF + ((u >> 16) & 1);
    return (unsigned short)(u >> 16);
}
__device__ inline float bf2f(unsigned short h) {
    return __uint_as_float(((unsigned)h) << 16);
}

#define GLOAD_LDS16(gsrc, ldst)                                                     \
    __builtin_amdgcn_global_load_lds(                                               \
        (const __attribute__((address_space(1))) void*)(gsrc),                      \
        (__attribute__((address_space(3))) void*)(ldst), 16, 0, 0)

// counted-vmcnt barrier pieces (T4): tile in flight stays across the barrier
#define WAIT_VM4  asm volatile("s_waitcnt vmcnt(4)" ::: "memory")
#define WAIT_VM0  asm volatile("s_waitcnt vmcnt(0)" ::: "memory")
#define WAIT_LGKM asm volatile("s_waitcnt lgkmcnt(0)" ::: "memory")

// ---------------------------------------------------------------------------
// split_act: fp16 2-term split of activations. Plane0 = f16(x) (scale 1),
// plane1 = f16(2^11 * (x - plane0)) (scale 2^11). Residual <= 2^-22 |x|.
// ---------------------------------------------------------------------------
__global__ __launch_bounds__(256)
void split_act(const float* __restrict__ srt, const float* __restrict__ com,
               _Float16* __restrict__ pS, _Float16* __restrict__ pC) {
    const int g = blockIdx.x * 256 + threadIdx.x;   // one 8-elem group / thread
    const int E0 = N_SRT * D_S / 8;
    const float* src;
    _Float16* dst;
    size_t stride;
    if (g < E0) {
        src = srt + (size_t)g * 8; dst = pS + (size_t)g * 8;
        stride = (size_t)N_SRT * D_S;
    } else {
        const int g2 = g - E0;
        src = com + (size_t)g2 * 8; dst = pC + (size_t)g2 * 8;
        stride = (size_t)B_C * D_C;
    }
    const float4 a = *reinterpret_cast<const float4*>(src);
    const float4 b = *reinterpret_cast<const float4*>(src + 4);
    const float x[8] = {a.x, a.y, a.z, a.w, b.x, b.y, b.z, b.w};
    half8 hv, mv;
#pragma unroll
    for (int j = 0; j < 8; ++j) {
        const _Float16 h = (_Float16)x[j];
        const float    r = x[j] - (float)h;          // exact
        hv[j] = h; mv[j] = (_Float16)(r * 2048.0f);
    }
    *reinterpret_cast<half8*>(dst)          = hv;
    *reinterpret_cast<half8*>(dst + stride) = mv;
}

// ---------------------------------------------------------------------------
// split_w_all (round-12: both weight splits in ONE launch).
// W[k][n] -> 2 fp16 planes of W^T: Wt[p][n][k]. Plane0 = f16(2^15 W),
// plane1 = f16(2^11 * residual) (scale 2^26). 64x64 LDS transpose, pad 65.
// Blocks [0,256) -> Ws (16 n-tiles x 16 k-tiles); [256,448) -> Wc (16 x 12).
// ---------------------------------------------------------------------------
__global__ __launch_bounds__(256)
void split_w_all(const float* __restrict__ Ws, _Float16* __restrict__ WtS,
                 const float* __restrict__ Wc, _Float16* __restrict__ WtC) {
    __shared__ float t[64][65];
    const bool p1 = (int)blockIdx.x >= 256;
    const int  b  = p1 ? (int)blockIdx.x - 256 : (int)blockIdx.x;
    const float* __restrict__ W = p1 ? Wc : Ws;
    _Float16* __restrict__ Wt   = p1 ? WtC : WtS;
    const int K  = p1 ? D_C : D_S;
    const int n0 = (b & 15) * 64, k0 = (b >> 4) * 64;

    const int tid = threadIdx.x;
    const int c = tid & 63, rq = tid >> 6;
#pragma unroll
    for (int j = 0; j < 16; ++j) {
        const int kr = rq * 16 + j;
        t[kr][c] = W[(size_t)(k0 + kr) * D_S + n0 + c];
    }
    __syncthreads();
    const size_t PS = (size_t)K * D_S;
#pragma unroll
    for (int j = 0; j < 16; ++j) {
        const int nr = rq * 16 + j;
        const float xs = t[c][nr] * 32768.0f;        // exact (pow2 scale)
        const _Float16 h = (_Float16)xs;
        const float    r = xs - (float)h;            // exact
        const size_t o = (size_t)(n0 + nr) * K + k0 + c;
        Wt[o]      = h;
        Wt[o + PS] = (_Float16)(r * 2048.0f);
    }
}

// ---------------------------------------------------------------------------
// transform_mfma_all: round-11 verified structure (256 threads, 4 waves 2x2,
// 128x128 tile, BK=32, XOR swizzle, XCD-chunked swizzle, 3-buffer LDS with
// counted vmcnt(4) + raw s_barrier, scaled fp16x3 single accumulator) plus
// round-12 T5: s_setprio(1) around the MFMA cluster (the counted-vmcnt
// staging gives waves different roles at an instant -> scheduler has
// something to arbitrate; evidence range 0..+34%).
// ---------------------------------------------------------------------------
__global__ __launch_bounds__(256)
void transform_mfma_all(const _Float16* __restrict__ actS,
                        const _Float16* __restrict__ wtS,
                        const float* __restrict__ bS,
                        float* __restrict__ CS, unsigned short* __restrict__ HS,
                        const _Float16* __restrict__ actC,
                        const _Float16* __restrict__ wtC,
                        const float* __restrict__ bC,
                        float* __restrict__ CC, unsigned short* __restrict__ HC) {
    __shared__ __align__(16) _Float16 sA[3][128 * 32];  // Wt tiles (8KB each)
    __shared__ __align__(16) _Float16 sB[3][128 * 32];  // Act tiles
    const int tid  = threadIdx.x;
    const int lane = tid & 63;
    const int w    = tid >> 6;
    const int lr   = lane & 15, lg = lane >> 4;
    const int wn   = w & 1, wc = w >> 1;

    // per-segment XCD-chunked bijective swizzle (512%8==0, 256%8==0)
    const int hw = blockIdx.x;
    int lgid, seg;
    if (hw < 512) { seg = 0; lgid = (hw & 7) * 64 + (hw >> 3); }
    else          { const int h2 = hw - 512; seg = 1; lgid = (h2 & 7) * 32 + (h2 >> 3); }

    const _Float16* __restrict__ actP = seg ? actC : actS;
    const _Float16* __restrict__ wtP  = seg ? wtC  : wtS;
    const float* __restrict__ bias    = seg ? bC   : bS;
    float* __restrict__ C             = seg ? CC   : CS;
    unsigned short* __restrict__ H    = seg ? HC   : HS;
    const int K   = seg ? D_C : D_S;
    const int KC  = seg ? (D_C / 32) : (D_S / 32);    // 24 : 32
    const size_t aps = seg ? (size_t)B_C * D_C : (size_t)N_SRT * D_S;
    const size_t wps = (size_t)D_S * K;

    const int bn = (lgid & 7) * 128;      // out-col tile
    const int bm = (lgid >> 3) * 128;     // act-row tile

    const f32x4 vzero = {0.f, 0.f, 0.f, 0.f};
    f32x4 acc[4][4];
#pragma unroll
    for (int i = 0; i < 4; ++i)
#pragma unroll
        for (int j = 0; j < 4; ++j) acc[i][j] = vzero;

    const int NT = 3 * KC;

    auto stage = [&](int buf, int t) {     // 4 gload_lds / thread / tile
        const int pp = (t >= KC) + (t >= 2 * KC);    // 0,1,2
        const int kb = (t - pp * KC) * 32;
        const _Float16* gA = wtP  + (pp == 2 ? wps : 0) + (size_t)bn * K + kb;
        const _Float16* gB = actP + (pp == 1 ? aps : 0) + (size_t)bm * K + kb;
#pragma unroll
        for (int i = 0; i < 2; ++i) {
            const int idx = tid + i * 256;           // 0..511
            const int r   = idx >> 2;                // row 0..127
            const int sw  = ((idx & 3) ^ ((r >> 1) & 3)) * 8;  // elem offset
            GLOAD_LDS16(gA + (size_t)r * K + sw,
                        (char*)&sA[buf][0] + idx * 16);
            GLOAD_LDS16(gB + (size_t)r * K + sw,
                        (char*)&sB[buf][0] + idx * 16);
        }
    };

    stage(0, 0);
    stage(1, 1);
    WAIT_VM4;                              // tile 0 landed (tile 1 in flight)
    __builtin_amdgcn_s_barrier();

    int cur = 0;
    for (int t = 0; t < NT; ++t) {
        const bool first = (t < KC);       // pp0: scale act frags by 2^11
        const bool more  = (t + 2 < NT);

        half8 a[4], b[4];
#pragma unroll
        for (int t4 = 0; t4 < 4; ++t4) {
            const int ra = wn * 64 + t4 * 16 + lr;
            a[t4] = *(const half8*)((const char*)&sA[cur][0] + ra * 64 +
                                    ((lg ^ ((ra >> 1) & 3)) * 16));
            const int rb = wc * 64 + t4 * 16 + lr;
            b[t4] = *(const half8*)((const char*)&sB[cur][0] + rb * 64 +
                                    ((lg ^ ((rb >> 1) & 3)) * 16));
        }
        if (more) {
            int nx2 = cur + 2; if (nx2 >= 3) nx2 -= 3;
            stage(nx2, t + 2);
        }
        if (first) {
#pragma unroll
            for (int t4 = 0; t4 < 4; ++t4)
                b[t4] = b[t4] * (_Float16)2048.0f;   // exact pow2
        }
        __builtin_amdgcn_s_setprio(1);
#pragma unroll
        for (int i = 0; i < 4; ++i)
#pragma unroll
            for (int j = 0; j < 4; ++j)
                acc[i][j] = __builtin_amdgcn_mfma_f32_16x16x32_f16(
                    a[i], b[j], acc[i][j], 0, 0, 0);
        __builtin_amdgcn_s_setprio(0);

        if (more) { WAIT_VM4; } else { WAIT_VM0; }   // tile t+1 ready
        WAIT_LGKM;                                   // own reads retired
        __builtin_amdgcn_s_barrier();
        ++cur; if (cur == 3) cur = 0;
    }

    // epilogue: n = bn + wn*64 + i*16 + lg*4 + q;  m = bm + wc*64 + j*16 + lr
    const float s2 = 1.4901161193847656e-8f;    // 2^-26
#pragma unroll
    for (int i = 0; i < 4; ++i) {
        const int n = bn + wn * 64 + i * 16 + lg * 4;
        const f32x4 bb = *reinterpret_cast<const f32x4*>(&bias[n]);
#pragma unroll
        for (int j = 0; j < 4; ++j) {
            const int m = bm + wc * 64 + j * 16 + lr;
            f32x4 o;
#pragma unroll
            for (int q = 0; q < 4; ++q)
                o[q] = fmaxf(fmaf(acc[i][j][q], s2, bb[q]), 0.f);
            *reinterpret_cast<f32x4*>(&C[(size_t)m * D_S + n]) = o;
            ushort4 hh;
            hh.x = f2bf(o[0]); hh.y = f2bf(o[1]);
            hh.z = f2bf(o[2]); hh.w = f2bf(o[3]);
            *reinterpret_cast<ushort4*>(&H[(size_t)m * D_S + n]) = hh;
        }
    }
}

// ---------------------------------------------------------------------------
// FALLBACK (round-5 verified): fused fp32 VALU transforms (ws too small).
// ---------------------------------------------------------------------------
#define NB0 ((B_C / 128) * (D_S / 128))     // 256
#define NB1 ((N_SRT / 128) * (D_S / 128))   // 512

__global__ __launch_bounds__(256)
void transform_fused(const float* __restrict__ A0, const float* __restrict__ W0,
                     const float* __restrict__ b0, float* __restrict__ C0,
                     unsigned short* __restrict__ H0,
                     const float* __restrict__ A1, const float* __restrict__ W1,
                     const float* __restrict__ b1, float* __restrict__ C1,
                     unsigned short* __restrict__ H1) {
    __shared__ __align__(16) float As[2][128][16];
    __shared__ __align__(16) float Bs[2][2048];

    const bool p1 = (int)blockIdx.x >= NB0;
    const int  b  = p1 ? (int)blockIdx.x - NB0 : (int)blockIdx.x;
    const float* __restrict__ A = p1 ? A1 : A0;
    const float* __restrict__ W = p1 ? W1 : W0;
    const float* __restrict__ bias = p1 ? b1 : b0;
    float* __restrict__ C = p1 ? C1 : C0;
    unsigned short* __restrict__ H = p1 ? H1 : H0;
    const int K = p1 ? D_S : D_C;

    const int bn = (b & 7) * 128;
    const int bm = (b >> 3) * 128;

    const int tid = threadIdx.x;
    const int tx = tid & 15, ty = tid >> 4;

    int a_off[2], w_off[2];
#pragma unroll
    for (int i = 0; i < 2; ++i) {
        const int idx = tid + i * 256;
        const int r = idx >> 2, q = idx & 3;
        a_off[i] = r * K + (q ^ ((r >> 3) & 3)) * 4;
        const int s = idx & 63;
        const int kloc = 2 * (idx >> 6) + ((s >> 4) & 1);
        const int cb   = 2 * (s & 15) + (s >> 5);
        w_off[i] = kloc * D_S + cb * 4;
    }

#define STAGE(bufi, k0)                                                        \
    {                                                                          \
        _Pragma("unroll")                                                      \
        for (int i = 0; i < 2; ++i) {                                          \
            const int idx = tid + i * 256;                                     \
            GLOAD_LDS16(A + (size_t)bm * K + (k0) + a_off[i],                  \
                        (char*)&As[bufi][0][0] + idx * 16);                    \
            GLOAD_LDS16(W + (size_t)(k0) * D_S + bn + w_off[i],                \
                        (char*)&Bs[bufi][0] + idx * 16);                       \
        }                                                                      \
    }

    float acc[8][8] = {};

    STAGE(0, 0);
    __syncthreads();

    const int nk = K / 16;
    for (int t = 0; t < nk; ++t) {
        const int cur = t & 1;
        if (t + 1 < nk) STAGE(t & 1 ? 0 : 1, (t + 1) * 16);

        const float* __restrict__ Bf = &Bs[cur][0];
#pragma unroll
        for (int kq = 0; kq < 4; ++kq) {
            f32x4 a4[8];
#pragma unroll
            for (int i = 0; i < 8; ++i)
                a4[i] = *reinterpret_cast<const f32x4*>(
                    &As[cur][ty * 8 + i][(kq ^ (ty & 3)) * 4]);
#pragma unroll
            for (int k2 = 0; k2 < 4; ++k2) {
                const int k = kq * 4 + k2;
                const int boff = (k >> 1) * 256 + (tx + ((k & 1) << 4)) * 4;
                const f32x4 bx = *reinterpret_cast<const f32x4*>(Bf + boff);
                const f32x4 by = *reinterpret_cast<const f32x4*>(Bf + boff + 128);
                const float bv[8] = {bx[0], bx[1], bx[2], bx[3], by[0], by[1], by[2], by[3]};
#pragma unroll
                for (int i = 0; i < 8; ++i) {
                    const float av = a4[i][k2];
#pragma unroll
                    for (int j = 0; j < 8; ++j)
                        acc[i][j] = fmaf(av, bv[j], acc[i][j]);
                }
            }
        }
        __syncthreads();
    }
#undef STAGE

    const f32x4 g0 = *reinterpret_cast<const f32x4*>(&bias[bn + tx * 8]);
    const f32x4 g1 = *reinterpret_cast<const f32x4*>(&bias[bn + tx * 8 + 4]);
#pragma unroll
    for (int i = 0; i < 8; ++i) {
        const int m = bm + ty * 8 + i;
        const int n = bn + tx * 8;
        f32x4 o0, o1;
#pragma unroll
        for (int j = 0; j < 4; ++j) {
            o0[j] = fmaxf(acc[i][j]     + g0[j], 0.f);
            o1[j] = fmaxf(acc[i][j + 4] + g1[j], 0.f);
        }
        *reinterpret_cast<f32x4*>(&C[(size_t)m * D_S + n])     = o0;
        *reinterpret_cast<f32x4*>(&C[(size_t)m * D_S + n + 4]) = o1;
        short8 h;
#pragma unroll
        for (int j = 0; j < 4; ++j) {
            h[j]     = (short)f2bf(o0[j]);
            h[j + 4] = (short)f2bf(o1[j]);
        }
        *reinterpret_cast<short8*>(&H[(size_t)m * D_S + n]) = h;
    }
}

// ---------------------------------------------------------------------------
// Kernel 2: bf16 MFMA score filter — round-11 verified structure + T5
// setprio around the MFMA cluster.
// ---------------------------------------------------------------------------
__global__ __launch_bounds__(256)
void scores_filter(const unsigned short* __restrict__ TSh,
                   const unsigned short* __restrict__ TCh,
                   unsigned short* __restrict__ G) {
    __shared__ __align__(16) unsigned short sA[3][128 * 32];
    __shared__ __align__(16) unsigned short sB[3][128 * 32];
    const int tid  = threadIdx.x;
    const int lane = tid & 63;
    const int w    = tid >> 6;
    const int lr   = lane & 15, lg = lane >> 4;
    const int wn   = w & 1, wc = w >> 1;
    const int n0   = blockIdx.x * 128;
    const int c0   = blockIdx.y * 128;

    const f32x4 vzero = {0.f, 0.f, 0.f, 0.f};
    f32x4 acc[4][4];
#pragma unroll
    for (int i = 0; i < 4; ++i)
#pragma unroll
        for (int j = 0; j < 4; ++j) acc[i][j] = vzero;

    auto stage = [&](int buf, int kc) {    // 4 gload_lds / thread / tile
        const int kb = kc * 32;
#pragma unroll
        for (int i = 0; i < 2; ++i) {
            const int idx = tid + i * 256;
            const int r   = idx >> 2;
            const int sw  = ((idx & 3) ^ ((r >> 1) & 3)) * 8;
            GLOAD_LDS16(TSh + (size_t)(n0 + r) * D_S + kb + sw,
                        (char*)&sA[buf][0] + idx * 16);
            GLOAD_LDS16(TCh + (size_t)(c0 + r) * D_S + kb + sw,
                        (char*)&sB[buf][0] + idx * 16);
        }
    };

    stage(0, 0);
    stage(1, 1);
    WAIT_VM4;
    __builtin_amdgcn_s_barrier();

    int cur = 0;
    for (int kc = 0; kc < 32; ++kc) {
        const bool more = (kc + 2 < 32);

        short8 a[4], b[4];
#pragma unroll
        for (int t = 0; t < 4; ++t) {
            const int ra = wn * 64 + t * 16 + lr;
            a[t] = *(const short8*)((const char*)&sA[cur][0] + ra * 64 +
                                    ((lg ^ ((ra >> 1) & 3)) * 16));
            const int rb = wc * 64 + t * 16 + lr;
            b[t] = *(const short8*)((const char*)&sB[cur][0] + rb * 64 +
                                    ((lg ^ ((rb >> 1) & 3)) * 16));
        }
        if (more) {
            int nx2 = cur + 2; if (nx2 >= 3) nx2 -= 3;
            stage(nx2, kc + 2);
        }
        __builtin_amdgcn_s_setprio(1);
#pragma unroll
        for (int i = 0; i < 4; ++i)
#pragma unroll
            for (int j = 0; j < 4; ++j)
                acc[i][j] = __builtin_amdgcn_mfma_f32_16x16x32_bf16(
                    a[i], b[j], acc[i][j], 0, 0, 0);
        __builtin_amdgcn_s_setprio(0);

        if (more) { WAIT_VM4; } else { WAIT_VM0; }
        WAIT_LGKM;
        __builtin_amdgcn_s_barrier();
        ++cur; if (cur == 3) cur = 0;
    }

    // extraction: per-lane j-run is 4 consecutive n => natural 4-wide group max
#pragma unroll
    for (int nt = 0; nt < 4; ++nt) {
        const int n4 = (n0 >> 2) + wn * 16 + nt * 4 + lg;
#pragma unroll
        for (int ct = 0; ct < 4; ++ct) {
            const int c = c0 + wc * 64 + ct * 16 + lr;
            const f32x4 v = acc[nt][ct];
            const float m = fmaxf(fmaxf(v.x, v.y), fmaxf(v.z, v.w));
            G[(size_t)c * NGRP + n4] = f2bf(m);
        }
    }
}

// ---------------------------------------------------------------------------
// Kernel 3: per comment row, top-8 groups by approx group-max (unchanged).
// ---------------------------------------------------------------------------
__global__ __launch_bounds__(256)
void top_groups(const unsigned short* __restrict__ G, int* __restrict__ g8) {
    const int w = threadIdx.x >> 6, lane = threadIdx.x & 63;
    const int row = blockIdx.x * 4 + w;
    float v[32];
    const unsigned short* gp = G + (size_t)row * NGRP + lane * 32;
#pragma unroll
    for (int i = 0; i < 4; ++i) {
        short8 h = *(const short8*)(gp + i * 8);
#pragma unroll
        for (int j = 0; j < 8; ++j) v[i * 8 + j] = bf2f((unsigned short)h[j]);
    }
    float pv = INFINITY; int pi = -1;
    int gl[8];
#pragma unroll
    for (int k = 0; k < 8; ++k) {
        float bv = -INFINITY; int bi = NGRP;
#pragma unroll
        for (int i = 0; i < 32; ++i) {
            const int idx = lane * 32 + i;
            const bool after  = (v[i] < pv) || (v[i] == pv && idx > pi);
            const bool before = (v[i] > bv) || (v[i] == bv && idx < bi);
            if (after && before) { bv = v[i]; bi = idx; }
        }
#pragma unroll
        for (int off = 32; off >= 1; off >>= 1) {
            const float ov = __shfl_xor(bv, off);
            const int   oi = __shfl_xor(bi, off);
            if ((ov > bv) || (ov == bv && oi < bi)) { bv = ov; bi = oi; }
        }
        gl[k] = bi; pv = bv; pi = bi;
    }
#pragma unroll
    for (int a = 0; a < 8; ++a)
#pragma unroll
        for (int b2 = 0; b2 < 7; ++b2)
            if (gl[b2] > gl[b2 + 1]) { int t = gl[b2]; gl[b2] = gl[b2 + 1]; gl[b2 + 1] = t; }
    if (lane == 0) {
        int4 lo = make_int4(gl[0], gl[1], gl[2], gl[3]);
        int4 hi = make_int4(gl[4], gl[5], gl[6], gl[7]);
        *reinterpret_cast<int4*>(g8 + (size_t)row * 8)     = lo;
        *reinterpret_cast<int4*>(g8 + (size_t)row * 8 + 4) = hi;
    }
}

// ---------------------------------------------------------------------------
// Kernel 4 (round-12: fused refine + gather): exact fp32 refine of the 32
// candidates per row -> top-2 indices, then this block directly copies the
// two selected t_s rows to the output (drops the separate gather launch).
// ---------------------------------------------------------------------------
__global__ __launch_bounds__(256)
void refine_gather(const float* __restrict__ t_c, const float* __restrict__ t_s,
                   const int* __restrict__ g8, float* __restrict__ out) {
    __shared__ float tc[D_S];
    __shared__ float sc[4 * PGRP];
    __shared__ int   sel[2];
    const int row = blockIdx.x;
    const int tid = threadIdx.x;
    *reinterpret_cast<float4*>(&tc[tid * 4]) =
        *reinterpret_cast<const float4*>(&t_c[(size_t)row * D_S + tid * 4]);
    __syncthreads();
    const int w = tid >> 6, lane = tid & 63;
    float4 c4[4];
#pragma unroll
    for (int q = 0; q < 4; ++q)
        c4[q] = *reinterpret_cast<const float4*>(&tc[lane * 16 + q * 4]);
#pragma unroll
    for (int i = 0; i < 2; ++i) {
        const int slotg = w * 2 + i;
        const int g = g8[(size_t)row * 8 + slotg];
#pragma unroll
        for (int o = 0; o < 4; ++o) {
            const int n = g * 4 + o;
            const float* ts = t_s + (size_t)n * D_S + lane * 16;
            float p = 0.f;
#pragma unroll
            for (int q = 0; q < 4; ++q) {
                const float4 tv = *reinterpret_cast<const float4*>(ts + q * 4);
                p += c4[q].x * tv.x + c4[q].y * tv.y + c4[q].z * tv.z + c4[q].w * tv.w;
            }
#pragma unroll
            for (int off = 32; off >= 1; off >>= 1) p += __shfl_xor(p, off);
            if (lane == 0) sc[slotg * 4 + o] = p;
        }
    }
    __syncthreads();
    if (tid == 0) {
        float v1 = -INFINITY, v2 = -INFINITY; int i1 = 0, i2 = 0;
#pragma unroll
        for (int s = 0; s < 4 * PGRP; ++s) {
            const int n = g8[(size_t)row * 8 + (s >> 2)] * 4 + (s & 3);
            const float v = sc[s];
            if (v > v1)      { v2 = v1; i2 = i1; v1 = v; i1 = n; }
            else if (v > v2) { v2 = v; i2 = n; }
        }
        sel[0] = i1; sel[1] = i2;
    }
    __syncthreads();
    // gather: copy the two selected rows (1024 floats each) to out
#pragma unroll
    for (int q = 0; q < 2; ++q) {
        const int src = sel[q];
        const float4 v = *reinterpret_cast<const float4*>(
            &t_s[(size_t)src * D_S + tid * 4]);
        *reinterpret_cast<float4*>(
            &out[((size_t)row * KSEL + q) * D_S + tid * 4]) = v;
    }
}

// ---------------------------------------------------------------------------
extern "C" void kernel_launch(void* const* d_in, const int* in_sizes, int n_in,
                              void* d_out, int out_size, void* d_ws, size_t ws_size,
                              hipStream_t stream) {
    const float* srt      = (const float*)d_in[0];  // [8192,1024]
    const float* comments = (const float*)d_in[1];  // [4096,768]
    const float* Wc       = (const float*)d_in[2];  // [768,1024]
    const float* bc       = (const float*)d_in[3];  // [1024]
    const float* Ws       = (const float*)d_in[4];  // [1024,1024]
    const float* bs       = (const float*)d_in[5];  // [1024]
    float* out = (float*)d_out;

    // base workspace layout (identical to previous rounds)
    char* p = (char*)d_ws;
    float* t_c = (float*)p;          p += (size_t)B_C * D_S * 4;     // 16 MB
    float* t_s = (float*)p;          p += (size_t)N_SRT * D_S * 4;   // 32 MB
    unsigned short* tc_h = (unsigned short*)p; p += (size_t)B_C * D_S * 2;    // 8 MB
    unsigned short* ts_h = (unsigned short*)p; p += (size_t)N_SRT * D_S * 2;  // 16 MB
    unsigned short* G    = (unsigned short*)p; p += (size_t)B_C * NGRP * 2;   // 16 MB
    int* g8   = (int*)p;             p += (size_t)B_C * PGRP * 4;
    p += (size_t)B_C * KSEL * 4;     // (tidx slot kept for layout, unused)

    // fp16 2-plane workspace (appended; ~53.4 MB)
    _Float16* actS = (_Float16*)p; p += 2 * (size_t)N_SRT * D_S * 2; // 33.5 MB
    _Float16* actC = (_Float16*)p; p += 2 * (size_t)B_C * D_C * 2;   // 12.6 MB
    _Float16* wtS  = (_Float16*)p; p += 2 * (size_t)D_S * D_S * 2;   // 4.2 MB
    _Float16* wtC  = (_Float16*)p; p += 2 * (size_t)D_S * D_C * 2;   // 3.1 MB
    const size_t required = (size_t)(p - (char*)d_ws);

    if (ws_size >= required) {
        // --- scaled fp16x3 MFMA transform path ---
        split_act<<<(N_SRT * D_S / 8 + B_C * D_C / 8) / 256, 256, 0, stream>>>(
            srt, comments, actS, actC);
        split_w_all<<<256 + 192, 256, 0, stream>>>(Ws, wtS, Wc, wtC);

        transform_mfma_all<<<512 + 256, 256, 0, stream>>>(
            actS, wtS, bs, t_s, ts_h,
            actC, wtC, bc, t_c, tc_h);
    } else {
        // --- fallback: round-5 verified fp32 VALU path ---
        transform_fused<<<NB0 + NB1, 256, 0, stream>>>(
            comments, Wc, bc, t_c, tc_h,
            srt,      Ws, bs, t_s, ts_h);
    }

    scores_filter<<<dim3(N_SRT / 128, B_C / 128), 256, 0, stream>>>(ts_h, tc_h, G);
    top_groups<<<B_C / 4, 256, 0, stream>>>(G, g8);
    refine_gather<<<B_C, 256, 0, stream>>>(t_c, t_s, g8, out);
}

// Round 13
// 279.664 us; speedup vs baseline: 1.1871x; 1.0123x over previous
//
#include <hip/hip_runtime.h>
#include <math.h>

#define B_C   4096   // comments
#define N_SRT 8192   // srt rows
#define D_C   768
#define D_S   1024
#define KSEL  2
#define NGRP  (N_SRT / 4)   // 2048 groups of 4 consecutive srt rows
#define PGRP  8             // groups refined per comment row (32 candidates)

typedef float    f32x4  __attribute__((ext_vector_type(4)));
typedef short    short8 __attribute__((ext_vector_type(8)));
typedef _Float16 half8  __attribute__((ext_vector_type(8)));

__device__ inline unsigned short f2bf(float f) {           // RTNE float->bf16
    unsigned u = __float_as_uint(f);
    u += 0x7FFF + ((u >> 16) & 1);
    return (unsigned short)(u >> 16);
}
__device__ inline float bf2f(unsigned short h) {
    return __uint_as_float(((unsigned)h) << 16);
}

#define GLOAD_LDS16(gsrc, ldst)                                                     \
    __builtin_amdgcn_global_load_lds(                                               \
        (const __attribute__((address_space(1))) void*)(gsrc),                      \
        (__attribute__((address_space(3))) void*)(ldst), 16, 0, 0)

// counted-vmcnt barrier pieces
#define WAIT_VM4  asm volatile("s_waitcnt vmcnt(4)" ::: "memory")
#define WAIT_VM0  asm volatile("s_waitcnt vmcnt(0)" ::: "memory")
#define WAIT_LGKM asm volatile("s_waitcnt lgkmcnt(0)" ::: "memory")

// ---------------------------------------------------------------------------
// split_act: fp16 2-term split of activations. Plane0 = f16(x) (scale 1),
// plane1 = f16(2^11 * (x - plane0)) (scale 2^11). Residual <= 2^-22 |x|.
// ---------------------------------------------------------------------------
__global__ __launch_bounds__(256)
void split_act(const float* __restrict__ srt, const float* __restrict__ com,
               _Float16* __restrict__ pS, _Float16* __restrict__ pC) {
    const int g = blockIdx.x * 256 + threadIdx.x;   // one 8-elem group / thread
    const int E0 = N_SRT * D_S / 8;
    const float* src;
    _Float16* dst;
    size_t stride;
    if (g < E0) {
        src = srt + (size_t)g * 8; dst = pS + (size_t)g * 8;
        stride = (size_t)N_SRT * D_S;
    } else {
        const int g2 = g - E0;
        src = com + (size_t)g2 * 8; dst = pC + (size_t)g2 * 8;
        stride = (size_t)B_C * D_C;
    }
    const float4 a = *reinterpret_cast<const float4*>(src);
    const float4 b = *reinterpret_cast<const float4*>(src + 4);
    const float x[8] = {a.x, a.y, a.z, a.w, b.x, b.y, b.z, b.w};
    half8 hv, mv;
#pragma unroll
    for (int j = 0; j < 8; ++j) {
        const _Float16 h = (_Float16)x[j];
        const float    r = x[j] - (float)h;          // exact
        hv[j] = h; mv[j] = (_Float16)(r * 2048.0f);
    }
    *reinterpret_cast<half8*>(dst)          = hv;
    *reinterpret_cast<half8*>(dst + stride) = mv;
}

// ---------------------------------------------------------------------------
// split_w_all: both weight splits in ONE launch (round-12 verified).
// W[k][n] -> 2 fp16 planes of W^T: Wt[p][n][k]. Plane0 = f16(2^15 W),
// plane1 = f16(2^11 * residual) (scale 2^26). 64x64 LDS transpose, pad 65.
// ---------------------------------------------------------------------------
__global__ __launch_bounds__(256)
void split_w_all(const float* __restrict__ Ws, _Float16* __restrict__ WtS,
                 const float* __restrict__ Wc, _Float16* __restrict__ WtC) {
    __shared__ float t[64][65];
    const bool p1 = (int)blockIdx.x >= 256;
    const int  b  = p1 ? (int)blockIdx.x - 256 : (int)blockIdx.x;
    const float* __restrict__ W = p1 ? Wc : Ws;
    _Float16* __restrict__ Wt   = p1 ? WtC : WtS;
    const int K  = p1 ? D_C : D_S;
    const int n0 = (b & 15) * 64, k0 = (b >> 4) * 64;

    const int tid = threadIdx.x;
    const int c = tid & 63, rq = tid >> 6;
#pragma unroll
    for (int j = 0; j < 16; ++j) {
        const int kr = rq * 16 + j;
        t[kr][c] = W[(size_t)(k0 + kr) * D_S + n0 + c];
    }
    __syncthreads();
    const size_t PS = (size_t)K * D_S;
#pragma unroll
    for (int j = 0; j < 16; ++j) {
        const int nr = rq * 16 + j;
        const float xs = t[c][nr] * 32768.0f;        // exact (pow2 scale)
        const _Float16 h = (_Float16)xs;
        const float    r = xs - (float)h;            // exact
        const size_t o = (size_t)(n0 + nr) * K + k0 + c;
        Wt[o]      = h;
        Wt[o + PS] = (_Float16)(r * 2048.0f);
    }
}

// ---------------------------------------------------------------------------
// transform_mfma_all (round-13: plane-pair CHUNK FUSION).
// Per K-chunk of 32, stage all four tiles {W0, W1, A0, A1} (32KB/buffer,
// 2 buffers = 64KB -> 2 blocks/CU) and compute all three products from one
// residency: acc += W0*(2^11*A0) + W0*A1 + W1*A0, all at scale 2^26.
// 48 MFMA per barrier (vs 16), 16 ds_reads/48 MFMA (vs 24/48), stage
// 32KB/48 MFMA (vs 48KB). Barrier count 96->32 (srt). The ~60% per-step
// fixed overhead (round-12 cycle accounting) is paid 3x less per MFMA.
// Geometry/swizzles/epilogue identical to round-12 (verified).
// ---------------------------------------------------------------------------
__global__ __launch_bounds__(256)
void transform_mfma_all(const _Float16* __restrict__ actS,
                        const _Float16* __restrict__ wtS,
                        const float* __restrict__ bS,
                        float* __restrict__ CS, unsigned short* __restrict__ HS,
                        const _Float16* __restrict__ actC,
                        const _Float16* __restrict__ wtC,
                        const float* __restrict__ bC,
                        float* __restrict__ CC, unsigned short* __restrict__ HC) {
    __shared__ __align__(16) _Float16 sW[2][2][128 * 32];  // [buf][plane], 8KB each
    __shared__ __align__(16) _Float16 sA[2][2][128 * 32];  // [buf][plane]
    const int tid  = threadIdx.x;
    const int lane = tid & 63;
    const int w    = tid >> 6;
    const int lr   = lane & 15, lg = lane >> 4;
    const int wn   = w & 1, wc = w >> 1;

    // per-segment XCD-chunked bijective swizzle (512%8==0, 256%8==0)
    const int hw = blockIdx.x;
    int lgid, seg;
    if (hw < 512) { seg = 0; lgid = (hw & 7) * 64 + (hw >> 3); }
    else          { const int h2 = hw - 512; seg = 1; lgid = (h2 & 7) * 32 + (h2 >> 3); }

    const _Float16* __restrict__ actP = seg ? actC : actS;
    const _Float16* __restrict__ wtP  = seg ? wtC  : wtS;
    const float* __restrict__ bias    = seg ? bC   : bS;
    float* __restrict__ C             = seg ? CC   : CS;
    unsigned short* __restrict__ H    = seg ? HC   : HS;
    const int K   = seg ? D_C : D_S;
    const int NC  = seg ? (D_C / 32) : (D_S / 32);    // 24 : 32 chunks
    const size_t aps = seg ? (size_t)B_C * D_C : (size_t)N_SRT * D_S;
    const size_t wps = (size_t)D_S * K;

    const int bn = (lgid & 7) * 128;      // out-col tile
    const int bm = (lgid >> 3) * 128;     // act-row tile

    const f32x4 vzero = {0.f, 0.f, 0.f, 0.f};
    f32x4 acc[4][4];
#pragma unroll
    for (int i = 0; i < 4; ++i)
#pragma unroll
        for (int j = 0; j < 4; ++j) acc[i][j] = vzero;

    auto stage = [&](int buf, int c) {     // 8 gload_lds / thread / chunk
        const int kb = c * 32;
#pragma unroll
        for (int i = 0; i < 2; ++i) {
            const int idx = tid + i * 256;           // 0..511
            const int r   = idx >> 2;                // row 0..127
            const int sw  = ((idx & 3) ^ ((r >> 1) & 3)) * 8;  // elem offset
            const size_t wo = (size_t)(bn + r) * K + kb + sw;
            const size_t ao = (size_t)(bm + r) * K + kb + sw;
            GLOAD_LDS16(wtP  + wo,       (char*)&sW[buf][0][0] + idx * 16);
            GLOAD_LDS16(wtP  + wps + wo, (char*)&sW[buf][1][0] + idx * 16);
            GLOAD_LDS16(actP + ao,       (char*)&sA[buf][0][0] + idx * 16);
            GLOAD_LDS16(actP + aps + ao, (char*)&sA[buf][1][0] + idx * 16);
        }
    };

    stage(0, 0);
    WAIT_VM0;
    __builtin_amdgcn_s_barrier();

    for (int c = 0; c < NC; ++c) {
        const int cur = c & 1;
        if (c + 1 < NC) stage(cur ^ 1, c + 1);   // loads fly under ds_read+MFMA

        half8 a0[4], a1[4], b0[4], b1[4], b0s[4];
#pragma unroll
        for (int t4 = 0; t4 < 4; ++t4) {
            const int ra = wn * 64 + t4 * 16 + lr;
            const int oa = ra * 64 + ((lg ^ ((ra >> 1) & 3)) * 16);
            a0[t4] = *(const half8*)((const char*)&sW[cur][0][0] + oa);
            a1[t4] = *(const half8*)((const char*)&sW[cur][1][0] + oa);
            const int rb = wc * 64 + t4 * 16 + lr;
            const int ob = rb * 64 + ((lg ^ ((rb >> 1) & 3)) * 16);
            b0[t4] = *(const half8*)((const char*)&sA[cur][0][0] + ob);
            b1[t4] = *(const half8*)((const char*)&sA[cur][1][0] + ob);
            b0s[t4] = b0[t4] * (_Float16)2048.0f;    // exact pow2
        }
        __builtin_amdgcn_s_setprio(1);
#pragma unroll
        for (int i = 0; i < 4; ++i)
#pragma unroll
            for (int j = 0; j < 4; ++j) {
                acc[i][j] = __builtin_amdgcn_mfma_f32_16x16x32_f16(
                    a0[i], b0s[j], acc[i][j], 0, 0, 0);   // hh (2^26)
                acc[i][j] = __builtin_amdgcn_mfma_f32_16x16x32_f16(
                    a0[i], b1[j],  acc[i][j], 0, 0, 0);   // hm (2^26)
                acc[i][j] = __builtin_amdgcn_mfma_f32_16x16x32_f16(
                    a1[i], b0[j],  acc[i][j], 0, 0, 0);   // mh (2^26)
            }
        __builtin_amdgcn_s_setprio(0);

        WAIT_VM0;                                   // next chunk landed
        WAIT_LGKM;                                  // own reads retired
        __builtin_amdgcn_s_barrier();
    }

    // epilogue: n = bn + wn*64 + i*16 + lg*4 + q;  m = bm + wc*64 + j*16 + lr
    const float s2 = 1.4901161193847656e-8f;    // 2^-26
#pragma unroll
    for (int i = 0; i < 4; ++i) {
        const int n = bn + wn * 64 + i * 16 + lg * 4;
        const f32x4 bb = *reinterpret_cast<const f32x4*>(&bias[n]);
#pragma unroll
        for (int j = 0; j < 4; ++j) {
            const int m = bm + wc * 64 + j * 16 + lr;
            f32x4 o;
#pragma unroll
            for (int q = 0; q < 4; ++q)
                o[q] = fmaxf(fmaf(acc[i][j][q], s2, bb[q]), 0.f);
            *reinterpret_cast<f32x4*>(&C[(size_t)m * D_S + n]) = o;
            ushort4 hh;
            hh.x = f2bf(o[0]); hh.y = f2bf(o[1]);
            hh.z = f2bf(o[2]); hh.w = f2bf(o[3]);
            *reinterpret_cast<ushort4*>(&H[(size_t)m * D_S + n]) = hh;
        }
    }
}

// ---------------------------------------------------------------------------
// FALLBACK (round-5 verified): fused fp32 VALU transforms (ws too small).
// ---------------------------------------------------------------------------
#define NB0 ((B_C / 128) * (D_S / 128))     // 256
#define NB1 ((N_SRT / 128) * (D_S / 128))   // 512

__global__ __launch_bounds__(256)
void transform_fused(const float* __restrict__ A0, const float* __restrict__ W0,
                     const float* __restrict__ b0, float* __restrict__ C0,
                     unsigned short* __restrict__ H0,
                     const float* __restrict__ A1, const float* __restrict__ W1,
                     const float* __restrict__ b1, float* __restrict__ C1,
                     unsigned short* __restrict__ H1) {
    __shared__ __align__(16) float As[2][128][16];
    __shared__ __align__(16) float Bs[2][2048];

    const bool p1 = (int)blockIdx.x >= NB0;
    const int  b  = p1 ? (int)blockIdx.x - NB0 : (int)blockIdx.x;
    const float* __restrict__ A = p1 ? A1 : A0;
    const float* __restrict__ W = p1 ? W1 : W0;
    const float* __restrict__ bias = p1 ? b1 : b0;
    float* __restrict__ C = p1 ? C1 : C0;
    unsigned short* __restrict__ H = p1 ? H1 : H0;
    const int K = p1 ? D_S : D_C;

    const int bn = (b & 7) * 128;
    const int bm = (b >> 3) * 128;

    const int tid = threadIdx.x;
    const int tx = tid & 15, ty = tid >> 4;

    int a_off[2], w_off[2];
#pragma unroll
    for (int i = 0; i < 2; ++i) {
        const int idx = tid + i * 256;
        const int r = idx >> 2, q = idx & 3;
        a_off[i] = r * K + (q ^ ((r >> 3) & 3)) * 4;
        const int s = idx & 63;
        const int kloc = 2 * (idx >> 6) + ((s >> 4) & 1);
        const int cb   = 2 * (s & 15) + (s >> 5);
        w_off[i] = kloc * D_S + cb * 4;
    }

#define STAGE(bufi, k0)                                                        \
    {                                                                          \
        _Pragma("unroll")                                                      \
        for (int i = 0; i < 2; ++i) {                                          \
            const int idx = tid + i * 256;                                     \
            GLOAD_LDS16(A + (size_t)bm * K + (k0) + a_off[i],                  \
                        (char*)&As[bufi][0][0] + idx * 16);                    \
            GLOAD_LDS16(W + (size_t)(k0) * D_S + bn + w_off[i],                \
                        (char*)&Bs[bufi][0] + idx * 16);                       \
        }                                                                      \
    }

    float acc[8][8] = {};

    STAGE(0, 0);
    __syncthreads();

    const int nk = K / 16;
    for (int t = 0; t < nk; ++t) {
        const int cur = t & 1;
        if (t + 1 < nk) STAGE(t & 1 ? 0 : 1, (t + 1) * 16);

        const float* __restrict__ Bf = &Bs[cur][0];
#pragma unroll
        for (int kq = 0; kq < 4; ++kq) {
            f32x4 a4[8];
#pragma unroll
            for (int i = 0; i < 8; ++i)
                a4[i] = *reinterpret_cast<const f32x4*>(
                    &As[cur][ty * 8 + i][(kq ^ (ty & 3)) * 4]);
#pragma unroll
            for (int k2 = 0; k2 < 4; ++k2) {
                const int k = kq * 4 + k2;
                const int boff = (k >> 1) * 256 + (tx + ((k & 1) << 4)) * 4;
                const f32x4 bx = *reinterpret_cast<const f32x4*>(Bf + boff);
                const f32x4 by = *reinterpret_cast<const f32x4*>(Bf + boff + 128);
                const float bv[8] = {bx[0], bx[1], bx[2], bx[3], by[0], by[1], by[2], by[3]};
#pragma unroll
                for (int i = 0; i < 8; ++i) {
                    const float av = a4[i][k2];
#pragma unroll
                    for (int j = 0; j < 8; ++j)
                        acc[i][j] = fmaf(av, bv[j], acc[i][j]);
                }
            }
        }
        __syncthreads();
    }
#undef STAGE

    const f32x4 g0 = *reinterpret_cast<const f32x4*>(&bias[bn + tx * 8]);
    const f32x4 g1 = *reinterpret_cast<const f32x4*>(&bias[bn + tx * 8 + 4]);
#pragma unroll
    for (int i = 0; i < 8; ++i) {
        const int m = bm + ty * 8 + i;
        const int n = bn + tx * 8;
        f32x4 o0, o1;
#pragma unroll
        for (int j = 0; j < 4; ++j) {
            o0[j] = fmaxf(acc[i][j]     + g0[j], 0.f);
            o1[j] = fmaxf(acc[i][j + 4] + g1[j], 0.f);
        }
        *reinterpret_cast<f32x4*>(&C[(size_t)m * D_S + n])     = o0;
        *reinterpret_cast<f32x4*>(&C[(size_t)m * D_S + n + 4]) = o1;
        short8 h;
#pragma unroll
        for (int j = 0; j < 4; ++j) {
            h[j]     = (short)f2bf(o0[j]);
            h[j + 4] = (short)f2bf(o1[j]);
        }
        *reinterpret_cast<short8*>(&H[(size_t)m * D_S + n]) = h;
    }
}

// ---------------------------------------------------------------------------
// Kernel 2: bf16 MFMA score filter — round-11/12 verified structure
// (3-buffer counted-vmcnt + setprio). Unchanged.
// ---------------------------------------------------------------------------
__global__ __launch_bounds__(256)
void scores_filter(const unsigned short* __restrict__ TSh,
                   const unsigned short* __restrict__ TCh,
                   unsigned short* __restrict__ G) {
    __shared__ __align__(16) unsigned short sA[3][128 * 32];
    __shared__ __align__(16) unsigned short sB[3][128 * 32];
    const int tid  = threadIdx.x;
    const int lane = tid & 63;
    const int w    = tid >> 6;
    const int lr   = lane & 15, lg = lane >> 4;
    const int wn   = w & 1, wc = w >> 1;
    const int n0   = blockIdx.x * 128;
    const int c0   = blockIdx.y * 128;

    const f32x4 vzero = {0.f, 0.f, 0.f, 0.f};
    f32x4 acc[4][4];
#pragma unroll
    for (int i = 0; i < 4; ++i)
#pragma unroll
        for (int j = 0; j < 4; ++j) acc[i][j] = vzero;

    auto stage = [&](int buf, int kc) {    // 4 gload_lds / thread / tile
        const int kb = kc * 32;
#pragma unroll
        for (int i = 0; i < 2; ++i) {
            const int idx = tid + i * 256;
            const int r   = idx >> 2;
            const int sw  = ((idx & 3) ^ ((r >> 1) & 3)) * 8;
            GLOAD_LDS16(TSh + (size_t)(n0 + r) * D_S + kb + sw,
                        (char*)&sA[buf][0] + idx * 16);
            GLOAD_LDS16(TCh + (size_t)(c0 + r) * D_S + kb + sw,
                        (char*)&sB[buf][0] + idx * 16);
        }
    };

    stage(0, 0);
    stage(1, 1);
    WAIT_VM4;
    __builtin_amdgcn_s_barrier();

    int cur = 0;
    for (int kc = 0; kc < 32; ++kc) {
        const bool more = (kc + 2 < 32);

        short8 a[4], b[4];
#pragma unroll
        for (int t = 0; t < 4; ++t) {
            const int ra = wn * 64 + t * 16 + lr;
            a[t] = *(const short8*)((const char*)&sA[cur][0] + ra * 64 +
                                    ((lg ^ ((ra >> 1) & 3)) * 16));
            const int rb = wc * 64 + t * 16 + lr;
            b[t] = *(const short8*)((const char*)&sB[cur][0] + rb * 64 +
                                    ((lg ^ ((rb >> 1) & 3)) * 16));
        }
        if (more) {
            int nx2 = cur + 2; if (nx2 >= 3) nx2 -= 3;
            stage(nx2, kc + 2);
        }
        __builtin_amdgcn_s_setprio(1);
#pragma unroll
        for (int i = 0; i < 4; ++i)
#pragma unroll
            for (int j = 0; j < 4; ++j)
                acc[i][j] = __builtin_amdgcn_mfma_f32_16x16x32_bf16(
                    a[i], b[j], acc[i][j], 0, 0, 0);
        __builtin_amdgcn_s_setprio(0);

        if (more) { WAIT_VM4; } else { WAIT_VM0; }
        WAIT_LGKM;
        __builtin_amdgcn_s_barrier();
        ++cur; if (cur == 3) cur = 0;
    }

    // extraction: per-lane j-run is 4 consecutive n => natural 4-wide group max
#pragma unroll
    for (int nt = 0; nt < 4; ++nt) {
        const int n4 = (n0 >> 2) + wn * 16 + nt * 4 + lg;
#pragma unroll
        for (int ct = 0; ct < 4; ++ct) {
            const int c = c0 + wc * 64 + ct * 16 + lr;
            const f32x4 v = acc[nt][ct];
            const float m = fmaxf(fmaxf(v.x, v.y), fmaxf(v.z, v.w));
            G[(size_t)c * NGRP + n4] = f2bf(m);
        }
    }
}

// ---------------------------------------------------------------------------
// Kernel 3: per comment row, top-8 groups by approx group-max (unchanged).
// ---------------------------------------------------------------------------
__global__ __launch_bounds__(256)
void top_groups(const unsigned short* __restrict__ G, int* __restrict__ g8) {
    const int w = threadIdx.x >> 6, lane = threadIdx.x & 63;
    const int row = blockIdx.x * 4 + w;
    float v[32];
    const unsigned short* gp = G + (size_t)row * NGRP + lane * 32;
#pragma unroll
    for (int i = 0; i < 4; ++i) {
        short8 h = *(const short8*)(gp + i * 8);
#pragma unroll
        for (int j = 0; j < 8; ++j) v[i * 8 + j] = bf2f((unsigned short)h[j]);
    }
    float pv = INFINITY; int pi = -1;
    int gl[8];
#pragma unroll
    for (int k = 0; k < 8; ++k) {
        float bv = -INFINITY; int bi = NGRP;
#pragma unroll
        for (int i = 0; i < 32; ++i) {
            const int idx = lane * 32 + i;
            const bool after  = (v[i] < pv) || (v[i] == pv && idx > pi);
            const bool before = (v[i] > bv) || (v[i] == bv && idx < bi);
            if (after && before) { bv = v[i]; bi = idx; }
        }
#pragma unroll
        for (int off = 32; off >= 1; off >>= 1) {
            const float ov = __shfl_xor(bv, off);
            const int   oi = __shfl_xor(bi, off);
            if ((ov > bv) || (ov == bv && oi < bi)) { bv = ov; bi = oi; }
        }
        gl[k] = bi; pv = bv; pi = bi;
    }
#pragma unroll
    for (int a = 0; a < 8; ++a)
#pragma unroll
        for (int b2 = 0; b2 < 7; ++b2)
            if (gl[b2] > gl[b2 + 1]) { int t = gl[b2]; gl[b2] = gl[b2 + 1]; gl[b2 + 1] = t; }
    if (lane == 0) {
        int4 lo = make_int4(gl[0], gl[1], gl[2], gl[3]);
        int4 hi = make_int4(gl[4], gl[5], gl[6], gl[7]);
        *reinterpret_cast<int4*>(g8 + (size_t)row * 8)     = lo;
        *reinterpret_cast<int4*>(g8 + (size_t)row * 8 + 4) = hi;
    }
}

// ---------------------------------------------------------------------------
// Kernel 4: fused refine + gather (round-12 verified). Unchanged.
// ---------------------------------------------------------------------------
__global__ __launch_bounds__(256)
void refine_gather(const float* __restrict__ t_c, const float* __restrict__ t_s,
                   const int* __restrict__ g8, float* __restrict__ out) {
    __shared__ float tc[D_S];
    __shared__ float sc[4 * PGRP];
    __shared__ int   sel[2];
    const int row = blockIdx.x;
    const int tid = threadIdx.x;
    *reinterpret_cast<float4*>(&tc[tid * 4]) =
        *reinterpret_cast<const float4*>(&t_c[(size_t)row * D_S + tid * 4]);
    __syncthreads();
    const int w = tid >> 6, lane = tid & 63;
    float4 c4[4];
#pragma unroll
    for (int q = 0; q < 4; ++q)
        c4[q] = *reinterpret_cast<const float4*>(&tc[lane * 16 + q * 4]);
#pragma unroll
    for (int i = 0; i < 2; ++i) {
        const int slotg = w * 2 + i;
        const int g = g8[(size_t)row * 8 + slotg];
#pragma unroll
        for (int o = 0; o < 4; ++o) {
            const int n = g * 4 + o;
            const float* ts = t_s + (size_t)n * D_S + lane * 16;
            float p = 0.f;
#pragma unroll
            for (int q = 0; q < 4; ++q) {
                const float4 tv = *reinterpret_cast<const float4*>(ts + q * 4);
                p += c4[q].x * tv.x + c4[q].y * tv.y + c4[q].z * tv.z + c4[q].w * tv.w;
            }
#pragma unroll
            for (int off = 32; off >= 1; off >>= 1) p += __shfl_xor(p, off);
            if (lane == 0) sc[slotg * 4 + o] = p;
        }
    }
    __syncthreads();
    if (tid == 0) {
        float v1 = -INFINITY, v2 = -INFINITY; int i1 = 0, i2 = 0;
#pragma unroll
        for (int s = 0; s < 4 * PGRP; ++s) {
            const int n = g8[(size_t)row * 8 + (s >> 2)] * 4 + (s & 3);
            const float v = sc[s];
            if (v > v1)      { v2 = v1; i2 = i1; v1 = v; i1 = n; }
            else if (v > v2) { v2 = v; i2 = n; }
        }
        sel[0] = i1; sel[1] = i2;
    }
    __syncthreads();
#pragma unroll
    for (int q = 0; q < 2; ++q) {
        const int src = sel[q];
        const float4 v = *reinterpret_cast<const float4*>(
            &t_s[(size_t)src * D_S + tid * 4]);
        *reinterpret_cast<float4*>(
            &out[((size_t)row * KSEL + q) * D_S + tid * 4]) = v;
    }
}

// ---------------------------------------------------------------------------
extern "C" void kernel_launch(void* const* d_in, const int* in_sizes, int n_in,
                              void* d_out, int out_size, void* d_ws, size_t ws_size,
                              hipStream_t stream) {
    const float* srt      = (const float*)d_in[0];  // [8192,1024]
    const float* comments = (const float*)d_in[1];  // [4096,768]
    const float* Wc       = (const float*)d_in[2];  // [768,1024]
    const float* bc       = (const float*)d_in[3];  // [1024]
    const float* Ws       = (const float*)d_in[4];  // [1024,1024]
    const float* bs       = (const float*)d_in[5];  // [1024]
    float* out = (float*)d_out;

    // base workspace layout (identical to previous rounds)
    char* p = (char*)d_ws;
    float* t_c = (float*)p;          p += (size_t)B_C * D_S * 4;     // 16 MB
    float* t_s = (float*)p;          p += (size_t)N_SRT * D_S * 4;   // 32 MB
    unsigned short* tc_h = (unsigned short*)p; p += (size_t)B_C * D_S * 2;    // 8 MB
    unsigned short* ts_h = (unsigned short*)p; p += (size_t)N_SRT * D_S * 2;  // 16 MB
    unsigned short* G    = (unsigned short*)p; p += (size_t)B_C * NGRP * 2;   // 16 MB
    int* g8   = (int*)p;             p += (size_t)B_C * PGRP * 4;
    p += (size_t)B_C * KSEL * 4;     // (tidx slot kept for layout, unused)

    // fp16 2-plane workspace (appended; ~53.4 MB)
    _Float16* actS = (_Float16*)p; p += 2 * (size_t)N_SRT * D_S * 2; // 33.5 MB
    _Float16* actC = (_Float16*)p; p += 2 * (size_t)B_C * D_C * 2;   // 12.6 MB
    _Float16* wtS  = (_Float16*)p; p += 2 * (size_t)D_S * D_S * 2;   // 4.2 MB
    _Float16* wtC  = (_Float16*)p; p += 2 * (size_t)D_S * D_C * 2;   // 3.1 MB
    const size_t required = (size_t)(p - (char*)d_ws);

    if (ws_size >= required) {
        // --- scaled fp16x3 MFMA transform path ---
        split_act<<<(N_SRT * D_S / 8 + B_C * D_C / 8) / 256, 256, 0, stream>>>(
            srt, comments, actS, actC);
        split_w_all<<<256 + 192, 256, 0, stream>>>(Ws, wtS, Wc, wtC);

        transform_mfma_all<<<512 + 256, 256, 0, stream>>>(
            actS, wtS, bs, t_s, ts_h,
            actC, wtC, bc, t_c, tc_h);
    } else {
        // --- fallback: round-5 verified fp32 VALU path ---
        transform_fused<<<NB0 + NB1, 256, 0, stream>>>(
            comments, Wc, bc, t_c, tc_h,
            srt,      Ws, bs, t_s, ts_h);
    }

    scores_filter<<<dim3(N_SRT / 128, B_C / 128), 256, 0, stream>>>(ts_h, tc_h, G);
    top_groups<<<B_C / 4, 256, 0, stream>>>(G, g8);
    refine_gather<<<B_C, 256, 0, stream>>>(t_c, t_s, g8, out);
}

// Round 14
// 278.710 us; speedup vs baseline: 1.1912x; 1.0034x over previous
//
#include <hip/hip_runtime.h>
#include <math.h>

#define B_C   4096   // comments
#define N_SRT 8192   // srt rows
#define D_C   768
#define D_S   1024
#define KSEL  2
#define NGRP  (N_SRT / 4)   // 2048 groups of 4 consecutive srt rows
#define PGRP  8             // groups refined per comment row (32 candidates)

typedef float    f32x4  __attribute__((ext_vector_type(4)));
typedef short    short8 __attribute__((ext_vector_type(8)));
typedef _Float16 half8  __attribute__((ext_vector_type(8)));

__device__ inline unsigned short f2bf(float f) {           // RTNE float->bf16
    unsigned u = __float_as_uint(f);
    u += 0x7FFF + ((u >> 16) & 1);
    return (unsigned short)(u >> 16);
}
__device__ inline float bf2f(unsigned short h) {
    return __uint_as_float(((unsigned)h) << 16);
}

#define GLOAD_LDS16(gsrc, ldst)                                                     \
    __builtin_amdgcn_global_load_lds(                                               \
        (const __attribute__((address_space(1))) void*)(gsrc),                      \
        (__attribute__((address_space(3))) void*)(ldst), 16, 0, 0)

// counted-vmcnt barrier pieces
#define WAIT_VM4  asm volatile("s_waitcnt vmcnt(4)" ::: "memory")
#define WAIT_VM0  asm volatile("s_waitcnt vmcnt(0)" ::: "memory")
#define WAIT_LGKM asm volatile("s_waitcnt lgkmcnt(0)" ::: "memory")

// ---------------------------------------------------------------------------
// split_act: fp16 2-term split of activations (verified).
// ---------------------------------------------------------------------------
__global__ __launch_bounds__(256)
void split_act(const float* __restrict__ srt, const float* __restrict__ com,
               _Float16* __restrict__ pS, _Float16* __restrict__ pC) {
    const int g = blockIdx.x * 256 + threadIdx.x;   // one 8-elem group / thread
    const int E0 = N_SRT * D_S / 8;
    const float* src;
    _Float16* dst;
    size_t stride;
    if (g < E0) {
        src = srt + (size_t)g * 8; dst = pS + (size_t)g * 8;
        stride = (size_t)N_SRT * D_S;
    } else {
        const int g2 = g - E0;
        src = com + (size_t)g2 * 8; dst = pC + (size_t)g2 * 8;
        stride = (size_t)B_C * D_C;
    }
    const float4 a = *reinterpret_cast<const float4*>(src);
    const float4 b = *reinterpret_cast<const float4*>(src + 4);
    const float x[8] = {a.x, a.y, a.z, a.w, b.x, b.y, b.z, b.w};
    half8 hv, mv;
#pragma unroll
    for (int j = 0; j < 8; ++j) {
        const _Float16 h = (_Float16)x[j];
        const float    r = x[j] - (float)h;          // exact
        hv[j] = h; mv[j] = (_Float16)(r * 2048.0f);
    }
    *reinterpret_cast<half8*>(dst)          = hv;
    *reinterpret_cast<half8*>(dst + stride) = mv;
}

// ---------------------------------------------------------------------------
// split_w_all: both weight splits in ONE launch (verified).
// ---------------------------------------------------------------------------
__global__ __launch_bounds__(256)
void split_w_all(const float* __restrict__ Ws, _Float16* __restrict__ WtS,
                 const float* __restrict__ Wc, _Float16* __restrict__ WtC) {
    __shared__ float t[64][65];
    const bool p1 = (int)blockIdx.x >= 256;
    const int  b  = p1 ? (int)blockIdx.x - 256 : (int)blockIdx.x;
    const float* __restrict__ W = p1 ? Wc : Ws;
    _Float16* __restrict__ Wt   = p1 ? WtC : WtS;
    const int K  = p1 ? D_C : D_S;
    const int n0 = (b & 15) * 64, k0 = (b >> 4) * 64;

    const int tid = threadIdx.x;
    const int c = tid & 63, rq = tid >> 6;
#pragma unroll
    for (int j = 0; j < 16; ++j) {
        const int kr = rq * 16 + j;
        t[kr][c] = W[(size_t)(k0 + kr) * D_S + n0 + c];
    }
    __syncthreads();
    const size_t PS = (size_t)K * D_S;
#pragma unroll
    for (int j = 0; j < 16; ++j) {
        const int nr = rq * 16 + j;
        const float xs = t[c][nr] * 32768.0f;        // exact (pow2 scale)
        const _Float16 h = (_Float16)xs;
        const float    r = xs - (float)h;            // exact
        const size_t o = (size_t)(n0 + nr) * K + k0 + c;
        Wt[o]      = h;
        Wt[o + PS] = (_Float16)(r * 2048.0f);
    }
}

// ---------------------------------------------------------------------------
// transform_mfma_all: round-13 verified (chunk-fused scaled fp16x3).
// Unchanged this round.
// ---------------------------------------------------------------------------
__global__ __launch_bounds__(256)
void transform_mfma_all(const _Float16* __restrict__ actS,
                        const _Float16* __restrict__ wtS,
                        const float* __restrict__ bS,
                        float* __restrict__ CS, unsigned short* __restrict__ HS,
                        const _Float16* __restrict__ actC,
                        const _Float16* __restrict__ wtC,
                        const float* __restrict__ bC,
                        float* __restrict__ CC, unsigned short* __restrict__ HC) {
    __shared__ __align__(16) _Float16 sW[2][2][128 * 32];  // [buf][plane]
    __shared__ __align__(16) _Float16 sA[2][2][128 * 32];
    const int tid  = threadIdx.x;
    const int lane = tid & 63;
    const int w    = tid >> 6;
    const int lr   = lane & 15, lg = lane >> 4;
    const int wn   = w & 1, wc = w >> 1;

    const int hw = blockIdx.x;
    int lgid, seg;
    if (hw < 512) { seg = 0; lgid = (hw & 7) * 64 + (hw >> 3); }
    else          { const int h2 = hw - 512; seg = 1; lgid = (h2 & 7) * 32 + (h2 >> 3); }

    const _Float16* __restrict__ actP = seg ? actC : actS;
    const _Float16* __restrict__ wtP  = seg ? wtC  : wtS;
    const float* __restrict__ bias    = seg ? bC   : bS;
    float* __restrict__ C             = seg ? CC   : CS;
    unsigned short* __restrict__ H    = seg ? HC   : HS;
    const int K   = seg ? D_C : D_S;
    const int NC  = seg ? (D_C / 32) : (D_S / 32);    // 24 : 32 chunks
    const size_t aps = seg ? (size_t)B_C * D_C : (size_t)N_SRT * D_S;
    const size_t wps = (size_t)D_S * K;

    const int bn = (lgid & 7) * 128;
    const int bm = (lgid >> 3) * 128;

    const f32x4 vzero = {0.f, 0.f, 0.f, 0.f};
    f32x4 acc[4][4];
#pragma unroll
    for (int i = 0; i < 4; ++i)
#pragma unroll
        for (int j = 0; j < 4; ++j) acc[i][j] = vzero;

    auto stage = [&](int buf, int c) {
        const int kb = c * 32;
#pragma unroll
        for (int i = 0; i < 2; ++i) {
            const int idx = tid + i * 256;
            const int r   = idx >> 2;
            const int sw  = ((idx & 3) ^ ((r >> 1) & 3)) * 8;
            const size_t wo = (size_t)(bn + r) * K + kb + sw;
            const size_t ao = (size_t)(bm + r) * K + kb + sw;
            GLOAD_LDS16(wtP  + wo,       (char*)&sW[buf][0][0] + idx * 16);
            GLOAD_LDS16(wtP  + wps + wo, (char*)&sW[buf][1][0] + idx * 16);
            GLOAD_LDS16(actP + ao,       (char*)&sA[buf][0][0] + idx * 16);
            GLOAD_LDS16(actP + aps + ao, (char*)&sA[buf][1][0] + idx * 16);
        }
    };

    stage(0, 0);
    WAIT_VM0;
    __builtin_amdgcn_s_barrier();

    for (int c = 0; c < NC; ++c) {
        const int cur = c & 1;
        if (c + 1 < NC) stage(cur ^ 1, c + 1);

        half8 a0[4], a1[4], b0[4], b1[4], b0s[4];
#pragma unroll
        for (int t4 = 0; t4 < 4; ++t4) {
            const int ra = wn * 64 + t4 * 16 + lr;
            const int oa = ra * 64 + ((lg ^ ((ra >> 1) & 3)) * 16);
            a0[t4] = *(const half8*)((const char*)&sW[cur][0][0] + oa);
            a1[t4] = *(const half8*)((const char*)&sW[cur][1][0] + oa);
            const int rb = wc * 64 + t4 * 16 + lr;
            const int ob = rb * 64 + ((lg ^ ((rb >> 1) & 3)) * 16);
            b0[t4] = *(const half8*)((const char*)&sA[cur][0][0] + ob);
            b1[t4] = *(const half8*)((const char*)&sA[cur][1][0] + ob);
            b0s[t4] = b0[t4] * (_Float16)2048.0f;    // exact pow2
        }
        __builtin_amdgcn_s_setprio(1);
#pragma unroll
        for (int i = 0; i < 4; ++i)
#pragma unroll
            for (int j = 0; j < 4; ++j) {
                acc[i][j] = __builtin_amdgcn_mfma_f32_16x16x32_f16(
                    a0[i], b0s[j], acc[i][j], 0, 0, 0);   // hh (2^26)
                acc[i][j] = __builtin_amdgcn_mfma_f32_16x16x32_f16(
                    a0[i], b1[j],  acc[i][j], 0, 0, 0);   // hm (2^26)
                acc[i][j] = __builtin_amdgcn_mfma_f32_16x16x32_f16(
                    a1[i], b0[j],  acc[i][j], 0, 0, 0);   // mh (2^26)
            }
        __builtin_amdgcn_s_setprio(0);

        WAIT_VM0;
        WAIT_LGKM;
        __builtin_amdgcn_s_barrier();
    }

    const float s2 = 1.4901161193847656e-8f;    // 2^-26
#pragma unroll
    for (int i = 0; i < 4; ++i) {
        const int n = bn + wn * 64 + i * 16 + lg * 4;
        const f32x4 bb = *reinterpret_cast<const f32x4*>(&bias[n]);
#pragma unroll
        for (int j = 0; j < 4; ++j) {
            const int m = bm + wc * 64 + j * 16 + lr;
            f32x4 o;
#pragma unroll
            for (int q = 0; q < 4; ++q)
                o[q] = fmaxf(fmaf(acc[i][j][q], s2, bb[q]), 0.f);
            *reinterpret_cast<f32x4*>(&C[(size_t)m * D_S + n]) = o;
            ushort4 hh;
            hh.x = f2bf(o[0]); hh.y = f2bf(o[1]);
            hh.z = f2bf(o[2]); hh.w = f2bf(o[3]);
            *reinterpret_cast<ushort4*>(&H[(size_t)m * D_S + n]) = hh;
        }
    }
}

// ---------------------------------------------------------------------------
// FALLBACK (round-5 verified): fused fp32 VALU transforms (ws too small).
// ---------------------------------------------------------------------------
#define NB0 ((B_C / 128) * (D_S / 128))     // 256
#define NB1 ((N_SRT / 128) * (D_S / 128))   // 512

__global__ __launch_bounds__(256)
void transform_fused(const float* __restrict__ A0, const float* __restrict__ W0,
                     const float* __restrict__ b0, float* __restrict__ C0,
                     unsigned short* __restrict__ H0,
                     const float* __restrict__ A1, const float* __restrict__ W1,
                     const float* __restrict__ b1, float* __restrict__ C1,
                     unsigned short* __restrict__ H1) {
    __shared__ __align__(16) float As[2][128][16];
    __shared__ __align__(16) float Bs[2][2048];

    const bool p1 = (int)blockIdx.x >= NB0;
    const int  b  = p1 ? (int)blockIdx.x - NB0 : (int)blockIdx.x;
    const float* __restrict__ A = p1 ? A1 : A0;
    const float* __restrict__ W = p1 ? W1 : W0;
    const float* __restrict__ bias = p1 ? b1 : b0;
    float* __restrict__ C = p1 ? C1 : C0;
    unsigned short* __restrict__ H = p1 ? H1 : H0;
    const int K = p1 ? D_S : D_C;

    const int bn = (b & 7) * 128;
    const int bm = (b >> 3) * 128;

    const int tid = threadIdx.x;
    const int tx = tid & 15, ty = tid >> 4;

    int a_off[2], w_off[2];
#pragma unroll
    for (int i = 0; i < 2; ++i) {
        const int idx = tid + i * 256;
        const int r = idx >> 2, q = idx & 3;
        a_off[i] = r * K + (q ^ ((r >> 3) & 3)) * 4;
        const int s = idx & 63;
        const int kloc = 2 * (idx >> 6) + ((s >> 4) & 1);
        const int cb   = 2 * (s & 15) + (s >> 5);
        w_off[i] = kloc * D_S + cb * 4;
    }

#define STAGE(bufi, k0)                                                        \
    {                                                                          \
        _Pragma("unroll")                                                      \
        for (int i = 0; i < 2; ++i) {                                          \
            const int idx = tid + i * 256;                                     \
            GLOAD_LDS16(A + (size_t)bm * K + (k0) + a_off[i],                  \
                        (char*)&As[bufi][0][0] + idx * 16);                    \
            GLOAD_LDS16(W + (size_t)(k0) * D_S + bn + w_off[i],                \
                        (char*)&Bs[bufi][0] + idx * 16);                       \
        }                                                                      \
    }

    float acc[8][8] = {};

    STAGE(0, 0);
    __syncthreads();

    const int nk = K / 16;
    for (int t = 0; t < nk; ++t) {
        const int cur = t & 1;
        if (t + 1 < nk) STAGE(t & 1 ? 0 : 1, (t + 1) * 16);

        const float* __restrict__ Bf = &Bs[cur][0];
#pragma unroll
        for (int kq = 0; kq < 4; ++kq) {
            f32x4 a4[8];
#pragma unroll
            for (int i = 0; i < 8; ++i)
                a4[i] = *reinterpret_cast<const f32x4*>(
                    &As[cur][ty * 8 + i][(kq ^ (ty & 3)) * 4]);
#pragma unroll
            for (int k2 = 0; k2 < 4; ++k2) {
                const int k = kq * 4 + k2;
                const int boff = (k >> 1) * 256 + (tx + ((k & 1) << 4)) * 4;
                const f32x4 bx = *reinterpret_cast<const f32x4*>(Bf + boff);
                const f32x4 by = *reinterpret_cast<const f32x4*>(Bf + boff + 128);
                const float bv[8] = {bx[0], bx[1], bx[2], bx[3], by[0], by[1], by[2], by[3]};
#pragma unroll
                for (int i = 0; i < 8; ++i) {
                    const float av = a4[i][k2];
#pragma unroll
                    for (int j = 0; j < 8; ++j)
                        acc[i][j] = fmaf(av, bv[j], acc[i][j]);
                }
            }
        }
        __syncthreads();
    }
#undef STAGE

    const f32x4 g0 = *reinterpret_cast<const f32x4*>(&bias[bn + tx * 8]);
    const f32x4 g1 = *reinterpret_cast<const f32x4*>(&bias[bn + tx * 8 + 4]);
#pragma unroll
    for (int i = 0; i < 8; ++i) {
        const int m = bm + ty * 8 + i;
        const int n = bn + tx * 8;
        f32x4 o0, o1;
#pragma unroll
        for (int j = 0; j < 4; ++j) {
            o0[j] = fmaxf(acc[i][j]     + g0[j], 0.f);
            o1[j] = fmaxf(acc[i][j + 4] + g1[j], 0.f);
        }
        *reinterpret_cast<f32x4*>(&C[(size_t)m * D_S + n])     = o0;
        *reinterpret_cast<f32x4*>(&C[(size_t)m * D_S + n + 4]) = o1;
        short8 h;
#pragma unroll
        for (int j = 0; j < 4; ++j) {
            h[j]     = (short)f2bf(o0[j]);
            h[j + 4] = (short)f2bf(o1[j]);
        }
        *reinterpret_cast<short8*>(&H[(size_t)m * D_S + n]) = h;
    }
}

// ---------------------------------------------------------------------------
// Kernel 2 (round-14): bf16 MFMA score filter, 256x256 big-tile.
// 512 threads (8 waves, 2Mx4N), wave-tile 128(srt) x 64(c), BK=32.
// 3 LDS buffers (3 x 32KB = 96KB, 1 block/CU): stage(kt+2) -> buf[(kt+2)%3]
// which is NEVER the buffer being read (kt%3) nor next (kt+1)%3 — hazard-free
// by construction (r11-verified rotation). Per K-tile, TWO sub-phases of
// 16 MFMA each with {ds_reads ∥ 2 gload_lds -> barrier -> lgkm -> setprio ->
// MFMA -> setprio -> barrier}: phase-split gives the role diversity T5 needs;
// counted vmcnt(4) only at K-tile end keeps kt+2's loads in flight across
// barriers (T4). Staging-bytes/MFMA halves vs the 128² structure.
// Swizzle/fragments/extraction reuse r9-verified BK=32 patterns.
// ---------------------------------------------------------------------------
__global__ __launch_bounds__(512)
void scores_filter(const unsigned short* __restrict__ TSh,
                   const unsigned short* __restrict__ TCh,
                   unsigned short* __restrict__ G) {
    __shared__ __align__(16) unsigned short sA[3][256 * 32];  // TS tiles, 16KB
    __shared__ __align__(16) unsigned short sB[3][256 * 32];  // TC tiles
    const int tid  = threadIdx.x;
    const int lane = tid & 63;
    const int w    = tid >> 6;          // 0..7
    const int mw   = w >> 2;            // 0..1  (srt 128-half)
    const int nw   = w & 3;             // 0..3  (c 64-quarter)
    const int lr   = lane & 15, lg = lane >> 4;

    // XCD-chunked bijective swizzle over 512 blocks; consecutive lgid share c-tile
    const int hw   = blockIdx.x;
    const int lgid = (hw & 7) * 64 + (hw >> 3);
    const int n0   = (lgid & 31) * 256;     // srt tile
    const int c0   = (lgid >> 5) * 256;     // comment tile

    const f32x4 vzero = {0.f, 0.f, 0.f, 0.f};
    f32x4 acc[8][4];
#pragma unroll
    for (int i = 0; i < 8; ++i)
#pragma unroll
        for (int j = 0; j < 4; ++j) acc[i][j] = vzero;

    // staging: tile = 256 rows x 32 cols bf16 = 1024 x 16B slots; 2 slots/thread
    // slot idx -> r = idx>>2, blk = idx&3; global col-block = blk ^ ((r>>1)&3)
    auto stageA = [&](int buf, int kt) {
        const int kb = kt * 32;
#pragma unroll
        for (int i = 0; i < 2; ++i) {
            const int idx = tid + i * 512;
            const int r   = idx >> 2;
            const int sw  = ((idx & 3) ^ ((r >> 1) & 3)) * 8;
            GLOAD_LDS16(TSh + (size_t)(n0 + r) * D_S + kb + sw,
                        (char*)&sA[buf][0] + idx * 16);
        }
    };
    auto stageB = [&](int buf, int kt) {
        const int kb = kt * 32;
#pragma unroll
        for (int i = 0; i < 2; ++i) {
            const int idx = tid + i * 512;
            const int r   = idx >> 2;
            const int sw  = ((idx & 3) ^ ((r >> 1) & 3)) * 8;
            GLOAD_LDS16(TCh + (size_t)(c0 + r) * D_S + kb + sw,
                        (char*)&sB[buf][0] + idx * 16);
        }
    };

    const int NT = D_S / 32;   // 32 K-tiles

    stageA(0, 0); stageB(0, 0);
    stageA(1, 1); stageB(1, 1);
    WAIT_VM4;                  // kt0's 4 loads landed (kt1's 4 in flight)
    __builtin_amdgcn_s_barrier();

    int cur = 0;
    for (int kt = 0; kt < NT; ++kt) {
        const bool more = (kt + 2 < NT);
        int nx2 = cur + 2; if (nx2 >= 3) nx2 -= 3;

        // ---- sub-phase 0: b-frags + a-frags m0-3; stage A(kt+2) ----
        short8 bfr[4], afr[4];
#pragma unroll
        for (int j = 0; j < 4; ++j) {
            const int rb = nw * 64 + j * 16 + lr;
            bfr[j] = *(const short8*)((const char*)&sB[cur][0] + rb * 64 +
                                      ((lg ^ ((rb >> 1) & 3)) * 16));
        }
#pragma unroll
        for (int i = 0; i < 4; ++i) {
            const int ra = mw * 128 + i * 16 + lr;
            afr[i] = *(const short8*)((const char*)&sA[cur][0] + ra * 64 +
                                      ((lg ^ ((ra >> 1) & 3)) * 16));
        }
        if (more) stageA(nx2, kt + 2);
        __builtin_amdgcn_s_barrier();
        WAIT_LGKM;
        __builtin_amdgcn_s_setprio(1);
#pragma unroll
        for (int i = 0; i < 4; ++i)
#pragma unroll
            for (int j = 0; j < 4; ++j)
                acc[i][j] = __builtin_amdgcn_mfma_f32_16x16x32_bf16(
                    afr[i], bfr[j], acc[i][j], 0, 0, 0);
        __builtin_amdgcn_s_setprio(0);
        __builtin_amdgcn_s_barrier();

        // ---- sub-phase 1: a-frags m4-7; stage B(kt+2) ----
#pragma unroll
        for (int i = 0; i < 4; ++i) {
            const int ra = mw * 128 + (i + 4) * 16 + lr;
            afr[i] = *(const short8*)((const char*)&sA[cur][0] + ra * 64 +
                                      ((lg ^ ((ra >> 1) & 3)) * 16));
        }
        if (more) stageB(nx2, kt + 2);
        __builtin_amdgcn_s_barrier();
        WAIT_LGKM;
        __builtin_amdgcn_s_setprio(1);
#pragma unroll
        for (int i = 0; i < 4; ++i)
#pragma unroll
            for (int j = 0; j < 4; ++j)
                acc[i + 4][j] = __builtin_amdgcn_mfma_f32_16x16x32_bf16(
                    afr[i], bfr[j], acc[i + 4][j], 0, 0, 0);
        __builtin_amdgcn_s_setprio(0);

        // ---- end of K-tile: kt+1 must be fully landed ----
        if (more) { WAIT_VM4; } else { WAIT_VM0; }
        __builtin_amdgcn_s_barrier();
        ++cur; if (cur == 3) cur = 0;
    }

    // extraction: n = n0 + mw*128 + i*16 + lg*4 + q (4 consecutive -> group max)
#pragma unroll
    for (int i = 0; i < 8; ++i) {
        const int n4 = ((n0 + mw * 128 + i * 16) >> 2) + lg;
#pragma unroll
        for (int j = 0; j < 4; ++j) {
            const int c = c0 + nw * 64 + j * 16 + lr;
            const f32x4 v = acc[i][j];
            const float m = fmaxf(fmaxf(v.x, v.y), fmaxf(v.z, v.w));
            G[(size_t)c * NGRP + n4] = f2bf(m);
        }
    }
}

// ---------------------------------------------------------------------------
// Kernel 3: per comment row, top-8 groups by approx group-max (unchanged).
// ---------------------------------------------------------------------------
__global__ __launch_bounds__(256)
void top_groups(const unsigned short* __restrict__ G, int* __restrict__ g8) {
    const int w = threadIdx.x >> 6, lane = threadIdx.x & 63;
    const int row = blockIdx.x * 4 + w;
    float v[32];
    const unsigned short* gp = G + (size_t)row * NGRP + lane * 32;
#pragma unroll
    for (int i = 0; i < 4; ++i) {
        short8 h = *(const short8*)(gp + i * 8);
#pragma unroll
        for (int j = 0; j < 8; ++j) v[i * 8 + j] = bf2f((unsigned short)h[j]);
    }
    float pv = INFINITY; int pi = -1;
    int gl[8];
#pragma unroll
    for (int k = 0; k < 8; ++k) {
        float bv = -INFINITY; int bi = NGRP;
#pragma unroll
        for (int i = 0; i < 32; ++i) {
            const int idx = lane * 32 + i;
            const bool after  = (v[i] < pv) || (v[i] == pv && idx > pi);
            const bool before = (v[i] > bv) || (v[i] == bv && idx < bi);
            if (after && before) { bv = v[i]; bi = idx; }
        }
#pragma unroll
        for (int off = 32; off >= 1; off >>= 1) {
            const float ov = __shfl_xor(bv, off);
            const int   oi = __shfl_xor(bi, off);
            if ((ov > bv) || (ov == bv && oi < bi)) { bv = ov; bi = oi; }
        }
        gl[k] = bi; pv = bv; pi = bi;
    }
#pragma unroll
    for (int a = 0; a < 8; ++a)
#pragma unroll
        for (int b2 = 0; b2 < 7; ++b2)
            if (gl[b2] > gl[b2 + 1]) { int t = gl[b2]; gl[b2] = gl[b2 + 1]; gl[b2 + 1] = t; }
    if (lane == 0) {
        int4 lo = make_int4(gl[0], gl[1], gl[2], gl[3]);
        int4 hi = make_int4(gl[4], gl[5], gl[6], gl[7]);
        *reinterpret_cast<int4*>(g8 + (size_t)row * 8)     = lo;
        *reinterpret_cast<int4*>(g8 + (size_t)row * 8 + 4) = hi;
    }
}

// ---------------------------------------------------------------------------
// Kernel 4: fused refine + gather (verified). Unchanged.
// ---------------------------------------------------------------------------
__global__ __launch_bounds__(256)
void refine_gather(const float* __restrict__ t_c, const float* __restrict__ t_s,
                   const int* __restrict__ g8, float* __restrict__ out) {
    __shared__ float tc[D_S];
    __shared__ float sc[4 * PGRP];
    __shared__ int   sel[2];
    const int row = blockIdx.x;
    const int tid = threadIdx.x;
    *reinterpret_cast<float4*>(&tc[tid * 4]) =
        *reinterpret_cast<const float4*>(&t_c[(size_t)row * D_S + tid * 4]);
    __syncthreads();
    const int w = tid >> 6, lane = tid & 63;
    float4 c4[4];
#pragma unroll
    for (int q = 0; q < 4; ++q)
        c4[q] = *reinterpret_cast<const float4*>(&tc[lane * 16 + q * 4]);
#pragma unroll
    for (int i = 0; i < 2; ++i) {
        const int slotg = w * 2 + i;
        const int g = g8[(size_t)row * 8 + slotg];
#pragma unroll
        for (int o = 0; o < 4; ++o) {
            const int n = g * 4 + o;
            const float* ts = t_s + (size_t)n * D_S + lane * 16;
            float p = 0.f;
#pragma unroll
            for (int q = 0; q < 4; ++q) {
                const float4 tv = *reinterpret_cast<const float4*>(ts + q * 4);
                p += c4[q].x * tv.x + c4[q].y * tv.y + c4[q].z * tv.z + c4[q].w * tv.w;
            }
#pragma unroll
            for (int off = 32; off >= 1; off >>= 1) p += __shfl_xor(p, off);
            if (lane == 0) sc[slotg * 4 + o] = p;
        }
    }
    __syncthreads();
    if (tid == 0) {
        float v1 = -INFINITY, v2 = -INFINITY; int i1 = 0, i2 = 0;
#pragma unroll
        for (int s = 0; s < 4 * PGRP; ++s) {
            const int n = g8[(size_t)row * 8 + (s >> 2)] * 4 + (s & 3);
            const float v = sc[s];
            if (v > v1)      { v2 = v1; i2 = i1; v1 = v; i1 = n; }
            else if (v > v2) { v2 = v; i2 = n; }
        }
        sel[0] = i1; sel[1] = i2;
    }
    __syncthreads();
#pragma unroll
    for (int q = 0; q < 2; ++q) {
        const int src = sel[q];
        const float4 v = *reinterpret_cast<const float4*>(
            &t_s[(size_t)src * D_S + tid * 4]);
        *reinterpret_cast<float4*>(
            &out[((size_t)row * KSEL + q) * D_S + tid * 4]) = v;
    }
}

// ---------------------------------------------------------------------------
extern "C" void kernel_launch(void* const* d_in, const int* in_sizes, int n_in,
                              void* d_out, int out_size, void* d_ws, size_t ws_size,
                              hipStream_t stream) {
    const float* srt      = (const float*)d_in[0];  // [8192,1024]
    const float* comments = (const float*)d_in[1];  // [4096,768]
    const float* Wc       = (const float*)d_in[2];  // [768,1024]
    const float* bc       = (const float*)d_in[3];  // [1024]
    const float* Ws       = (const float*)d_in[4];  // [1024,1024]
    const float* bs       = (const float*)d_in[5];  // [1024]
    float* out = (float*)d_out;

    // base workspace layout (identical to previous rounds)
    char* p = (char*)d_ws;
    float* t_c = (float*)p;          p += (size_t)B_C * D_S * 4;     // 16 MB
    float* t_s = (float*)p;          p += (size_t)N_SRT * D_S * 4;   // 32 MB
    unsigned short* tc_h = (unsigned short*)p; p += (size_t)B_C * D_S * 2;    // 8 MB
    unsigned short* ts_h = (unsigned short*)p; p += (size_t)N_SRT * D_S * 2;  // 16 MB
    unsigned short* G    = (unsigned short*)p; p += (size_t)B_C * NGRP * 2;   // 16 MB
    int* g8   = (int*)p;             p += (size_t)B_C * PGRP * 4;
    p += (size_t)B_C * KSEL * 4;     // (tidx slot kept for layout, unused)

    // fp16 2-plane workspace (appended; ~53.4 MB)
    _Float16* actS = (_Float16*)p; p += 2 * (size_t)N_SRT * D_S * 2; // 33.5 MB
    _Float16* actC = (_Float16*)p; p += 2 * (size_t)B_C * D_C * 2;   // 12.6 MB
    _Float16* wtS  = (_Float16*)p; p += 2 * (size_t)D_S * D_S * 2;   // 4.2 MB
    _Float16* wtC  = (_Float16*)p; p += 2 * (size_t)D_S * D_C * 2;   // 3.1 MB
    const size_t required = (size_t)(p - (char*)d_ws);

    if (ws_size >= required) {
        // --- scaled fp16x3 MFMA transform path ---
        split_act<<<(N_SRT * D_S / 8 + B_C * D_C / 8) / 256, 256, 0, stream>>>(
            srt, comments, actS, actC);
        split_w_all<<<256 + 192, 256, 0, stream>>>(Ws, wtS, Wc, wtC);

        transform_mfma_all<<<512 + 256, 256, 0, stream>>>(
            actS, wtS, bs, t_s, ts_h,
            actC, wtC, bc, t_c, tc_h);
    } else {
        // --- fallback: round-5 verified fp32 VALU path ---
        transform_fused<<<NB0 + NB1, 256, 0, stream>>>(
            comments, Wc, bc, t_c, tc_h,
            srt,      Ws, bs, t_s, ts_h);
    }

    scores_filter<<<512, 512, 0, stream>>>(ts_h, tc_h, G);
    top_groups<<<B_C / 4, 256, 0, stream>>>(G, g8);
    refine_gather<<<B_C, 256, 0, stream>>>(t_c, t_s, g8, out);
}

// Round 15
// 274.968 us; speedup vs baseline: 1.2074x; 1.0136x over previous
//
#include <hip/hip_runtime.h>
#include <math.h>

#define B_C   4096   // comments
#define N_SRT 8192   // srt rows
#define D_C   768
#define D_S   1024
#define KSEL  2
#define NGRP  (N_SRT / 4)   // 2048 groups of 4 consecutive srt rows
#define PGRP  8             // groups refined per comment row (32 candidates)

typedef float    f32x4  __attribute__((ext_vector_type(4)));
typedef short    short8 __attribute__((ext_vector_type(8)));
typedef _Float16 half8  __attribute__((ext_vector_type(8)));

__device__ inline unsigned short f2bf(float f) {           // RTNE float->bf16
    unsigned u = __float_as_uint(f);
    u += 0x7FFF + ((u >> 16) & 1);
    return (unsigned short)(u >> 16);
}
__device__ inline float bf2f(unsigned short h) {
    return __uint_as_float(((unsigned)h) << 16);
}

#define GLOAD_LDS16(gsrc, ldst)                                                     \
    __builtin_amdgcn_global_load_lds(                                               \
        (const __attribute__((address_space(1))) void*)(gsrc),                      \
        (__attribute__((address_space(3))) void*)(ldst), 16, 0, 0)

// counted-vmcnt barrier pieces
#define WAIT_VM4  asm volatile("s_waitcnt vmcnt(4)" ::: "memory")
#define WAIT_VM0  asm volatile("s_waitcnt vmcnt(0)" ::: "memory")
#define WAIT_LGKM asm volatile("s_waitcnt lgkmcnt(0)" ::: "memory")

// ---------------------------------------------------------------------------
// split_act: fp16 2-term split of activations (verified).
// ---------------------------------------------------------------------------
__global__ __launch_bounds__(256)
void split_act(const float* __restrict__ srt, const float* __restrict__ com,
               _Float16* __restrict__ pS, _Float16* __restrict__ pC) {
    const int g = blockIdx.x * 256 + threadIdx.x;   // one 8-elem group / thread
    const int E0 = N_SRT * D_S / 8;
    const float* src;
    _Float16* dst;
    size_t stride;
    if (g < E0) {
        src = srt + (size_t)g * 8; dst = pS + (size_t)g * 8;
        stride = (size_t)N_SRT * D_S;
    } else {
        const int g2 = g - E0;
        src = com + (size_t)g2 * 8; dst = pC + (size_t)g2 * 8;
        stride = (size_t)B_C * D_C;
    }
    const float4 a = *reinterpret_cast<const float4*>(src);
    const float4 b = *reinterpret_cast<const float4*>(src + 4);
    const float x[8] = {a.x, a.y, a.z, a.w, b.x, b.y, b.z, b.w};
    half8 hv, mv;
#pragma unroll
    for (int j = 0; j < 8; ++j) {
        const _Float16 h = (_Float16)x[j];
        const float    r = x[j] - (float)h;          // exact
        hv[j] = h; mv[j] = (_Float16)(r * 2048.0f);
    }
    *reinterpret_cast<half8*>(dst)          = hv;
    *reinterpret_cast<half8*>(dst + stride) = mv;
}

// ---------------------------------------------------------------------------
// split_w_all: both weight splits in ONE launch (verified).
// ---------------------------------------------------------------------------
__global__ __launch_bounds__(256)
void split_w_all(const float* __restrict__ Ws, _Float16* __restrict__ WtS,
                 const float* __restrict__ Wc, _Float16* __restrict__ WtC) {
    __shared__ float t[64][65];
    const bool p1 = (int)blockIdx.x >= 256;
    const int  b  = p1 ? (int)blockIdx.x - 256 : (int)blockIdx.x;
    const float* __restrict__ W = p1 ? Wc : Ws;
    _Float16* __restrict__ Wt   = p1 ? WtC : WtS;
    const int K  = p1 ? D_C : D_S;
    const int n0 = (b & 15) * 64, k0 = (b >> 4) * 64;

    const int tid = threadIdx.x;
    const int c = tid & 63, rq = tid >> 6;
#pragma unroll
    for (int j = 0; j < 16; ++j) {
        const int kr = rq * 16 + j;
        t[kr][c] = W[(size_t)(k0 + kr) * D_S + n0 + c];
    }
    __syncthreads();
    const size_t PS = (size_t)K * D_S;
#pragma unroll
    for (int j = 0; j < 16; ++j) {
        const int nr = rq * 16 + j;
        const float xs = t[c][nr] * 32768.0f;        // exact (pow2 scale)
        const _Float16 h = (_Float16)xs;
        const float    r = xs - (float)h;            // exact
        const size_t o = (size_t)(n0 + nr) * K + k0 + c;
        Wt[o]      = h;
        Wt[o + PS] = (_Float16)(r * 2048.0f);
    }
}

// ---------------------------------------------------------------------------
// transform_mfma_all: round-13 verified (chunk-fused scaled fp16x3). Frozen.
// ---------------------------------------------------------------------------
__global__ __launch_bounds__(256)
void transform_mfma_all(const _Float16* __restrict__ actS,
                        const _Float16* __restrict__ wtS,
                        const float* __restrict__ bS,
                        float* __restrict__ CS, unsigned short* __restrict__ HS,
                        const _Float16* __restrict__ actC,
                        const _Float16* __restrict__ wtC,
                        const float* __restrict__ bC,
                        float* __restrict__ CC, unsigned short* __restrict__ HC) {
    __shared__ __align__(16) _Float16 sW[2][2][128 * 32];  // [buf][plane]
    __shared__ __align__(16) _Float16 sA[2][2][128 * 32];
    const int tid  = threadIdx.x;
    const int lane = tid & 63;
    const int w    = tid >> 6;
    const int lr   = lane & 15, lg = lane >> 4;
    const int wn   = w & 1, wc = w >> 1;

    const int hw = blockIdx.x;
    int lgid, seg;
    if (hw < 512) { seg = 0; lgid = (hw & 7) * 64 + (hw >> 3); }
    else          { const int h2 = hw - 512; seg = 1; lgid = (h2 & 7) * 32 + (h2 >> 3); }

    const _Float16* __restrict__ actP = seg ? actC : actS;
    const _Float16* __restrict__ wtP  = seg ? wtC  : wtS;
    const float* __restrict__ bias    = seg ? bC   : bS;
    float* __restrict__ C             = seg ? CC   : CS;
    unsigned short* __restrict__ H    = seg ? HC   : HS;
    const int K   = seg ? D_C : D_S;
    const int NC  = seg ? (D_C / 32) : (D_S / 32);    // 24 : 32 chunks
    const size_t aps = seg ? (size_t)B_C * D_C : (size_t)N_SRT * D_S;
    const size_t wps = (size_t)D_S * K;

    const int bn = (lgid & 7) * 128;
    const int bm = (lgid >> 3) * 128;

    const f32x4 vzero = {0.f, 0.f, 0.f, 0.f};
    f32x4 acc[4][4];
#pragma unroll
    for (int i = 0; i < 4; ++i)
#pragma unroll
        for (int j = 0; j < 4; ++j) acc[i][j] = vzero;

    auto stage = [&](int buf, int c) {
        const int kb = c * 32;
#pragma unroll
        for (int i = 0; i < 2; ++i) {
            const int idx = tid + i * 256;
            const int r   = idx >> 2;
            const int sw  = ((idx & 3) ^ ((r >> 1) & 3)) * 8;
            const size_t wo = (size_t)(bn + r) * K + kb + sw;
            const size_t ao = (size_t)(bm + r) * K + kb + sw;
            GLOAD_LDS16(wtP  + wo,       (char*)&sW[buf][0][0] + idx * 16);
            GLOAD_LDS16(wtP  + wps + wo, (char*)&sW[buf][1][0] + idx * 16);
            GLOAD_LDS16(actP + ao,       (char*)&sA[buf][0][0] + idx * 16);
            GLOAD_LDS16(actP + aps + ao, (char*)&sA[buf][1][0] + idx * 16);
        }
    };

    stage(0, 0);
    WAIT_VM0;
    __builtin_amdgcn_s_barrier();

    for (int c = 0; c < NC; ++c) {
        const int cur = c & 1;
        if (c + 1 < NC) stage(cur ^ 1, c + 1);

        half8 a0[4], a1[4], b0[4], b1[4], b0s[4];
#pragma unroll
        for (int t4 = 0; t4 < 4; ++t4) {
            const int ra = wn * 64 + t4 * 16 + lr;
            const int oa = ra * 64 + ((lg ^ ((ra >> 1) & 3)) * 16);
            a0[t4] = *(const half8*)((const char*)&sW[cur][0][0] + oa);
            a1[t4] = *(const half8*)((const char*)&sW[cur][1][0] + oa);
            const int rb = wc * 64 + t4 * 16 + lr;
            const int ob = rb * 64 + ((lg ^ ((rb >> 1) & 3)) * 16);
            b0[t4] = *(const half8*)((const char*)&sA[cur][0][0] + ob);
            b1[t4] = *(const half8*)((const char*)&sA[cur][1][0] + ob);
            b0s[t4] = b0[t4] * (_Float16)2048.0f;    // exact pow2
        }
        __builtin_amdgcn_s_setprio(1);
#pragma unroll
        for (int i = 0; i < 4; ++i)
#pragma unroll
            for (int j = 0; j < 4; ++j) {
                acc[i][j] = __builtin_amdgcn_mfma_f32_16x16x32_f16(
                    a0[i], b0s[j], acc[i][j], 0, 0, 0);   // hh (2^26)
                acc[i][j] = __builtin_amdgcn_mfma_f32_16x16x32_f16(
                    a0[i], b1[j],  acc[i][j], 0, 0, 0);   // hm (2^26)
                acc[i][j] = __builtin_amdgcn_mfma_f32_16x16x32_f16(
                    a1[i], b0[j],  acc[i][j], 0, 0, 0);   // mh (2^26)
            }
        __builtin_amdgcn_s_setprio(0);

        WAIT_VM0;
        WAIT_LGKM;
        __builtin_amdgcn_s_barrier();
    }

    const float s2 = 1.4901161193847656e-8f;    // 2^-26
#pragma unroll
    for (int i = 0; i < 4; ++i) {
        const int n = bn + wn * 64 + i * 16 + lg * 4;
        const f32x4 bb = *reinterpret_cast<const f32x4*>(&bias[n]);
#pragma unroll
        for (int j = 0; j < 4; ++j) {
            const int m = bm + wc * 64 + j * 16 + lr;
            f32x4 o;
#pragma unroll
            for (int q = 0; q < 4; ++q)
                o[q] = fmaxf(fmaf(acc[i][j][q], s2, bb[q]), 0.f);
            *reinterpret_cast<f32x4*>(&C[(size_t)m * D_S + n]) = o;
            ushort4 hh;
            hh.x = f2bf(o[0]); hh.y = f2bf(o[1]);
            hh.z = f2bf(o[2]); hh.w = f2bf(o[3]);
            *reinterpret_cast<ushort4*>(&H[(size_t)m * D_S + n]) = hh;
        }
    }
}

// ---------------------------------------------------------------------------
// FALLBACK (round-5 verified): fused fp32 VALU transforms (ws too small).
// ---------------------------------------------------------------------------
#define NB0 ((B_C / 128) * (D_S / 128))     // 256
#define NB1 ((N_SRT / 128) * (D_S / 128))   // 512

__global__ __launch_bounds__(256)
void transform_fused(const float* __restrict__ A0, const float* __restrict__ W0,
                     const float* __restrict__ b0, float* __restrict__ C0,
                     unsigned short* __restrict__ H0,
                     const float* __restrict__ A1, const float* __restrict__ W1,
                     const float* __restrict__ b1, float* __restrict__ C1,
                     unsigned short* __restrict__ H1) {
    __shared__ __align__(16) float As[2][128][16];
    __shared__ __align__(16) float Bs[2][2048];

    const bool p1 = (int)blockIdx.x >= NB0;
    const int  b  = p1 ? (int)blockIdx.x - NB0 : (int)blockIdx.x;
    const float* __restrict__ A = p1 ? A1 : A0;
    const float* __restrict__ W = p1 ? W1 : W0;
    const float* __restrict__ bias = p1 ? b1 : b0;
    float* __restrict__ C = p1 ? C1 : C0;
    unsigned short* __restrict__ H = p1 ? H1 : H0;
    const int K = p1 ? D_S : D_C;

    const int bn = (b & 7) * 128;
    const int bm = (b >> 3) * 128;

    const int tid = threadIdx.x;
    const int tx = tid & 15, ty = tid >> 4;

    int a_off[2], w_off[2];
#pragma unroll
    for (int i = 0; i < 2; ++i) {
        const int idx = tid + i * 256;
        const int r = idx >> 2, q = idx & 3;
        a_off[i] = r * K + (q ^ ((r >> 3) & 3)) * 4;
        const int s = idx & 63;
        const int kloc = 2 * (idx >> 6) + ((s >> 4) & 1);
        const int cb   = 2 * (s & 15) + (s >> 5);
        w_off[i] = kloc * D_S + cb * 4;
    }

#define STAGE(bufi, k0)                                                        \
    {                                                                          \
        _Pragma("unroll")                                                      \
        for (int i = 0; i < 2; ++i) {                                          \
            const int idx = tid + i * 256;                                     \
            GLOAD_LDS16(A + (size_t)bm * K + (k0) + a_off[i],                  \
                        (char*)&As[bufi][0][0] + idx * 16);                    \
            GLOAD_LDS16(W + (size_t)(k0) * D_S + bn + w_off[i],                \
                        (char*)&Bs[bufi][0] + idx * 16);                       \
        }                                                                      \
    }

    float acc[8][8] = {};

    STAGE(0, 0);
    __syncthreads();

    const int nk = K / 16;
    for (int t = 0; t < nk; ++t) {
        const int cur = t & 1;
        if (t + 1 < nk) STAGE(t & 1 ? 0 : 1, (t + 1) * 16);

        const float* __restrict__ Bf = &Bs[cur][0];
#pragma unroll
        for (int kq = 0; kq < 4; ++kq) {
            f32x4 a4[8];
#pragma unroll
            for (int i = 0; i < 8; ++i)
                a4[i] = *reinterpret_cast<const f32x4*>(
                    &As[cur][ty * 8 + i][(kq ^ (ty & 3)) * 4]);
#pragma unroll
            for (int k2 = 0; k2 < 4; ++k2) {
                const int k = kq * 4 + k2;
                const int boff = (k >> 1) * 256 + (tx + ((k & 1) << 4)) * 4;
                const f32x4 bx = *reinterpret_cast<const f32x4*>(Bf + boff);
                const f32x4 by = *reinterpret_cast<const f32x4*>(Bf + boff + 128);
                const float bv[8] = {bx[0], bx[1], bx[2], bx[3], by[0], by[1], by[2], by[3]};
#pragma unroll
                for (int i = 0; i < 8; ++i) {
                    const float av = a4[i][k2];
#pragma unroll
                    for (int j = 0; j < 8; ++j)
                        acc[i][j] = fmaf(av, bv[j], acc[i][j]);
                }
            }
        }
        __syncthreads();
    }
#undef STAGE

    const f32x4 g0 = *reinterpret_cast<const f32x4*>(&bias[bn + tx * 8]);
    const f32x4 g1 = *reinterpret_cast<const f32x4*>(&bias[bn + tx * 8 + 4]);
#pragma unroll
    for (int i = 0; i < 8; ++i) {
        const int m = bm + ty * 8 + i;
        const int n = bn + tx * 8;
        f32x4 o0, o1;
#pragma unroll
        for (int j = 0; j < 4; ++j) {
            o0[j] = fmaxf(acc[i][j]     + g0[j], 0.f);
            o1[j] = fmaxf(acc[i][j + 4] + g1[j], 0.f);
        }
        *reinterpret_cast<f32x4*>(&C[(size_t)m * D_S + n])     = o0;
        *reinterpret_cast<f32x4*>(&C[(size_t)m * D_S + n + 4]) = o1;
        short8 h;
#pragma unroll
        for (int j = 0; j < 4; ++j) {
            h[j]     = (short)f2bf(o0[j]);
            h[j + 4] = (short)f2bf(o1[j]);
        }
        *reinterpret_cast<short8*>(&H[(size_t)m * D_S + n]) = h;
    }
}

// ---------------------------------------------------------------------------
// Kernel 2 (round-15): bf16 MFMA score filter — faithful m201-style 8-phase
// half-tile schedule. 256x256 tile, BK=64, 512 threads (8 waves 2Mx4N),
// LDS 128KB = {parity}x{half}x{A,B} 16KB half-tiles.
// Iteration = 2 K-steps (even: parity0, odd: parity1), 4 quadrant-phases each.
// Phase = {ds-reads (12 at q0: 8 B-frags + 4 A; else 4 A) || stage ONE
// half-tile -> s_barrier -> lgkmcnt(0) -> setprio -> 16 MFMA -> setprio ->
// s_barrier}. Staging slots follow death order (Be dies ph0, Ae ph3, Bo ph4,
// Ao ph7); vmcnt(4) only at phases 3 and 7 of each parity group keeps 2
// half-tiles in flight across barriers (never drains mid-loop).
// Hazards hand-verified: staged buffer dead >=1 barrier before write; all
// reads covered by the preceding vmcnt(4) checkpoint.
// ---------------------------------------------------------------------------
__global__ __launch_bounds__(512)
void scores_filter(const unsigned short* __restrict__ TSh,
                   const unsigned short* __restrict__ TCh,
                   unsigned short* __restrict__ G) {
    __shared__ __align__(16) unsigned short sA[2][2][128 * 64];  // [parity][half]
    __shared__ __align__(16) unsigned short sB[2][2][128 * 64];
    const int tid  = threadIdx.x;
    const int lane = tid & 63;
    const int w    = tid >> 6;          // 0..7
    const int mw   = w >> 2;            // A(srt) half: 0..1
    const int nw   = w & 3;             // B(c) quarter: 0..3
    const int bh   = nw >> 1;           // B half this wave reads
    const int lr   = lane & 15, lg = lane >> 4;

    const int hw   = blockIdx.x;
    const int lgid = (hw & 7) * 64 + (hw >> 3);
    const int n0   = (lgid & 31) * 256;     // srt tile
    const int c0   = (lgid >> 5) * 256;     // comment tile

    const f32x4 vzero = {0.f, 0.f, 0.f, 0.f};
    f32x4 acc[8][4];
#pragma unroll
    for (int i = 0; i < 8; ++i)
#pragma unroll
        for (int j = 0; j < 4; ++j) acc[i][j] = vzero;

    // half-tile = 128 rows x 64 k bf16 = 1024 x 16B slots; 2 slots/thread.
    // slot idx -> r=idx>>3, b=idx&7; source k-block = b^(r&7) (involution;
    // read side uses same XOR). r5-verified BK=64 both-sides pattern.
    auto stageHalf = [&](unsigned short* ldsbase, const unsigned short* grow0,
                         int kb) {
#pragma unroll
        for (int i = 0; i < 2; ++i) {
            const int idx = tid + i * 512;
            const int r   = idx >> 3;
            const int sw  = ((idx & 7) ^ (r & 7)) * 8;
            GLOAD_LDS16(grow0 + (size_t)r * D_S + kb + sw,
                        (char*)ldsbase + idx * 16);
        }
    };

    const unsigned short* TS0 = TSh + (size_t)n0 * D_S;          // A half0 rows
    const unsigned short* TS1 = TSh + (size_t)(n0 + 128) * D_S;  // A half1
    const unsigned short* TC0 = TCh + (size_t)c0 * D_S;          // B half0
    const unsigned short* TC1 = TCh + (size_t)(c0 + 128) * D_S;  // B half1

    // prologue: Ae(0) both halves, Be(0) both halves, Bo(1) both halves
    stageHalf(&sA[0][0][0], TS0, 0);
    stageHalf(&sA[0][1][0], TS1, 0);
    stageHalf(&sB[0][0][0], TC0, 0);
    stageHalf(&sB[0][1][0], TC1, 0);
    stageHalf(&sB[1][0][0], TC0, 64);
    stageHalf(&sB[1][1][0], TC1, 64);
    WAIT_VM4;                           // Ae(0)+Be(0) (first 4 half-tiles) landed
    __builtin_amdgcn_s_barrier();

    const int NITER = D_S / 128;        // 8 iterations, 2 K-steps each
    for (int t = 0; t < NITER; ++t) {
        const bool nl = (t + 1 < NITER);   // not last

#pragma unroll
        for (int par = 0; par < 2; ++par) {
            short8 bfr[4][2];
#pragma unroll
            for (int ph = 0; ph < 4; ++ph) {
                // ---- ds reads ----
                short8 afr[2][2];
                if (ph == 0) {
#pragma unroll
                    for (int j = 0; j < 4; ++j) {
                        const int rb = (nw & 1) * 64 + j * 16 + lr;
#pragma unroll
                        for (int kk = 0; kk < 2; ++kk)
                            bfr[j][kk] = *(const short8*)(
                                (const char*)&sB[par][bh][0] + rb * 128 +
                                (((kk * 4 + lg) ^ (rb & 7)) * 16));
                    }
                }
#pragma unroll
                for (int ii = 0; ii < 2; ++ii) {
                    const int ra = (ph * 2 + ii) * 16 + lr;
#pragma unroll
                    for (int kk = 0; kk < 2; ++kk)
                        afr[ii][kk] = *(const short8*)(
                            (const char*)&sA[par][mw][0] + ra * 128 +
                            (((kk * 4 + lg) ^ (ra & 7)) * 16));
                }
                // ---- stage one half-tile (slot table) ----
                if (par == 0) {
                    if (ph == 0)            stageHalf(&sA[1][0][0], TS0, (2*t+1)*64); // Ao h0
                    else if (ph == 1)       stageHalf(&sA[1][1][0], TS1, (2*t+1)*64); // Ao h1
                    else if (ph == 2) { if (nl) stageHalf(&sB[0][0][0], TC0, (2*t+2)*64); } // Be' h0
                    else              { if (nl) stageHalf(&sB[0][1][0], TC1, (2*t+2)*64); } // Be' h1
                } else {
                    if (ph == 0)      { if (nl) stageHalf(&sA[0][0][0], TS0, (2*t+2)*64); } // Ae' h0
                    else if (ph == 1) { if (nl) stageHalf(&sA[0][1][0], TS1, (2*t+2)*64); } // Ae' h1
                    else if (ph == 2) { if (nl) stageHalf(&sB[1][0][0], TC0, (2*t+3)*64); } // Bo' h0
                    else              { if (nl) stageHalf(&sB[1][1][0], TC1, (2*t+3)*64); } // Bo' h1
                }
                // ---- counted vmcnt at the 4th phase of each parity group ----
                if (ph == 3) { if (nl) { WAIT_VM4; } else { WAIT_VM0; } }
                __builtin_amdgcn_s_barrier();
                WAIT_LGKM;
                __builtin_amdgcn_s_setprio(1);
#pragma unroll
                for (int ii = 0; ii < 2; ++ii)
#pragma unroll
                    for (int j = 0; j < 4; ++j)
#pragma unroll
                        for (int kk = 0; kk < 2; ++kk)
                            acc[ph * 2 + ii][j] = __builtin_amdgcn_mfma_f32_16x16x32_bf16(
                                afr[ii][kk], bfr[j][kk], acc[ph * 2 + ii][j], 0, 0, 0);
                __builtin_amdgcn_s_setprio(0);
                __builtin_amdgcn_s_barrier();
            }
        }
    }

    // extraction: n = n0 + mw*128 + i*16 + lg*4 + q (4 consecutive -> group max)
#pragma unroll
    for (int i = 0; i < 8; ++i) {
        const int n4 = ((n0 + mw * 128 + i * 16) >> 2) + lg;
#pragma unroll
        for (int j = 0; j < 4; ++j) {
            const int c = c0 + nw * 64 + j * 16 + lr;
            const f32x4 v = acc[i][j];
            const float m = fmaxf(fmaxf(v.x, v.y), fmaxf(v.z, v.w));
            G[(size_t)c * NGRP + n4] = f2bf(m);
        }
    }
}

// ---------------------------------------------------------------------------
// Kernel 3: per comment row, top-8 groups by approx group-max (unchanged).
// ---------------------------------------------------------------------------
__global__ __launch_bounds__(256)
void top_groups(const unsigned short* __restrict__ G, int* __restrict__ g8) {
    const int w = threadIdx.x >> 6, lane = threadIdx.x & 63;
    const int row = blockIdx.x * 4 + w;
    float v[32];
    const unsigned short* gp = G + (size_t)row * NGRP + lane * 32;
#pragma unroll
    for (int i = 0; i < 4; ++i) {
        short8 h = *(const short8*)(gp + i * 8);
#pragma unroll
        for (int j = 0; j < 8; ++j) v[i * 8 + j] = bf2f((unsigned short)h[j]);
    }
    float pv = INFINITY; int pi = -1;
    int gl[8];
#pragma unroll
    for (int k = 0; k < 8; ++k) {
        float bv = -INFINITY; int bi = NGRP;
#pragma unroll
        for (int i = 0; i < 32; ++i) {
            const int idx = lane * 32 + i;
            const bool after  = (v[i] < pv) || (v[i] == pv && idx > pi);
            const bool before = (v[i] > bv) || (v[i] == bv && idx < bi);
            if (after && before) { bv = v[i]; bi = idx; }
        }
#pragma unroll
        for (int off = 32; off >= 1; off >>= 1) {
            const float ov = __shfl_xor(bv, off);
            const int   oi = __shfl_xor(bi, off);
            if ((ov > bv) || (ov == bv && oi < bi)) { bv = ov; bi = oi; }
        }
        gl[k] = bi; pv = bv; pi = bi;
    }
#pragma unroll
    for (int a = 0; a < 8; ++a)
#pragma unroll
        for (int b2 = 0; b2 < 7; ++b2)
            if (gl[b2] > gl[b2 + 1]) { int t = gl[b2]; gl[b2] = gl[b2 + 1]; gl[b2 + 1] = t; }
    if (lane == 0) {
        int4 lo = make_int4(gl[0], gl[1], gl[2], gl[3]);
        int4 hi = make_int4(gl[4], gl[5], gl[6], gl[7]);
        *reinterpret_cast<int4*>(g8 + (size_t)row * 8)     = lo;
        *reinterpret_cast<int4*>(g8 + (size_t)row * 8 + 4) = hi;
    }
}

// ---------------------------------------------------------------------------
// Kernel 4: fused refine + gather (verified). Unchanged.
// ---------------------------------------------------------------------------
__global__ __launch_bounds__(256)
void refine_gather(const float* __restrict__ t_c, const float* __restrict__ t_s,
                   const int* __restrict__ g8, float* __restrict__ out) {
    __shared__ float tc[D_S];
    __shared__ float sc[4 * PGRP];
    __shared__ int   sel[2];
    const int row = blockIdx.x;
    const int tid = threadIdx.x;
    *reinterpret_cast<float4*>(&tc[tid * 4]) =
        *reinterpret_cast<const float4*>(&t_c[(size_t)row * D_S + tid * 4]);
    __syncthreads();
    const int w = tid >> 6, lane = tid & 63;
    float4 c4[4];
#pragma unroll
    for (int q = 0; q < 4; ++q)
        c4[q] = *reinterpret_cast<const float4*>(&tc[lane * 16 + q * 4]);
#pragma unroll
    for (int i = 0; i < 2; ++i) {
        const int slotg = w * 2 + i;
        const int g = g8[(size_t)row * 8 + slotg];
#pragma unroll
        for (int o = 0; o < 4; ++o) {
            const int n = g * 4 + o;
            const float* ts = t_s + (size_t)n * D_S + lane * 16;
            float p = 0.f;
#pragma unroll
            for (int q = 0; q < 4; ++q) {
                const float4 tv = *reinterpret_cast<const float4*>(ts + q * 4);
                p += c4[q].x * tv.x + c4[q].y * tv.y + c4[q].z * tv.z + c4[q].w * tv.w;
            }
#pragma unroll
            for (int off = 32; off >= 1; off >>= 1) p += __shfl_xor(p, off);
            if (lane == 0) sc[slotg * 4 + o] = p;
        }
    }
    __syncthreads();
    if (tid == 0) {
        float v1 = -INFINITY, v2 = -INFINITY; int i1 = 0, i2 = 0;
#pragma unroll
        for (int s = 0; s < 4 * PGRP; ++s) {
            const int n = g8[(size_t)row * 8 + (s >> 2)] * 4 + (s & 3);
            const float v = sc[s];
            if (v > v1)      { v2 = v1; i2 = i1; v1 = v; i1 = n; }
            else if (v > v2) { v2 = v; i2 = n; }
        }
        sel[0] = i1; sel[1] = i2;
    }
    __syncthreads();
#pragma unroll
    for (int q = 0; q < 2; ++q) {
        const int src = sel[q];
        const float4 v = *reinterpret_cast<const float4*>(
            &t_s[(size_t)src * D_S + tid * 4]);
        *reinterpret_cast<float4*>(
            &out[((size_t)row * KSEL + q) * D_S + tid * 4]) = v;
    }
}

// ---------------------------------------------------------------------------
extern "C" void kernel_launch(void* const* d_in, const int* in_sizes, int n_in,
                              void* d_out, int out_size, void* d_ws, size_t ws_size,
                              hipStream_t stream) {
    const float* srt      = (const float*)d_in[0];  // [8192,1024]
    const float* comments = (const float*)d_in[1];  // [4096,768]
    const float* Wc       = (const float*)d_in[2];  // [768,1024]
    const float* bc       = (const float*)d_in[3];  // [1024]
    const float* Ws       = (const float*)d_in[4];  // [1024,1024]
    const float* bs       = (const float*)d_in[5];  // [1024]
    float* out = (float*)d_out;

    // base workspace layout (identical to previous rounds)
    char* p = (char*)d_ws;
    float* t_c = (float*)p;          p += (size_t)B_C * D_S * 4;     // 16 MB
    float* t_s = (float*)p;          p += (size_t)N_SRT * D_S * 4;   // 32 MB
    unsigned short* tc_h = (unsigned short*)p; p += (size_t)B_C * D_S * 2;    // 8 MB
    unsigned short* ts_h = (unsigned short*)p; p += (size_t)N_SRT * D_S * 2;  // 16 MB
    unsigned short* G    = (unsigned short*)p; p += (size_t)B_C * NGRP * 2;   // 16 MB
    int* g8   = (int*)p;             p += (size_t)B_C * PGRP * 4;
    p += (size_t)B_C * KSEL * 4;     // (tidx slot kept for layout, unused)

    // fp16 2-plane workspace (appended; ~53.4 MB)
    _Float16* actS = (_Float16*)p; p += 2 * (size_t)N_SRT * D_S * 2; // 33.5 MB
    _Float16* actC = (_Float16*)p; p += 2 * (size_t)B_C * D_C * 2;   // 12.6 MB
    _Float16* wtS  = (_Float16*)p; p += 2 * (size_t)D_S * D_S * 2;   // 4.2 MB
    _Float16* wtC  = (_Float16*)p; p += 2 * (size_t)D_S * D_C * 2;   // 3.1 MB
    const size_t required = (size_t)(p - (char*)d_ws);

    if (ws_size >= required) {
        // --- scaled fp16x3 MFMA transform path ---
        split_act<<<(N_SRT * D_S / 8 + B_C * D_C / 8) / 256, 256, 0, stream>>>(
            srt, comments, actS, actC);
        split_w_all<<<256 + 192, 256, 0, stream>>>(Ws, wtS, Wc, wtC);

        transform_mfma_all<<<512 + 256, 256, 0, stream>>>(
            actS, wtS, bs, t_s, ts_h,
            actC, wtC, bc, t_c, tc_h);
    } else {
        // --- fallback: round-5 verified fp32 VALU path ---
        transform_fused<<<NB0 + NB1, 256, 0, stream>>>(
            comments, Wc, bc, t_c, tc_h,
            srt,      Ws, bs, t_s, ts_h);
    }

    scores_filter<<<512, 512, 0, stream>>>(ts_h, tc_h, G);
    top_groups<<<B_C / 4, 256, 0, stream>>>(G, g8);
    refine_gather<<<B_C, 256, 0, stream>>>(t_c, t_s, g8, out);
}

// Round 16
// 243.375 us; speedup vs baseline: 1.3642x; 1.1298x over previous
//
#include <hip/hip_runtime.h>
#include <math.h>

#define B_C   4096   // comments
#define N_SRT 8192   // srt rows
#define D_C   768
#define D_S   1024
#define KSEL  2
#define NGRP  (N_SRT / 4)   // 2048 groups of 4 consecutive srt rows
#define PGRP  8             // groups refined per comment row (32 candidates)

typedef float    f32x4  __attribute__((ext_vector_type(4)));
typedef short    short8 __attribute__((ext_vector_type(8)));
typedef _Float16 half8  __attribute__((ext_vector_type(8)));

__device__ inline unsigned short f2bf(float f) {           // RTNE float->bf16
    unsigned u = __float_as_uint(f);
    u += 0x7FFF + ((u >> 16) & 1);
    return (unsigned short)(u >> 16);
}
__device__ inline float bf2f(unsigned short h) {
    return __uint_as_float(((unsigned)h) << 16);
}

#define GLOAD_LDS16(gsrc, ldst)                                                     \
    __builtin_amdgcn_global_load_lds(                                               \
        (const __attribute__((address_space(1))) void*)(gsrc),                      \
        (__attribute__((address_space(3))) void*)(ldst), 16, 0, 0)

// counted-vmcnt barrier pieces
#define WAIT_VM4  asm volatile("s_waitcnt vmcnt(4)" ::: "memory")
#define WAIT_VM0  asm volatile("s_waitcnt vmcnt(0)" ::: "memory")
#define WAIT_LGKM asm volatile("s_waitcnt lgkmcnt(0)" ::: "memory")

// ---------------------------------------------------------------------------
// split_all (round-16: act split + weight split in ONE launch).
// Blocks [0, NS_ACT): fp16 2-term split of activations (verified logic).
// Blocks [NS_ACT, NS_ACT+448): W -> 2 fp16 planes of W^T (verified logic).
// ---------------------------------------------------------------------------
#define NS_ACT ((N_SRT * D_S / 8 + B_C * D_C / 8) / 256)   // 5632

__global__ __launch_bounds__(256)
void split_all(const float* __restrict__ srt, const float* __restrict__ com,
               _Float16* __restrict__ pS, _Float16* __restrict__ pC,
               const float* __restrict__ Ws, _Float16* __restrict__ WtS,
               const float* __restrict__ Wc, _Float16* __restrict__ WtC) {
    __shared__ float t[64][65];
    if ((int)blockIdx.x < NS_ACT) {
        const int g = blockIdx.x * 256 + threadIdx.x;
        const int E0 = N_SRT * D_S / 8;
        const float* src;
        _Float16* dst;
        size_t stride;
        if (g < E0) {
            src = srt + (size_t)g * 8; dst = pS + (size_t)g * 8;
            stride = (size_t)N_SRT * D_S;
        } else {
            const int g2 = g - E0;
            src = com + (size_t)g2 * 8; dst = pC + (size_t)g2 * 8;
            stride = (size_t)B_C * D_C;
        }
        const float4 a = *reinterpret_cast<const float4*>(src);
        const float4 b = *reinterpret_cast<const float4*>(src + 4);
        const float x[8] = {a.x, a.y, a.z, a.w, b.x, b.y, b.z, b.w};
        half8 hv, mv;
#pragma unroll
        for (int j = 0; j < 8; ++j) {
            const _Float16 h = (_Float16)x[j];
            const float    r = x[j] - (float)h;          // exact
            hv[j] = h; mv[j] = (_Float16)(r * 2048.0f);
        }
        *reinterpret_cast<half8*>(dst)          = hv;
        *reinterpret_cast<half8*>(dst + stride) = mv;
    } else {
        const int bb = (int)blockIdx.x - NS_ACT;
        const bool p1 = bb >= 256;
        const int  b  = p1 ? bb - 256 : bb;
        const float* __restrict__ W = p1 ? Wc : Ws;
        _Float16* __restrict__ Wt   = p1 ? WtC : WtS;
        const int K  = p1 ? D_C : D_S;
        const int n0 = (b & 15) * 64, k0 = (b >> 4) * 64;

        const int tid = threadIdx.x;
        const int c = tid & 63, rq = tid >> 6;
#pragma unroll
        for (int j = 0; j < 16; ++j) {
            const int kr = rq * 16 + j;
            t[kr][c] = W[(size_t)(k0 + kr) * D_S + n0 + c];
        }
        __syncthreads();
        const size_t PS = (size_t)K * D_S;
#pragma unroll
        for (int j = 0; j < 16; ++j) {
            const int nr = rq * 16 + j;
            const float xs = t[c][nr] * 32768.0f;        // exact (pow2 scale)
            const _Float16 h = (_Float16)xs;
            const float    r = xs - (float)h;            // exact
            const size_t o = (size_t)(n0 + nr) * K + k0 + c;
            Wt[o]      = h;
            Wt[o + PS] = (_Float16)(r * 2048.0f);
        }
    }
}

// ---------------------------------------------------------------------------
// transform_mfma_all: round-13 verified (chunk-fused scaled fp16x3). Frozen.
// ---------------------------------------------------------------------------
__global__ __launch_bounds__(256)
void transform_mfma_all(const _Float16* __restrict__ actS,
                        const _Float16* __restrict__ wtS,
                        const float* __restrict__ bS,
                        float* __restrict__ CS, unsigned short* __restrict__ HS,
                        const _Float16* __restrict__ actC,
                        const _Float16* __restrict__ wtC,
                        const float* __restrict__ bC,
                        float* __restrict__ CC, unsigned short* __restrict__ HC) {
    __shared__ __align__(16) _Float16 sW[2][2][128 * 32];  // [buf][plane]
    __shared__ __align__(16) _Float16 sA[2][2][128 * 32];
    const int tid  = threadIdx.x;
    const int lane = tid & 63;
    const int w    = tid >> 6;
    const int lr   = lane & 15, lg = lane >> 4;
    const int wn   = w & 1, wc = w >> 1;

    const int hw = blockIdx.x;
    int lgid, seg;
    if (hw < 512) { seg = 0; lgid = (hw & 7) * 64 + (hw >> 3); }
    else          { const int h2 = hw - 512; seg = 1; lgid = (h2 & 7) * 32 + (h2 >> 3); }

    const _Float16* __restrict__ actP = seg ? actC : actS;
    const _Float16* __restrict__ wtP  = seg ? wtC  : wtS;
    const float* __restrict__ bias    = seg ? bC   : bS;
    float* __restrict__ C             = seg ? CC   : CS;
    unsigned short* __restrict__ H    = seg ? HC   : HS;
    const int K   = seg ? D_C : D_S;
    const int NC  = seg ? (D_C / 32) : (D_S / 32);    // 24 : 32 chunks
    const size_t aps = seg ? (size_t)B_C * D_C : (size_t)N_SRT * D_S;
    const size_t wps = (size_t)D_S * K;

    const int bn = (lgid & 7) * 128;
    const int bm = (lgid >> 3) * 128;

    const f32x4 vzero = {0.f, 0.f, 0.f, 0.f};
    f32x4 acc[4][4];
#pragma unroll
    for (int i = 0; i < 4; ++i)
#pragma unroll
        for (int j = 0; j < 4; ++j) acc[i][j] = vzero;

    auto stage = [&](int buf, int c) {
        const int kb = c * 32;
#pragma unroll
        for (int i = 0; i < 2; ++i) {
            const int idx = tid + i * 256;
            const int r   = idx >> 2;
            const int sw  = ((idx & 3) ^ ((r >> 1) & 3)) * 8;
            const size_t wo = (size_t)(bn + r) * K + kb + sw;
            const size_t ao = (size_t)(bm + r) * K + kb + sw;
            GLOAD_LDS16(wtP  + wo,       (char*)&sW[buf][0][0] + idx * 16);
            GLOAD_LDS16(wtP  + wps + wo, (char*)&sW[buf][1][0] + idx * 16);
            GLOAD_LDS16(actP + ao,       (char*)&sA[buf][0][0] + idx * 16);
            GLOAD_LDS16(actP + aps + ao, (char*)&sA[buf][1][0] + idx * 16);
        }
    };

    stage(0, 0);
    WAIT_VM0;
    __builtin_amdgcn_s_barrier();

    for (int c = 0; c < NC; ++c) {
        const int cur = c & 1;
        if (c + 1 < NC) stage(cur ^ 1, c + 1);

        half8 a0[4], a1[4], b0[4], b1[4], b0s[4];
#pragma unroll
        for (int t4 = 0; t4 < 4; ++t4) {
            const int ra = wn * 64 + t4 * 16 + lr;
            const int oa = ra * 64 + ((lg ^ ((ra >> 1) & 3)) * 16);
            a0[t4] = *(const half8*)((const char*)&sW[cur][0][0] + oa);
            a1[t4] = *(const half8*)((const char*)&sW[cur][1][0] + oa);
            const int rb = wc * 64 + t4 * 16 + lr;
            const int ob = rb * 64 + ((lg ^ ((rb >> 1) & 3)) * 16);
            b0[t4] = *(const half8*)((const char*)&sA[cur][0][0] + ob);
            b1[t4] = *(const half8*)((const char*)&sA[cur][1][0] + ob);
            b0s[t4] = b0[t4] * (_Float16)2048.0f;    // exact pow2
        }
        __builtin_amdgcn_s_setprio(1);
#pragma unroll
        for (int i = 0; i < 4; ++i)
#pragma unroll
            for (int j = 0; j < 4; ++j) {
                acc[i][j] = __builtin_amdgcn_mfma_f32_16x16x32_f16(
                    a0[i], b0s[j], acc[i][j], 0, 0, 0);   // hh (2^26)
                acc[i][j] = __builtin_amdgcn_mfma_f32_16x16x32_f16(
                    a0[i], b1[j],  acc[i][j], 0, 0, 0);   // hm (2^26)
                acc[i][j] = __builtin_amdgcn_mfma_f32_16x16x32_f16(
                    a1[i], b0[j],  acc[i][j], 0, 0, 0);   // mh (2^26)
            }
        __builtin_amdgcn_s_setprio(0);

        WAIT_VM0;
        WAIT_LGKM;
        __builtin_amdgcn_s_barrier();
    }

    const float s2 = 1.4901161193847656e-8f;    // 2^-26
#pragma unroll
    for (int i = 0; i < 4; ++i) {
        const int n = bn + wn * 64 + i * 16 + lg * 4;
        const f32x4 bb = *reinterpret_cast<const f32x4*>(&bias[n]);
#pragma unroll
        for (int j = 0; j < 4; ++j) {
            const int m = bm + wc * 64 + j * 16 + lr;
            f32x4 o;
#pragma unroll
            for (int q = 0; q < 4; ++q)
                o[q] = fmaxf(fmaf(acc[i][j][q], s2, bb[q]), 0.f);
            *reinterpret_cast<f32x4*>(&C[(size_t)m * D_S + n]) = o;
            ushort4 hh;
            hh.x = f2bf(o[0]); hh.y = f2bf(o[1]);
            hh.z = f2bf(o[2]); hh.w = f2bf(o[3]);
            *reinterpret_cast<ushort4*>(&H[(size_t)m * D_S + n]) = hh;
        }
    }
}

// ---------------------------------------------------------------------------
// FALLBACK (round-5 verified): fused fp32 VALU transforms (ws too small).
// ---------------------------------------------------------------------------
#define NB0 ((B_C / 128) * (D_S / 128))     // 256
#define NB1 ((N_SRT / 128) * (D_S / 128))   // 512

__global__ __launch_bounds__(256)
void transform_fused(const float* __restrict__ A0, const float* __restrict__ W0,
                     const float* __restrict__ b0, float* __restrict__ C0,
                     unsigned short* __restrict__ H0,
                     const float* __restrict__ A1, const float* __restrict__ W1,
                     const float* __restrict__ b1, float* __restrict__ C1,
                     unsigned short* __restrict__ H1) {
    __shared__ __align__(16) float As[2][128][16];
    __shared__ __align__(16) float Bs[2][2048];

    const bool p1 = (int)blockIdx.x >= NB0;
    const int  b  = p1 ? (int)blockIdx.x - NB0 : (int)blockIdx.x;
    const float* __restrict__ A = p1 ? A1 : A0;
    const float* __restrict__ W = p1 ? W1 : W0;
    const float* __restrict__ bias = p1 ? b1 : b0;
    float* __restrict__ C = p1 ? C1 : C0;
    unsigned short* __restrict__ H = p1 ? H1 : H0;
    const int K = p1 ? D_S : D_C;

    const int bn = (b & 7) * 128;
    const int bm = (b >> 3) * 128;

    const int tid = threadIdx.x;
    const int tx = tid & 15, ty = tid >> 4;

    int a_off[2], w_off[2];
#pragma unroll
    for (int i = 0; i < 2; ++i) {
        const int idx = tid + i * 256;
        const int r = idx >> 2, q = idx & 3;
        a_off[i] = r * K + (q ^ ((r >> 3) & 3)) * 4;
        const int s = idx & 63;
        const int kloc = 2 * (idx >> 6) + ((s >> 4) & 1);
        const int cb   = 2 * (s & 15) + (s >> 5);
        w_off[i] = kloc * D_S + cb * 4;
    }

#define STAGE(bufi, k0)                                                        \
    {                                                                          \
        _Pragma("unroll")                                                      \
        for (int i = 0; i < 2; ++i) {                                          \
            const int idx = tid + i * 256;                                     \
            GLOAD_LDS16(A + (size_t)bm * K + (k0) + a_off[i],                  \
                        (char*)&As[bufi][0][0] + idx * 16);                    \
            GLOAD_LDS16(W + (size_t)(k0) * D_S + bn + w_off[i],                \
                        (char*)&Bs[bufi][0] + idx * 16);                       \
        }                                                                      \
    }

    float acc[8][8] = {};

    STAGE(0, 0);
    __syncthreads();

    const int nk = K / 16;
    for (int t = 0; t < nk; ++t) {
        const int cur = t & 1;
        if (t + 1 < nk) STAGE(t & 1 ? 0 : 1, (t + 1) * 16);

        const float* __restrict__ Bf = &Bs[cur][0];
#pragma unroll
        for (int kq = 0; kq < 4; ++kq) {
            f32x4 a4[8];
#pragma unroll
            for (int i = 0; i < 8; ++i)
                a4[i] = *reinterpret_cast<const f32x4*>(
                    &As[cur][ty * 8 + i][(kq ^ (ty & 3)) * 4]);
#pragma unroll
            for (int k2 = 0; k2 < 4; ++k2) {
                const int k = kq * 4 + k2;
                const int boff = (k >> 1) * 256 + (tx + ((k & 1) << 4)) * 4;
                const f32x4 bx = *reinterpret_cast<const f32x4*>(Bf + boff);
                const f32x4 by = *reinterpret_cast<const f32x4*>(Bf + boff + 128);
                const float bv[8] = {bx[0], bx[1], bx[2], bx[3], by[0], by[1], by[2], by[3]};
#pragma unroll
                for (int i = 0; i < 8; ++i) {
                    const float av = a4[i][k2];
#pragma unroll
                    for (int j = 0; j < 8; ++j)
                        acc[i][j] = fmaf(av, bv[j], acc[i][j]);
                }
            }
        }
        __syncthreads();
    }
#undef STAGE

    const f32x4 g0 = *reinterpret_cast<const f32x4*>(&bias[bn + tx * 8]);
    const f32x4 g1 = *reinterpret_cast<const f32x4*>(&bias[bn + tx * 8 + 4]);
#pragma unroll
    for (int i = 0; i < 8; ++i) {
        const int m = bm + ty * 8 + i;
        const int n = bn + tx * 8;
        f32x4 o0, o1;
#pragma unroll
        for (int j = 0; j < 4; ++j) {
            o0[j] = fmaxf(acc[i][j]     + g0[j], 0.f);
            o1[j] = fmaxf(acc[i][j + 4] + g1[j], 0.f);
        }
        *reinterpret_cast<f32x4*>(&C[(size_t)m * D_S + n])     = o0;
        *reinterpret_cast<f32x4*>(&C[(size_t)m * D_S + n + 4]) = o1;
        short8 h;
#pragma unroll
        for (int j = 0; j < 4; ++j) {
            h[j]     = (short)f2bf(o0[j]);
            h[j + 4] = (short)f2bf(o1[j]);
        }
        *reinterpret_cast<short8*>(&H[(size_t)m * D_S + n]) = h;
    }
}

// ---------------------------------------------------------------------------
// Kernel 2: bf16 MFMA score filter — round-15 verified 8-phase main loop.
// Round-16 epilogue: per-(c row, 128-srt half) top-2 over the 32 group-maxes
// held in registers (per-lane top-2 over 8 regs + shfl_xor(16,32) merge
// across lg lanes), written directly to part[c][64] float4 entries
// {v1, g1, v2, g2}. G matrix eliminated (16MB write + 16MB read saved).
// Guard: true top-2's group survives per-half top-2 iff <2 in-half
// competitors noise-beat it (gaps ~0.2 vs bf16 noise ~0.01) — safe; refine
// re-ranks the candidate set exactly, so selection semantics are unchanged.
// ---------------------------------------------------------------------------
__global__ __launch_bounds__(512)
void scores_filter(const unsigned short* __restrict__ TSh,
                   const unsigned short* __restrict__ TCh,
                   float* __restrict__ part) {     // [B_C][64] float4 entries
    __shared__ __align__(16) unsigned short sA[2][2][128 * 64];  // [parity][half]
    __shared__ __align__(16) unsigned short sB[2][2][128 * 64];
    const int tid  = threadIdx.x;
    const int lane = tid & 63;
    const int w    = tid >> 6;          // 0..7
    const int mw   = w >> 2;            // A(srt) half: 0..1
    const int nw   = w & 3;             // B(c) quarter: 0..3
    const int bh   = nw >> 1;           // B half this wave reads
    const int lr   = lane & 15, lg = lane >> 4;

    const int hw   = blockIdx.x;
    const int lgid = (hw & 7) * 64 + (hw >> 3);
    const int n0   = (lgid & 31) * 256;     // srt tile
    const int c0   = (lgid >> 5) * 256;     // comment tile

    const f32x4 vzero = {0.f, 0.f, 0.f, 0.f};
    f32x4 acc[8][4];
#pragma unroll
    for (int i = 0; i < 8; ++i)
#pragma unroll
        for (int j = 0; j < 4; ++j) acc[i][j] = vzero;

    auto stageHalf = [&](unsigned short* ldsbase, const unsigned short* grow0,
                         int kb) {
#pragma unroll
        for (int i = 0; i < 2; ++i) {
            const int idx = tid + i * 512;
            const int r   = idx >> 3;
            const int sw  = ((idx & 7) ^ (r & 7)) * 8;
            GLOAD_LDS16(grow0 + (size_t)r * D_S + kb + sw,
                        (char*)ldsbase + idx * 16);
        }
    };

    const unsigned short* TS0 = TSh + (size_t)n0 * D_S;
    const unsigned short* TS1 = TSh + (size_t)(n0 + 128) * D_S;
    const unsigned short* TC0 = TCh + (size_t)c0 * D_S;
    const unsigned short* TC1 = TCh + (size_t)(c0 + 128) * D_S;

    stageHalf(&sA[0][0][0], TS0, 0);
    stageHalf(&sA[0][1][0], TS1, 0);
    stageHalf(&sB[0][0][0], TC0, 0);
    stageHalf(&sB[0][1][0], TC1, 0);
    stageHalf(&sB[1][0][0], TC0, 64);
    stageHalf(&sB[1][1][0], TC1, 64);
    WAIT_VM4;
    __builtin_amdgcn_s_barrier();

    const int NITER = D_S / 128;        // 8 iterations, 2 K-steps each
    for (int t = 0; t < NITER; ++t) {
        const bool nl = (t + 1 < NITER);

#pragma unroll
        for (int par = 0; par < 2; ++par) {
            short8 bfr[4][2];
#pragma unroll
            for (int ph = 0; ph < 4; ++ph) {
                short8 afr[2][2];
                if (ph == 0) {
#pragma unroll
                    for (int j = 0; j < 4; ++j) {
                        const int rb = (nw & 1) * 64 + j * 16 + lr;
#pragma unroll
                        for (int kk = 0; kk < 2; ++kk)
                            bfr[j][kk] = *(const short8*)(
                                (const char*)&sB[par][bh][0] + rb * 128 +
                                (((kk * 4 + lg) ^ (rb & 7)) * 16));
                    }
                }
#pragma unroll
                for (int ii = 0; ii < 2; ++ii) {
                    const int ra = (ph * 2 + ii) * 16 + lr;
#pragma unroll
                    for (int kk = 0; kk < 2; ++kk)
                        afr[ii][kk] = *(const short8*)(
                            (const char*)&sA[par][mw][0] + ra * 128 +
                            (((kk * 4 + lg) ^ (ra & 7)) * 16));
                }
                if (par == 0) {
                    if (ph == 0)            stageHalf(&sA[1][0][0], TS0, (2*t+1)*64);
                    else if (ph == 1)       stageHalf(&sA[1][1][0], TS1, (2*t+1)*64);
                    else if (ph == 2) { if (nl) stageHalf(&sB[0][0][0], TC0, (2*t+2)*64); }
                    else              { if (nl) stageHalf(&sB[0][1][0], TC1, (2*t+2)*64); }
                } else {
                    if (ph == 0)      { if (nl) stageHalf(&sA[0][0][0], TS0, (2*t+2)*64); }
                    else if (ph == 1) { if (nl) stageHalf(&sA[0][1][0], TS1, (2*t+2)*64); }
                    else if (ph == 2) { if (nl) stageHalf(&sB[1][0][0], TC0, (2*t+3)*64); }
                    else              { if (nl) stageHalf(&sB[1][1][0], TC1, (2*t+3)*64); }
                }
                if (ph == 3) { if (nl) { WAIT_VM4; } else { WAIT_VM0; } }
                __builtin_amdgcn_s_barrier();
                WAIT_LGKM;
                __builtin_amdgcn_s_setprio(1);
#pragma unroll
                for (int ii = 0; ii < 2; ++ii)
#pragma unroll
                    for (int j = 0; j < 4; ++j)
#pragma unroll
                        for (int kk = 0; kk < 2; ++kk)
                            acc[ph * 2 + ii][j] = __builtin_amdgcn_mfma_f32_16x16x32_bf16(
                                afr[ii][kk], bfr[j][kk], acc[ph * 2 + ii][j], 0, 0, 0);
                __builtin_amdgcn_s_setprio(0);
                __builtin_amdgcn_s_barrier();
            }
        }
    }

    // ---- round-16 epilogue: per-(c, half) top-2 -> part ----
    const int gbase = (n0 >> 2) + mw * 32;
#pragma unroll
    for (int j = 0; j < 4; ++j) {
        float v1 = -INFINITY, v2 = -INFINITY;
        int   g1 = 0, g2 = 0;
#pragma unroll
        for (int i = 0; i < 8; ++i) {
            const f32x4 v = acc[i][j];
            const float m = fmaxf(fmaxf(v.x, v.y), fmaxf(v.z, v.w));
            const int g = gbase + i * 4 + lg;
            if (m > v1)      { v2 = v1; g2 = g1; v1 = m; g1 = g; }
            else if (m > v2) { v2 = m; g2 = g; }
        }
        // merge across the 4 lg lanes (lane bits 4-5): xor 16, then 32
#pragma unroll
        for (int off = 16; off <= 32; off <<= 1) {
            const float ov1 = __shfl_xor(v1, off);
            const int   og1 = __shfl_xor(g1, off);
            const float ov2 = __shfl_xor(v2, off);
            const int   og2 = __shfl_xor(g2, off);
            if (ov1 > v1 || (ov1 == v1 && og1 < g1)) { v2 = v1; g2 = g1; v1 = ov1; g1 = og1; }
            else if (ov1 > v2 || (ov1 == v2 && og1 < g2)) { v2 = ov1; g2 = og1; }
            if (ov2 > v1 || (ov2 == v1 && og2 < g1)) { v2 = v1; g2 = g1; v1 = ov2; g1 = og2; }
            else if (ov2 > v2 || (ov2 == v2 && og2 < g2)) { v2 = ov2; g2 = og2; }
        }
        if (lg == 0) {
            const int c = c0 + nw * 64 + j * 16 + lr;
            const int blk2 = (lgid & 31) * 2 + mw;   // entry slot (ascending n)
            f32x4 e;
            e[0] = v1; e[1] = __int_as_float(g1);
            e[2] = v2; e[3] = __int_as_float(g2);
            *reinterpret_cast<f32x4*>(&part[((size_t)c * 64 + blk2) * 4]) = e;
        }
    }
}

// ---------------------------------------------------------------------------
// Kernel 3 (round-16): top-8 groups per row from the 64 partial top-2
// entries (128 candidates). One wave per row; lane holds one entry.
// 8 rounds of wave-argmax with total order (value desc, group asc).
// Output sorted ascending (refine's exact ascending-scan tie rule).
// ---------------------------------------------------------------------------
__global__ __launch_bounds__(256)
void top8_merge(const float* __restrict__ part, int* __restrict__ g8) {
    const int w = threadIdx.x >> 6, lane = threadIdx.x & 63;
    const int row = blockIdx.x * 4 + w;
    const f32x4 e = *reinterpret_cast<const f32x4*>(&part[((size_t)row * 64 + lane) * 4]);
    const float v[2]  = {e[0], e[2]};
    const int   gi[2] = {__float_as_int(e[1]), __float_as_int(e[3])};
    float pv = INFINITY; int pi = -1;
    int gl[8];
#pragma unroll
    for (int k = 0; k < 8; ++k) {
        float bv = -INFINITY; int bi = 0x7FFFFFFF;
#pragma unroll
        for (int s = 0; s < 2; ++s) {
            const bool after  = (v[s] < pv) || (v[s] == pv && gi[s] > pi);
            const bool before = (v[s] > bv) || (v[s] == bv && gi[s] < bi);
            if (after && before) { bv = v[s]; bi = gi[s]; }
        }
#pragma unroll
        for (int off = 32; off >= 1; off >>= 1) {
            const float ov = __shfl_xor(bv, off);
            const int   oi = __shfl_xor(bi, off);
            if ((ov > bv) || (ov == bv && oi < bi)) { bv = ov; bi = oi; }
        }
        gl[k] = bi; pv = bv; pi = bi;
    }
#pragma unroll
    for (int a = 0; a < 8; ++a)
#pragma unroll
        for (int b2 = 0; b2 < 7; ++b2)
            if (gl[b2] > gl[b2 + 1]) { int t = gl[b2]; gl[b2] = gl[b2 + 1]; gl[b2 + 1] = t; }
    if (lane == 0) {
        int4 lo = make_int4(gl[0], gl[1], gl[2], gl[3]);
        int4 hi = make_int4(gl[4], gl[5], gl[6], gl[7]);
        *reinterpret_cast<int4*>(g8 + (size_t)row * 8)     = lo;
        *reinterpret_cast<int4*>(g8 + (size_t)row * 8 + 4) = hi;
    }
}

// ---------------------------------------------------------------------------
// Kernel 4: fused refine + gather (verified). Unchanged.
// ---------------------------------------------------------------------------
__global__ __launch_bounds__(256)
void refine_gather(const float* __restrict__ t_c, const float* __restrict__ t_s,
                   const int* __restrict__ g8, float* __restrict__ out) {
    __shared__ float tc[D_S];
    __shared__ float sc[4 * PGRP];
    __shared__ int   sel[2];
    const int row = blockIdx.x;
    const int tid = threadIdx.x;
    *reinterpret_cast<float4*>(&tc[tid * 4]) =
        *reinterpret_cast<const float4*>(&t_c[(size_t)row * D_S + tid * 4]);
    __syncthreads();
    const int w = tid >> 6, lane = tid & 63;
    float4 c4[4];
#pragma unroll
    for (int q = 0; q < 4; ++q)
        c4[q] = *reinterpret_cast<const float4*>(&tc[lane * 16 + q * 4]);
#pragma unroll
    for (int i = 0; i < 2; ++i) {
        const int slotg = w * 2 + i;
        const int g = g8[(size_t)row * 8 + slotg];
#pragma unroll
        for (int o = 0; o < 4; ++o) {
            const int n = g * 4 + o;
            const float* ts = t_s + (size_t)n * D_S + lane * 16;
            float p = 0.f;
#pragma unroll
            for (int q = 0; q < 4; ++q) {
                const float4 tv = *reinterpret_cast<const float4*>(ts + q * 4);
                p += c4[q].x * tv.x + c4[q].y * tv.y + c4[q].z * tv.z + c4[q].w * tv.w;
            }
#pragma unroll
            for (int off = 32; off >= 1; off >>= 1) p += __shfl_xor(p, off);
            if (lane == 0) sc[slotg * 4 + o] = p;
        }
    }
    __syncthreads();
    if (tid == 0) {
        float v1 = -INFINITY, v2 = -INFINITY; int i1 = 0, i2 = 0;
#pragma unroll
        for (int s = 0; s < 4 * PGRP; ++s) {
            const int n = g8[(size_t)row * 8 + (s >> 2)] * 4 + (s & 3);
            const float v = sc[s];
            if (v > v1)      { v2 = v1; i2 = i1; v1 = v; i1 = n; }
            else if (v > v2) { v2 = v; i2 = n; }
        }
        sel[0] = i1; sel[1] = i2;
    }
    __syncthreads();
#pragma unroll
    for (int q = 0; q < 2; ++q) {
        const int src = sel[q];
        const float4 v = *reinterpret_cast<const float4*>(
            &t_s[(size_t)src * D_S + tid * 4]);
        *reinterpret_cast<float4*>(
            &out[((size_t)row * KSEL + q) * D_S + tid * 4]) = v;
    }
}

// ---------------------------------------------------------------------------
extern "C" void kernel_launch(void* const* d_in, const int* in_sizes, int n_in,
                              void* d_out, int out_size, void* d_ws, size_t ws_size,
                              hipStream_t stream) {
    const float* srt      = (const float*)d_in[0];  // [8192,1024]
    const float* comments = (const float*)d_in[1];  // [4096,768]
    const float* Wc       = (const float*)d_in[2];  // [768,1024]
    const float* bc       = (const float*)d_in[3];  // [1024]
    const float* Ws       = (const float*)d_in[4];  // [1024,1024]
    const float* bs       = (const float*)d_in[5];  // [1024]
    float* out = (float*)d_out;

    // base workspace layout
    char* p = (char*)d_ws;
    float* t_c = (float*)p;          p += (size_t)B_C * D_S * 4;     // 16 MB
    float* t_s = (float*)p;          p += (size_t)N_SRT * D_S * 4;   // 32 MB
    unsigned short* tc_h = (unsigned short*)p; p += (size_t)B_C * D_S * 2;    // 8 MB
    unsigned short* ts_h = (unsigned short*)p; p += (size_t)N_SRT * D_S * 2;  // 16 MB
    float* part = (float*)p;         p += (size_t)B_C * 64 * 4 * 4;  // 4 MB (in G's old 16MB slot)
    p += (size_t)B_C * NGRP * 2 - (size_t)B_C * 64 * 4 * 4;          // keep layout width
    int* g8   = (int*)p;             p += (size_t)B_C * PGRP * 4;
    p += (size_t)B_C * KSEL * 4;

    // fp16 2-plane workspace (appended; ~53.4 MB)
    _Float16* actS = (_Float16*)p; p += 2 * (size_t)N_SRT * D_S * 2; // 33.5 MB
    _Float16* actC = (_Float16*)p; p += 2 * (size_t)B_C * D_C * 2;   // 12.6 MB
    _Float16* wtS  = (_Float16*)p; p += 2 * (size_t)D_S * D_S * 2;   // 4.2 MB
    _Float16* wtC  = (_Float16*)p; p += 2 * (size_t)D_S * D_C * 2;   // 3.1 MB
    const size_t required = (size_t)(p - (char*)d_ws);

    if (ws_size >= required) {
        // --- scaled fp16x3 MFMA transform path ---
        split_all<<<NS_ACT + 448, 256, 0, stream>>>(
            srt, comments, actS, actC, Ws, wtS, Wc, wtC);

        transform_mfma_all<<<512 + 256, 256, 0, stream>>>(
            actS, wtS, bs, t_s, ts_h,
            actC, wtC, bc, t_c, tc_h);
    } else {
        // --- fallback: round-5 verified fp32 VALU path ---
        transform_fused<<<NB0 + NB1, 256, 0, stream>>>(
            comments, Wc, bc, t_c, tc_h,
            srt,      Ws, bs, t_s, ts_h);
    }

    scores_filter<<<512, 512, 0, stream>>>(ts_h, tc_h, part);
    top8_merge<<<B_C / 4, 256, 0, stream>>>(part, g8);
    refine_gather<<<B_C, 256, 0, stream>>>(t_c, t_s, g8, out);
}

// Round 17
// 217.128 us; speedup vs baseline: 1.5291x; 1.1209x over previous
//
#include <hip/hip_runtime.h>
#include <math.h>

#define B_C   4096   // comments
#define N_SRT 8192   // srt rows
#define D_C   768
#define D_S   1024
#define KSEL  2
#define NGRP  (N_SRT / 4)   // 2048 groups of 4 consecutive srt rows
#define PGRP  4             // groups refined per comment row (16 candidates)

typedef float    f32x4  __attribute__((ext_vector_type(4)));
typedef short    short8 __attribute__((ext_vector_type(8)));
typedef _Float16 half8  __attribute__((ext_vector_type(8)));

__device__ inline unsigned short f2bf(float f) {           // RTNE float->bf16
    unsigned u = __float_as_uint(f);
    u += 0x7FFF + ((u >> 16) & 1);
    return (unsigned short)(u >> 16);
}
__device__ inline float bf2f(unsigned short h) {
    return __uint_as_float(((unsigned)h) << 16);
}

#define GLOAD_LDS16(gsrc, ldst)                                                     \
    __builtin_amdgcn_global_load_lds(                                               \
        (const __attribute__((address_space(1))) void*)(gsrc),                      \
        (__attribute__((address_space(3))) void*)(ldst), 16, 0, 0)

// counted-vmcnt barrier pieces
#define WAIT_VM4  asm volatile("s_waitcnt vmcnt(4)" ::: "memory")
#define WAIT_VM0  asm volatile("s_waitcnt vmcnt(0)" ::: "memory")
#define WAIT_LGKM asm volatile("s_waitcnt lgkmcnt(0)" ::: "memory")

// ---------------------------------------------------------------------------
// split_all: act split + weight split in ONE launch (round-16 verified).
// ---------------------------------------------------------------------------
#define NS_ACT ((N_SRT * D_S / 8 + B_C * D_C / 8) / 256)   // 5632

__global__ __launch_bounds__(256)
void split_all(const float* __restrict__ srt, const float* __restrict__ com,
               _Float16* __restrict__ pS, _Float16* __restrict__ pC,
               const float* __restrict__ Ws, _Float16* __restrict__ WtS,
               const float* __restrict__ Wc, _Float16* __restrict__ WtC) {
    __shared__ float t[64][65];
    if ((int)blockIdx.x < NS_ACT) {
        const int g = blockIdx.x * 256 + threadIdx.x;
        const int E0 = N_SRT * D_S / 8;
        const float* src;
        _Float16* dst;
        size_t stride;
        if (g < E0) {
            src = srt + (size_t)g * 8; dst = pS + (size_t)g * 8;
            stride = (size_t)N_SRT * D_S;
        } else {
            const int g2 = g - E0;
            src = com + (size_t)g2 * 8; dst = pC + (size_t)g2 * 8;
            stride = (size_t)B_C * D_C;
        }
        const float4 a = *reinterpret_cast<const float4*>(src);
        const float4 b = *reinterpret_cast<const float4*>(src + 4);
        const float x[8] = {a.x, a.y, a.z, a.w, b.x, b.y, b.z, b.w};
        half8 hv, mv;
#pragma unroll
        for (int j = 0; j < 8; ++j) {
            const _Float16 h = (_Float16)x[j];
            const float    r = x[j] - (float)h;          // exact
            hv[j] = h; mv[j] = (_Float16)(r * 2048.0f);
        }
        *reinterpret_cast<half8*>(dst)          = hv;
        *reinterpret_cast<half8*>(dst + stride) = mv;
    } else {
        const int bb = (int)blockIdx.x - NS_ACT;
        const bool p1 = bb >= 256;
        const int  b  = p1 ? bb - 256 : bb;
        const float* __restrict__ W = p1 ? Wc : Ws;
        _Float16* __restrict__ Wt   = p1 ? WtC : WtS;
        const int K  = p1 ? D_C : D_S;
        const int n0 = (b & 15) * 64, k0 = (b >> 4) * 64;

        const int tid = threadIdx.x;
        const int c = tid & 63, rq = tid >> 6;
#pragma unroll
        for (int j = 0; j < 16; ++j) {
            const int kr = rq * 16 + j;
            t[kr][c] = W[(size_t)(k0 + kr) * D_S + n0 + c];
        }
        __syncthreads();
        const size_t PS = (size_t)K * D_S;
#pragma unroll
        for (int j = 0; j < 16; ++j) {
            const int nr = rq * 16 + j;
            const float xs = t[c][nr] * 32768.0f;        // exact (pow2 scale)
            const _Float16 h = (_Float16)xs;
            const float    r = xs - (float)h;            // exact
            const size_t o = (size_t)(n0 + nr) * K + k0 + c;
            Wt[o]      = h;
            Wt[o + PS] = (_Float16)(r * 2048.0f);
        }
    }
}

// ---------------------------------------------------------------------------
// transform_mfma_all: round-13 verified (chunk-fused scaled fp16x3). Frozen.
// ---------------------------------------------------------------------------
__global__ __launch_bounds__(256)
void transform_mfma_all(const _Float16* __restrict__ actS,
                        const _Float16* __restrict__ wtS,
                        const float* __restrict__ bS,
                        float* __restrict__ CS, unsigned short* __restrict__ HS,
                        const _Float16* __restrict__ actC,
                        const _Float16* __restrict__ wtC,
                        const float* __restrict__ bC,
                        float* __restrict__ CC, unsigned short* __restrict__ HC) {
    __shared__ __align__(16) _Float16 sW[2][2][128 * 32];  // [buf][plane]
    __shared__ __align__(16) _Float16 sA[2][2][128 * 32];
    const int tid  = threadIdx.x;
    const int lane = tid & 63;
    const int w    = tid >> 6;
    const int lr   = lane & 15, lg = lane >> 4;
    const int wn   = w & 1, wc = w >> 1;

    const int hw = blockIdx.x;
    int lgid, seg;
    if (hw < 512) { seg = 0; lgid = (hw & 7) * 64 + (hw >> 3); }
    else          { const int h2 = hw - 512; seg = 1; lgid = (h2 & 7) * 32 + (h2 >> 3); }

    const _Float16* __restrict__ actP = seg ? actC : actS;
    const _Float16* __restrict__ wtP  = seg ? wtC  : wtS;
    const float* __restrict__ bias    = seg ? bC   : bS;
    float* __restrict__ C             = seg ? CC   : CS;
    unsigned short* __restrict__ H    = seg ? HC   : HS;
    const int K   = seg ? D_C : D_S;
    const int NC  = seg ? (D_C / 32) : (D_S / 32);    // 24 : 32 chunks
    const size_t aps = seg ? (size_t)B_C * D_C : (size_t)N_SRT * D_S;
    const size_t wps = (size_t)D_S * K;

    const int bn = (lgid & 7) * 128;
    const int bm = (lgid >> 3) * 128;

    const f32x4 vzero = {0.f, 0.f, 0.f, 0.f};
    f32x4 acc[4][4];
#pragma unroll
    for (int i = 0; i < 4; ++i)
#pragma unroll
        for (int j = 0; j < 4; ++j) acc[i][j] = vzero;

    auto stage = [&](int buf, int c) {
        const int kb = c * 32;
#pragma unroll
        for (int i = 0; i < 2; ++i) {
            const int idx = tid + i * 256;
            const int r   = idx >> 2;
            const int sw  = ((idx & 3) ^ ((r >> 1) & 3)) * 8;
            const size_t wo = (size_t)(bn + r) * K + kb + sw;
            const size_t ao = (size_t)(bm + r) * K + kb + sw;
            GLOAD_LDS16(wtP  + wo,       (char*)&sW[buf][0][0] + idx * 16);
            GLOAD_LDS16(wtP  + wps + wo, (char*)&sW[buf][1][0] + idx * 16);
            GLOAD_LDS16(actP + ao,       (char*)&sA[buf][0][0] + idx * 16);
            GLOAD_LDS16(actP + aps + ao, (char*)&sA[buf][1][0] + idx * 16);
        }
    };

    stage(0, 0);
    WAIT_VM0;
    __builtin_amdgcn_s_barrier();

    for (int c = 0; c < NC; ++c) {
        const int cur = c & 1;
        if (c + 1 < NC) stage(cur ^ 1, c + 1);

        half8 a0[4], a1[4], b0[4], b1[4], b0s[4];
#pragma unroll
        for (int t4 = 0; t4 < 4; ++t4) {
            const int ra = wn * 64 + t4 * 16 + lr;
            const int oa = ra * 64 + ((lg ^ ((ra >> 1) & 3)) * 16);
            a0[t4] = *(const half8*)((const char*)&sW[cur][0][0] + oa);
            a1[t4] = *(const half8*)((const char*)&sW[cur][1][0] + oa);
            const int rb = wc * 64 + t4 * 16 + lr;
            const int ob = rb * 64 + ((lg ^ ((rb >> 1) & 3)) * 16);
            b0[t4] = *(const half8*)((const char*)&sA[cur][0][0] + ob);
            b1[t4] = *(const half8*)((const char*)&sA[cur][1][0] + ob);
            b0s[t4] = b0[t4] * (_Float16)2048.0f;    // exact pow2
        }
        __builtin_amdgcn_s_setprio(1);
#pragma unroll
        for (int i = 0; i < 4; ++i)
#pragma unroll
            for (int j = 0; j < 4; ++j) {
                acc[i][j] = __builtin_amdgcn_mfma_f32_16x16x32_f16(
                    a0[i], b0s[j], acc[i][j], 0, 0, 0);   // hh (2^26)
                acc[i][j] = __builtin_amdgcn_mfma_f32_16x16x32_f16(
                    a0[i], b1[j],  acc[i][j], 0, 0, 0);   // hm (2^26)
                acc[i][j] = __builtin_amdgcn_mfma_f32_16x16x32_f16(
                    a1[i], b0[j],  acc[i][j], 0, 0, 0);   // mh (2^26)
            }
        __builtin_amdgcn_s_setprio(0);

        WAIT_VM0;
        WAIT_LGKM;
        __builtin_amdgcn_s_barrier();
    }

    const float s2 = 1.4901161193847656e-8f;    // 2^-26
#pragma unroll
    for (int i = 0; i < 4; ++i) {
        const int n = bn + wn * 64 + i * 16 + lg * 4;
        const f32x4 bb = *reinterpret_cast<const f32x4*>(&bias[n]);
#pragma unroll
        for (int j = 0; j < 4; ++j) {
            const int m = bm + wc * 64 + j * 16 + lr;
            f32x4 o;
#pragma unroll
            for (int q = 0; q < 4; ++q)
                o[q] = fmaxf(fmaf(acc[i][j][q], s2, bb[q]), 0.f);
            *reinterpret_cast<f32x4*>(&C[(size_t)m * D_S + n]) = o;
            ushort4 hh;
            hh.x = f2bf(o[0]); hh.y = f2bf(o[1]);
            hh.z = f2bf(o[2]); hh.w = f2bf(o[3]);
            *reinterpret_cast<ushort4*>(&H[(size_t)m * D_S + n]) = hh;
        }
    }
}

// ---------------------------------------------------------------------------
// FALLBACK (round-5 verified): fused fp32 VALU transforms (ws too small).
// ---------------------------------------------------------------------------
#define NB0 ((B_C / 128) * (D_S / 128))     // 256
#define NB1 ((N_SRT / 128) * (D_S / 128))   // 512

__global__ __launch_bounds__(256)
void transform_fused(const float* __restrict__ A0, const float* __restrict__ W0,
                     const float* __restrict__ b0, float* __restrict__ C0,
                     unsigned short* __restrict__ H0,
                     const float* __restrict__ A1, const float* __restrict__ W1,
                     const float* __restrict__ b1, float* __restrict__ C1,
                     unsigned short* __restrict__ H1) {
    __shared__ __align__(16) float As[2][128][16];
    __shared__ __align__(16) float Bs[2][2048];

    const bool p1 = (int)blockIdx.x >= NB0;
    const int  b  = p1 ? (int)blockIdx.x - NB0 : (int)blockIdx.x;
    const float* __restrict__ A = p1 ? A1 : A0;
    const float* __restrict__ W = p1 ? W1 : W0;
    const float* __restrict__ bias = p1 ? b1 : b0;
    float* __restrict__ C = p1 ? C1 : C0;
    unsigned short* __restrict__ H = p1 ? H1 : H0;
    const int K = p1 ? D_S : D_C;

    const int bn = (b & 7) * 128;
    const int bm = (b >> 3) * 128;

    const int tid = threadIdx.x;
    const int tx = tid & 15, ty = tid >> 4;

    int a_off[2], w_off[2];
#pragma unroll
    for (int i = 0; i < 2; ++i) {
        const int idx = tid + i * 256;
        const int r = idx >> 2, q = idx & 3;
        a_off[i] = r * K + (q ^ ((r >> 3) & 3)) * 4;
        const int s = idx & 63;
        const int kloc = 2 * (idx >> 6) + ((s >> 4) & 1);
        const int cb   = 2 * (s & 15) + (s >> 5);
        w_off[i] = kloc * D_S + cb * 4;
    }

#define STAGE(bufi, k0)                                                        \
    {                                                                          \
        _Pragma("unroll")                                                      \
        for (int i = 0; i < 2; ++i) {                                          \
            const int idx = tid + i * 256;                                     \
            GLOAD_LDS16(A + (size_t)bm * K + (k0) + a_off[i],                  \
                        (char*)&As[bufi][0][0] + idx * 16);                    \
            GLOAD_LDS16(W + (size_t)(k0) * D_S + bn + w_off[i],                \
                        (char*)&Bs[bufi][0] + idx * 16);                       \
        }                                                                      \
    }

    float acc[8][8] = {};

    STAGE(0, 0);
    __syncthreads();

    const int nk = K / 16;
    for (int t = 0; t < nk; ++t) {
        const int cur = t & 1;
        if (t + 1 < nk) STAGE(t & 1 ? 0 : 1, (t + 1) * 16);

        const float* __restrict__ Bf = &Bs[cur][0];
#pragma unroll
        for (int kq = 0; kq < 4; ++kq) {
            f32x4 a4[8];
#pragma unroll
            for (int i = 0; i < 8; ++i)
                a4[i] = *reinterpret_cast<const f32x4*>(
                    &As[cur][ty * 8 + i][(kq ^ (ty & 3)) * 4]);
#pragma unroll
            for (int k2 = 0; k2 < 4; ++k2) {
                const int k = kq * 4 + k2;
                const int boff = (k >> 1) * 256 + (tx + ((k & 1) << 4)) * 4;
                const f32x4 bx = *reinterpret_cast<const f32x4*>(Bf + boff);
                const f32x4 by = *reinterpret_cast<const f32x4*>(Bf + boff + 128);
                const float bv[8] = {bx[0], bx[1], bx[2], bx[3], by[0], by[1], by[2], by[3]};
#pragma unroll
                for (int i = 0; i < 8; ++i) {
                    const float av = a4[i][k2];
#pragma unroll
                    for (int j = 0; j < 8; ++j)
                        acc[i][j] = fmaf(av, bv[j], acc[i][j]);
                }
            }
        }
        __syncthreads();
    }
#undef STAGE

    const f32x4 g0 = *reinterpret_cast<const f32x4*>(&bias[bn + tx * 8]);
    const f32x4 g1 = *reinterpret_cast<const f32x4*>(&bias[bn + tx * 8 + 4]);
#pragma unroll
    for (int i = 0; i < 8; ++i) {
        const int m = bm + ty * 8 + i;
        const int n = bn + tx * 8;
        f32x4 o0, o1;
#pragma unroll
        for (int j = 0; j < 4; ++j) {
            o0[j] = fmaxf(acc[i][j]     + g0[j], 0.f);
            o1[j] = fmaxf(acc[i][j + 4] + g1[j], 0.f);
        }
        *reinterpret_cast<f32x4*>(&C[(size_t)m * D_S + n])     = o0;
        *reinterpret_cast<f32x4*>(&C[(size_t)m * D_S + n + 4]) = o1;
        short8 h;
#pragma unroll
        for (int j = 0; j < 4; ++j) {
            h[j]     = (short)f2bf(o0[j]);
            h[j + 4] = (short)f2bf(o1[j]);
        }
        *reinterpret_cast<short8*>(&H[(size_t)m * D_S + n]) = h;
    }
}

// ---------------------------------------------------------------------------
// Kernel 2: bf16 MFMA score filter — round-15/16 verified (8-phase main loop
// + register top-2 epilogue into part). Unchanged.
// ---------------------------------------------------------------------------
__global__ __launch_bounds__(512)
void scores_filter(const unsigned short* __restrict__ TSh,
                   const unsigned short* __restrict__ TCh,
                   float* __restrict__ part) {     // [B_C][64] float4 entries
    __shared__ __align__(16) unsigned short sA[2][2][128 * 64];  // [parity][half]
    __shared__ __align__(16) unsigned short sB[2][2][128 * 64];
    const int tid  = threadIdx.x;
    const int lane = tid & 63;
    const int w    = tid >> 6;          // 0..7
    const int mw   = w >> 2;            // A(srt) half: 0..1
    const int nw   = w & 3;             // B(c) quarter: 0..3
    const int bh   = nw >> 1;           // B half this wave reads
    const int lr   = lane & 15, lg = lane >> 4;

    const int hw   = blockIdx.x;
    const int lgid = (hw & 7) * 64 + (hw >> 3);
    const int n0   = (lgid & 31) * 256;     // srt tile
    const int c0   = (lgid >> 5) * 256;     // comment tile

    const f32x4 vzero = {0.f, 0.f, 0.f, 0.f};
    f32x4 acc[8][4];
#pragma unroll
    for (int i = 0; i < 8; ++i)
#pragma unroll
        for (int j = 0; j < 4; ++j) acc[i][j] = vzero;

    auto stageHalf = [&](unsigned short* ldsbase, const unsigned short* grow0,
                         int kb) {
#pragma unroll
        for (int i = 0; i < 2; ++i) {
            const int idx = tid + i * 512;
            const int r   = idx >> 3;
            const int sw  = ((idx & 7) ^ (r & 7)) * 8;
            GLOAD_LDS16(grow0 + (size_t)r * D_S + kb + sw,
                        (char*)ldsbase + idx * 16);
        }
    };

    const unsigned short* TS0 = TSh + (size_t)n0 * D_S;
    const unsigned short* TS1 = TSh + (size_t)(n0 + 128) * D_S;
    const unsigned short* TC0 = TCh + (size_t)c0 * D_S;
    const unsigned short* TC1 = TCh + (size_t)(c0 + 128) * D_S;

    stageHalf(&sA[0][0][0], TS0, 0);
    stageHalf(&sA[0][1][0], TS1, 0);
    stageHalf(&sB[0][0][0], TC0, 0);
    stageHalf(&sB[0][1][0], TC1, 0);
    stageHalf(&sB[1][0][0], TC0, 64);
    stageHalf(&sB[1][1][0], TC1, 64);
    WAIT_VM4;
    __builtin_amdgcn_s_barrier();

    const int NITER = D_S / 128;        // 8 iterations, 2 K-steps each
    for (int t = 0; t < NITER; ++t) {
        const bool nl = (t + 1 < NITER);

#pragma unroll
        for (int par = 0; par < 2; ++par) {
            short8 bfr[4][2];
#pragma unroll
            for (int ph = 0; ph < 4; ++ph) {
                short8 afr[2][2];
                if (ph == 0) {
#pragma unroll
                    for (int j = 0; j < 4; ++j) {
                        const int rb = (nw & 1) * 64 + j * 16 + lr;
#pragma unroll
                        for (int kk = 0; kk < 2; ++kk)
                            bfr[j][kk] = *(const short8*)(
                                (const char*)&sB[par][bh][0] + rb * 128 +
                                (((kk * 4 + lg) ^ (rb & 7)) * 16));
                    }
                }
#pragma unroll
                for (int ii = 0; ii < 2; ++ii) {
                    const int ra = (ph * 2 + ii) * 16 + lr;
#pragma unroll
                    for (int kk = 0; kk < 2; ++kk)
                        afr[ii][kk] = *(const short8*)(
                            (const char*)&sA[par][mw][0] + ra * 128 +
                            (((kk * 4 + lg) ^ (ra & 7)) * 16));
                }
                if (par == 0) {
                    if (ph == 0)            stageHalf(&sA[1][0][0], TS0, (2*t+1)*64);
                    else if (ph == 1)       stageHalf(&sA[1][1][0], TS1, (2*t+1)*64);
                    else if (ph == 2) { if (nl) stageHalf(&sB[0][0][0], TC0, (2*t+2)*64); }
                    else              { if (nl) stageHalf(&sB[0][1][0], TC1, (2*t+2)*64); }
                } else {
                    if (ph == 0)      { if (nl) stageHalf(&sA[0][0][0], TS0, (2*t+2)*64); }
                    else if (ph == 1) { if (nl) stageHalf(&sA[0][1][0], TS1, (2*t+2)*64); }
                    else if (ph == 2) { if (nl) stageHalf(&sB[1][0][0], TC0, (2*t+3)*64); }
                    else              { if (nl) stageHalf(&sB[1][1][0], TC1, (2*t+3)*64); }
                }
                if (ph == 3) { if (nl) { WAIT_VM4; } else { WAIT_VM0; } }
                __builtin_amdgcn_s_barrier();
                WAIT_LGKM;
                __builtin_amdgcn_s_setprio(1);
#pragma unroll
                for (int ii = 0; ii < 2; ++ii)
#pragma unroll
                    for (int j = 0; j < 4; ++j)
#pragma unroll
                        for (int kk = 0; kk < 2; ++kk)
                            acc[ph * 2 + ii][j] = __builtin_amdgcn_mfma_f32_16x16x32_bf16(
                                afr[ii][kk], bfr[j][kk], acc[ph * 2 + ii][j], 0, 0, 0);
                __builtin_amdgcn_s_setprio(0);
                __builtin_amdgcn_s_barrier();
            }
        }
    }

    // epilogue: per-(c, half) top-2 -> part (round-16 verified)
    const int gbase = (n0 >> 2) + mw * 32;
#pragma unroll
    for (int j = 0; j < 4; ++j) {
        float v1 = -INFINITY, v2 = -INFINITY;
        int   g1 = 0, g2 = 0;
#pragma unroll
        for (int i = 0; i < 8; ++i) {
            const f32x4 v = acc[i][j];
            const float m = fmaxf(fmaxf(v.x, v.y), fmaxf(v.z, v.w));
            const int g = gbase + i * 4 + lg;
            if (m > v1)      { v2 = v1; g2 = g1; v1 = m; g1 = g; }
            else if (m > v2) { v2 = m; g2 = g; }
        }
#pragma unroll
        for (int off = 16; off <= 32; off <<= 1) {
            const float ov1 = __shfl_xor(v1, off);
            const int   og1 = __shfl_xor(g1, off);
            const float ov2 = __shfl_xor(v2, off);
            const int   og2 = __shfl_xor(g2, off);
            if (ov1 > v1 || (ov1 == v1 && og1 < g1)) { v2 = v1; g2 = g1; v1 = ov1; g1 = og1; }
            else if (ov1 > v2 || (ov1 == v2 && og1 < g2)) { v2 = ov1; g2 = og1; }
            if (ov2 > v1 || (ov2 == v1 && og2 < g1)) { v2 = v1; g2 = g1; v1 = ov2; g1 = og2; }
            else if (ov2 > v2 || (ov2 == v2 && og2 < g2)) { v2 = ov2; g2 = og2; }
        }
        if (lg == 0) {
            const int c = c0 + nw * 64 + j * 16 + lr;
            const int blk2 = (lgid & 31) * 2 + mw;
            f32x4 e;
            e[0] = v1; e[1] = __int_as_float(g1);
            e[2] = v2; e[3] = __int_as_float(g2);
            *reinterpret_cast<f32x4*>(&part[((size_t)c * 64 + blk2) * 4]) = e;
        }
    }
}

// ---------------------------------------------------------------------------
// Kernel 3 (round-17): fused merge + refine + gather. One block per row.
// Wave 0 merges the 64 partial top-2 entries -> top-PGRP(4) groups (total
// order value desc/group asc; output sorted ascending). Then each of 4 waves
// refines one group (4 exact fp32 dots), tid0 scans ascending-n with strict
// '>' (reference tie rule), block gathers the 2 selected rows.
// ---------------------------------------------------------------------------
__global__ __launch_bounds__(256)
void refine_gather(const float* __restrict__ t_c, const float* __restrict__ t_s,
                   const float* __restrict__ part, float* __restrict__ out) {
    __shared__ float tc[D_S];
    __shared__ float sc[4 * PGRP];
    __shared__ int   selg[PGRP];
    __shared__ int   sel[2];
    const int row = blockIdx.x;
    const int tid = threadIdx.x;
    *reinterpret_cast<float4*>(&tc[tid * 4]) =
        *reinterpret_cast<const float4*>(&t_c[(size_t)row * D_S + tid * 4]);
    const int w = tid >> 6, lane = tid & 63;

    if (w == 0) {   // merge: lane holds one part entry (2 candidates)
        const f32x4 e = *reinterpret_cast<const f32x4*>(
            &part[((size_t)row * 64 + lane) * 4]);
        const float v[2]  = {e[0], e[2]};
        const int   gi[2] = {__float_as_int(e[1]), __float_as_int(e[3])};
        float pv = INFINITY; int pi = -1;
        int gl[PGRP];
#pragma unroll
        for (int k = 0; k < PGRP; ++k) {
            float bv = -INFINITY; int bi = 0x7FFFFFFF;
#pragma unroll
            for (int s = 0; s < 2; ++s) {
                const bool after  = (v[s] < pv) || (v[s] == pv && gi[s] > pi);
                const bool before = (v[s] > bv) || (v[s] == bv && gi[s] < bi);
                if (after && before) { bv = v[s]; bi = gi[s]; }
            }
#pragma unroll
            for (int off = 32; off >= 1; off >>= 1) {
                const float ov = __shfl_xor(bv, off);
                const int   oi = __shfl_xor(bi, off);
                if ((ov > bv) || (ov == bv && oi < bi)) { bv = ov; bi = oi; }
            }
            gl[k] = bi; pv = bv; pi = bi;
        }
        // sort ascending (static indices)
#pragma unroll
        for (int a = 0; a < PGRP; ++a)
#pragma unroll
            for (int b2 = 0; b2 < PGRP - 1; ++b2)
                if (gl[b2] > gl[b2 + 1]) { int t = gl[b2]; gl[b2] = gl[b2 + 1]; gl[b2 + 1] = t; }
        if (lane == 0) {
#pragma unroll
            for (int k = 0; k < PGRP; ++k) selg[k] = gl[k];
        }
    }
    __syncthreads();

    float4 c4[4];
#pragma unroll
    for (int q = 0; q < 4; ++q)
        c4[q] = *reinterpret_cast<const float4*>(&tc[lane * 16 + q * 4]);
    const int g = selg[w];               // one group per wave
#pragma unroll
    for (int o = 0; o < 4; ++o) {
        const int n = g * 4 + o;
        const float* ts = t_s + (size_t)n * D_S + lane * 16;
        float p = 0.f;
#pragma unroll
        for (int q = 0; q < 4; ++q) {
            const float4 tv = *reinterpret_cast<const float4*>(ts + q * 4);
            p += c4[q].x * tv.x + c4[q].y * tv.y + c4[q].z * tv.z + c4[q].w * tv.w;
        }
#pragma unroll
        for (int off = 32; off >= 1; off >>= 1) p += __shfl_xor(p, off);
        if (lane == 0) sc[w * 4 + o] = p;
    }
    __syncthreads();
    if (tid == 0) {
        float v1 = -INFINITY, v2 = -INFINITY; int i1 = 0, i2 = 0;
#pragma unroll
        for (int s = 0; s < 4 * PGRP; ++s) {   // selg sorted => ascending n
            const int n = selg[s >> 2] * 4 + (s & 3);
            const float v = sc[s];
            if (v > v1)      { v2 = v1; i2 = i1; v1 = v; i1 = n; }
            else if (v > v2) { v2 = v; i2 = n; }
        }
        sel[0] = i1; sel[1] = i2;
    }
    __syncthreads();
#pragma unroll
    for (int q = 0; q < 2; ++q) {
        const int src = sel[q];
        const float4 v = *reinterpret_cast<const float4*>(
            &t_s[(size_t)src * D_S + tid * 4]);
        *reinterpret_cast<float4*>(
            &out[((size_t)row * KSEL + q) * D_S + tid * 4]) = v;
    }
}

// ---------------------------------------------------------------------------
extern "C" void kernel_launch(void* const* d_in, const int* in_sizes, int n_in,
                              void* d_out, int out_size, void* d_ws, size_t ws_size,
                              hipStream_t stream) {
    const float* srt      = (const float*)d_in[0];  // [8192,1024]
    const float* comments = (const float*)d_in[1];  // [4096,768]
    const float* Wc       = (const float*)d_in[2];  // [768,1024]
    const float* bc       = (const float*)d_in[3];  // [1024]
    const float* Ws       = (const float*)d_in[4];  // [1024,1024]
    const float* bs       = (const float*)d_in[5];  // [1024]
    float* out = (float*)d_out;

    // base workspace layout
    char* p = (char*)d_ws;
    float* t_c = (float*)p;          p += (size_t)B_C * D_S * 4;     // 16 MB
    float* t_s = (float*)p;          p += (size_t)N_SRT * D_S * 4;   // 32 MB
    unsigned short* tc_h = (unsigned short*)p; p += (size_t)B_C * D_S * 2;    // 8 MB
    unsigned short* ts_h = (unsigned short*)p; p += (size_t)N_SRT * D_S * 2;  // 16 MB
    float* part = (float*)p;         p += (size_t)B_C * NGRP * 2;    // part in G's old slot
    p += (size_t)B_C * PGRP * 4;
    p += (size_t)B_C * KSEL * 4;

    // fp16 2-plane workspace (appended; ~53.4 MB)
    _Float16* actS = (_Float16*)p; p += 2 * (size_t)N_SRT * D_S * 2; // 33.5 MB
    _Float16* actC = (_Float16*)p; p += 2 * (size_t)B_C * D_C * 2;   // 12.6 MB
    _Float16* wtS  = (_Float16*)p; p += 2 * (size_t)D_S * D_S * 2;   // 4.2 MB
    _Float16* wtC  = (_Float16*)p; p += 2 * (size_t)D_S * D_C * 2;   // 3.1 MB
    const size_t required = (size_t)(p - (char*)d_ws);

    if (ws_size >= required) {
        // --- scaled fp16x3 MFMA transform path ---
        split_all<<<NS_ACT + 448, 256, 0, stream>>>(
            srt, comments, actS, actC, Ws, wtS, Wc, wtC);

        transform_mfma_all<<<512 + 256, 256, 0, stream>>>(
            actS, wtS, bs, t_s, ts_h,
            actC, wtC, bc, t_c, tc_h);
    } else {
        // --- fallback: round-5 verified fp32 VALU path ---
        transform_fused<<<NB0 + NB1, 256, 0, stream>>>(
            comments, Wc, bc, t_c, tc_h,
            srt,      Ws, bs, t_s, ts_h);
    }

    scores_filter<<<512, 512, 0, stream>>>(ts_h, tc_h, part);
    refine_gather<<<B_C, 256, 0, stream>>>(t_c, t_s, part, out);
}